// Round 6
// baseline (262.442 us; speedup 1.0000x reference)
//
#include <hip/hip_runtime.h>

typedef short bf16x8 __attribute__((ext_vector_type(8)));
typedef float f32x4 __attribute__((ext_vector_type(4)));

struct Params {
  const float* loc; const float* ts; const int* cat; const int* seg;
  const int* off;
  const float *wl1,*bl1,*wl2,*bl2;
  const float *wt1,*bt1,*wt2,*bt2;
  const float *wa1,*ba1,*wa2,*ba2;
  const float *wm1,*bm1,*wm2,*bm2;
  const float *wc1,*bc1,*wc2,*bc2;
  float* out;
  int N, T, use_off;
};

__global__ void offsets_kernel(const int* __restrict__ seg, int* __restrict__ off, int T, int N) {
  int i = blockIdx.x * blockDim.x + threadIdx.x;
  if (i == 0) off[N] = T;
  if (i < T) {
    int s = seg[i];
    if (i == 0 || seg[i-1] != s) off[s] = i;
  }
}

__device__ __forceinline__ int rdlane_i(int v, int l) {
  return __builtin_amdgcn_readlane(v, l);
}

__device__ __forceinline__ unsigned bf16r(float f) {
  unsigned x = __float_as_uint(f);
  return (x + 0x7fffu + ((x >> 16) & 1u)) >> 16;
}
__device__ __forceinline__ unsigned pack_hl(float f) {
  unsigned hi = bf16r(f);
  float r = f - __uint_as_float(hi << 16);
  return (hi << 16) | bf16r(r);
}

__device__ __forceinline__ float exact_fmod(float a, float m, float rcp_m) {
  float q = floorf(a * rcp_m);
  float r = fmaf(q, -m, a);
  if (r < 0.0f) r += m;
  else if (r >= m) r -= m;
  return r;
}

__device__ __forceinline__ f32x4 mfma16(bf16x8 a, bf16x8 b, f32x4 c) {
  return __builtin_amdgcn_mfma_f32_16x16x32_bf16(a, b, c, 0, 0, 0);
}

__device__ __forceinline__ void lda(const unsigned* rp, bf16x8& hi, bf16x8& lo) {
  uint4 w0 = *(const uint4*)rp;
  uint4 w1 = *(const uint4*)(rp + 4);
  union { unsigned u[4]; bf16x8 v; } H, L;
  H.u[0] = __builtin_amdgcn_perm(w0.y, w0.x, 0x07060302u);
  H.u[1] = __builtin_amdgcn_perm(w0.w, w0.z, 0x07060302u);
  H.u[2] = __builtin_amdgcn_perm(w1.y, w1.x, 0x07060302u);
  H.u[3] = __builtin_amdgcn_perm(w1.w, w1.z, 0x07060302u);
  L.u[0] = __builtin_amdgcn_perm(w0.y, w0.x, 0x05040100u);
  L.u[1] = __builtin_amdgcn_perm(w0.w, w0.z, 0x05040100u);
  L.u[2] = __builtin_amdgcn_perm(w1.y, w1.x, 0x05040100u);
  L.u[3] = __builtin_amdgcn_perm(w1.w, w1.z, 0x05040100u);
  hi = H.v; lo = L.v;
}

__device__ __forceinline__ bf16x8 ldb(const unsigned* wf, int fi, int lane) {
  union { uint4 q; bf16x8 v; } U;
  U.q = *(const uint4*)(wf + ((fi * 64 + lane) << 2));
  return U.v;
}

__device__ __forceinline__ float bdval(const Params& p, int k, int col) {
  if ((k >> 4) != (col >> 4)) return 0.f;
  int b = col >> 4;
  const float* W2 = (b & 2) ? ((b & 1) ? p.wm2 : p.wa2) : ((b & 1) ? p.wt2 : p.wl2);
  return W2[(k & 15) * 16 + (col & 15)];
}

__device__ __forceinline__ int lower_bound(const int* seg, int T, int v) {
  int lo = 0, hi = T;
  while (lo < hi) { int m = (lo + hi) >> 1; if (seg[m] < v) lo = m + 1; else hi = m; }
  return lo;
}

// ---------------- wave64 segmented scans via DPP ----------------
#define DPPF0(v, ctrl, rm) __int_as_float(__builtin_amdgcn_update_dpp(0, __float_as_int(v), ctrl, rm, 0xf, true))
#define DPPI0(v, ctrl, rm) __builtin_amdgcn_update_dpp(0, (v), ctrl, rm, 0xf, true)
#define DPPFO(v, o, ctrl, rm) __int_as_float(__builtin_amdgcn_update_dpp(__float_as_int(o), __float_as_int(v), ctrl, rm, 0xf, false))

struct Conds { bool c1,c2,c4,c8,cA,cB; };

__device__ __forceinline__ Conds mkconds(int lane, int dist) {
  Conds C;
  C.c1 = dist >= 1; C.c2 = dist >= 2; C.c4 = dist >= 4; C.c8 = dist >= 8;
  C.cA = ((lane & 15) + 1) <= dist;   // bcast15: source = last lane of prev row
  C.cB = (lane - 31) <= dist;         // bcast31: source = lane 31
  return C;
}

__device__ __forceinline__ int smaxi(int v) {  // plain inclusive max-scan (v >= 0)
  int i;
  i = DPPI0(v,0x111,0xf); v = max(v,i);
  i = DPPI0(v,0x112,0xf); v = max(v,i);
  i = DPPI0(v,0x114,0xf); v = max(v,i);
  i = DPPI0(v,0x118,0xf); v = max(v,i);
  i = DPPI0(v,0x142,0xa); v = max(v,i);
  i = DPPI0(v,0x143,0xc); v = max(v,i);
  return v;
}
__device__ __forceinline__ float sadd(float v, const Conds& C) {
  float i;
  i = DPPF0(v,0x111,0xf); v = C.c1 ? v + i : v;
  i = DPPF0(v,0x112,0xf); v = C.c2 ? v + i : v;
  i = DPPF0(v,0x114,0xf); v = C.c4 ? v + i : v;
  i = DPPF0(v,0x118,0xf); v = C.c8 ? v + i : v;
  i = DPPF0(v,0x142,0xa); v = C.cA ? v + i : v;
  i = DPPF0(v,0x143,0xc); v = C.cB ? v + i : v;
  return v;
}
__device__ __forceinline__ unsigned saddu(unsigned v, const Conds& C) {
  int x = (int)v, i;
  i = DPPI0(x,0x111,0xf); x = C.c1 ? x + i : x;
  i = DPPI0(x,0x112,0xf); x = C.c2 ? x + i : x;
  i = DPPI0(x,0x114,0xf); x = C.c4 ? x + i : x;
  i = DPPI0(x,0x118,0xf); x = C.c8 ? x + i : x;
  i = DPPI0(x,0x142,0xa); x = C.cA ? x + i : x;
  i = DPPI0(x,0x143,0xc); x = C.cB ? x + i : x;
  return (unsigned)x;
}
__device__ __forceinline__ float smaxf(float v, const Conds& C) {
  const float NI = __int_as_float(0xff800000u);
  float i;
  i = DPPFO(v,NI,0x111,0xf); v = C.c1 ? fmaxf(v,i) : v;
  i = DPPFO(v,NI,0x112,0xf); v = C.c2 ? fmaxf(v,i) : v;
  i = DPPFO(v,NI,0x114,0xf); v = C.c4 ? fmaxf(v,i) : v;
  i = DPPFO(v,NI,0x118,0xf); v = C.c8 ? fmaxf(v,i) : v;
  i = DPPFO(v,NI,0x142,0xa); v = C.cA ? fmaxf(v,i) : v;
  i = DPPFO(v,NI,0x143,0xc); v = C.cB ? fmaxf(v,i) : v;
  return v;
}
__device__ __forceinline__ float sminf(float v, const Conds& C) {
  const float PI_ = __int_as_float(0x7f800000u);
  float i;
  i = DPPFO(v,PI_,0x111,0xf); v = C.c1 ? fminf(v,i) : v;
  i = DPPFO(v,PI_,0x112,0xf); v = C.c2 ? fminf(v,i) : v;
  i = DPPFO(v,PI_,0x114,0xf); v = C.c4 ? fminf(v,i) : v;
  i = DPPFO(v,PI_,0x118,0xf); v = C.c8 ? fminf(v,i) : v;
  i = DPPFO(v,PI_,0x142,0xa); v = C.cA ? fminf(v,i) : v;
  i = DPPFO(v,PI_,0x143,0xc); v = C.cB ? fminf(v,i) : v;
  return v;
}

// acc slots per user (stride 15): 0 sx/hx, 1 sy/hy, 2 sh, 3 sdy, 4 smo,
// 5 sdf, 6 sdf2, 7-10 hist(u32), 11 tmx(bits), 12 tmn(bits), 13 sD, 14 sD2
__global__ __launch_bounds__(256, 4) void mobility_kernel(Params p) {
  __shared__ __align__(16) unsigned s_wfrag[5120];   // 20480 B
  __shared__ __align__(16) unsigned s_pool[4352];    // 17408 B: acc[3840] | hash[512]
  __shared__ float s_w1[304];
  __shared__ float s_b1[64], s_b2[64], s_bc1[64], s_bc2[64];

  int tid = threadIdx.x;
  int lane = tid & 63, w = tid >> 6;
  float* accf = (float*)s_pool;

  // ---- stage W fragments (bf16) ----
  for (int m = tid; m < 5120; m += 256) {
    int fi = m >> 8;
    int ln = (m >> 2) & 63;
    int j2 = m & 3;
    int layer, nt, ks;
    if (fi < 4)       { layer = 0; nt = fi;             ks = nt >> 1; }
    else if (fi < 12) { layer = 1; nt = (fi - 4) >> 1;  ks = (fi - 4) & 1; }
    else              { layer = 2; nt = (fi - 12) >> 1; ks = (fi - 12) & 1; }
    int col = nt * 16 + (ln & 15);
    int k0  = ks * 32 + ((ln >> 4) << 3) + (j2 << 1);
    float v0, v1;
    if (layer == 0) { v0 = bdval(p, k0, col); v1 = bdval(p, k0 + 1, col); }
    else {
      const float* W = (layer == 1) ? p.wc1 : p.wc2;
      v0 = W[k0 * 64 + col]; v1 = W[(k0 + 1) * 64 + col];
    }
    s_wfrag[m] = (bf16r(v1) << 16) | bf16r(v0);
  }
  if (tid < 32)  s_w1[tid]       = p.wl1[tid];
  if (tid < 48)  s_w1[32 + tid]  = p.wt1[tid];
  if (tid < 160) s_w1[80 + tid]  = p.wa1[tid];
  if (tid < 64)  s_w1[240 + tid] = p.wm1[tid];
  if (tid < 16) {
    s_b1[tid]    = p.bl1[tid]; s_b1[16+tid] = p.bt1[tid];
    s_b1[32+tid] = p.ba1[tid]; s_b1[48+tid] = p.bm1[tid];
    s_b2[tid]    = p.bl2[tid]; s_b2[16+tid] = p.bt2[tid];
    s_b2[32+tid] = p.ba2[tid]; s_b2[48+tid] = p.bm2[tid];
  }
  if (tid < 64) { s_bc1[tid] = p.bc1[tid]; s_bc2[tid] = p.bc2[tid]; }
  // zero accumulators (tmn slot -> +inf bits)
  for (int i = tid; i < 3840; i += 256)
    accf[i] = (i % 15 == 12) ? __uint_as_float(0x7f800000u) : 0.0f;
  __syncthreads();

  int u0 = blockIdx.x * 256;
  int myu = u0 + tid;
  bool has_u = myu < p.N;
  int myuc = min(myu, p.N - 1);
  int s0, e0, E0, E1;
  if (p.use_off) {
    s0 = p.off[myuc]; e0 = p.off[myuc + 1];
    E0 = p.off[u0];   E1 = p.off[min(u0 + 256, p.N)];
  } else {
    s0 = lower_bound(p.seg, p.T, myuc);
    e0 = lower_bound(p.seg, p.T, myuc + 1);
    E0 = lower_bound(p.seg, p.T, u0);
    E1 = lower_bound(p.seg, p.T, min(u0 + 256, p.N));
  }

  const float2* lp2 = (const float2*)p.loc;

  // ---------------- pass 1: coalesced event stats via segmented scans ----------------
  for (int base = E0 + 64 * w; base < E1; base += 256) {
    int e = base + lane;
    bool on = e < E1;
    int ec = on ? e : (E1 - 1);
    int sv = p.seg[ec];
    int sp = (ec > 0) ? p.seg[ec - 1] : -99;
    int sn = (ec + 1 < p.T) ? p.seg[ec + 1] : -99;
    float2 xy = lp2[ec];
    float t  = p.ts[ec];
    float tn = (ec + 1 < p.T) ? p.ts[ec + 1] : 0.f;
    int c = p.cat[ec];
    int su = on ? sv : (-1 - (int)lane);

    bool head = (!on) || (e == 0) || (sp != sv);
    bool tail = (!on) || (sn != sv) || (lane == 63);
    bool dv   = on && (sn == sv);

    int idx = head ? (int)lane : 0;
    int j = smaxi(idx);
    int dist = (int)lane - j;
    Conds C = mkconds((int)lane, dist);

    float vx=0.f, vy=0.f, vh=0.f, vdy=0.f, vmo=0.f, vdf=0.f, vdf2=0.f;
    unsigned w0=0u, w1=0u, w2=0u, w3=0u;
    if (on) {
      vx = xy.x; vy = xy.y;
      float hr = exact_fmod(t, 86400.0f, 1.0f / 86400.0f);
      vh = hr * (1.0f / 3600.0f);
      float ud = (float)((double)t * (1.0 / 86400.0));
      vdy = exact_fmod(ud, 7.0f, 1.0f / 7.0f);
      vmo = t * (1.0f / 2592000.0f);
      int wsel = (c >= 9) ? 3 : (c / 3);
      int fld  = (c >= 9) ? 0 : (c - wsel * 3);
      unsigned bit = 1u << (10 * fld);
      w0 = (wsel == 0) ? bit : 0u;
      w1 = (wsel == 1) ? bit : 0u;
      w2 = (wsel == 2) ? bit : 0u;
      w3 = (wsel == 3) ? bit : 0u;
    }
    if (dv) { float dt = tn - t; vdf = dt; vdf2 = dt * dt; }
    float tmaxin = on ? t : __int_as_float(0xff800000u);
    float tminin = on ? t : __int_as_float(0x7f800000u);

    vx = sadd(vx, C); vy = sadd(vy, C); vh = sadd(vh, C);
    vdy = sadd(vdy, C); vmo = sadd(vmo, C);
    vdf = sadd(vdf, C); vdf2 = sadd(vdf2, C);
    w0 = saddu(w0, C); w1 = saddu(w1, C); w2 = saddu(w2, C); w3 = saddu(w3, C);
    float tmx = smaxf(tmaxin, C);
    float tmn = sminf(tminin, C);

    if (tail && su >= 0) {
      float* a = accf + (su - u0) * 15;
      atomicAdd(a + 0, vx);  atomicAdd(a + 1, vy);
      atomicAdd(a + 2, vh);  atomicAdd(a + 3, vdy);
      atomicAdd(a + 4, vmo); atomicAdd(a + 5, vdf);
      atomicAdd(a + 6, vdf2);
      unsigned* au = (unsigned*)a;
      atomicAdd(au + 7, w0); atomicAdd(au + 8, w1);
      atomicAdd(au + 9, w2); atomicAdd(au + 10, w3);
      atomicMax(au + 11, __float_as_uint(tmx));
      atomicMin(au + 12, __float_as_uint(tmn));
    }
  }
  __syncthreads();

  // ---------------- step 3: per-user home (overwrite slots 0,1) ----------------
  float Lf = (float)(e0 - s0);
  float hx = 0.f, hy = 0.f;
  {
    float* a = accf + tid * 15;
    float sx = a[0], sy = a[1];
    hx = sx / Lf; hy = sy / Lf;
    a[0] = hx; a[1] = hy;
  }
  __syncthreads();

  // ---------------- pass 2: coalesced distance sums ----------------
  for (int base = E0 + 64 * w; base < E1; base += 256) {
    int e = base + lane;
    bool on = e < E1;
    int ec = on ? e : (E1 - 1);
    int sv = p.seg[ec];
    int sp = (ec > 0) ? p.seg[ec - 1] : -99;
    int sn = (ec + 1 < p.T) ? p.seg[ec + 1] : -99;
    float2 xy = lp2[ec];
    int su = on ? sv : (-1 - (int)lane);

    bool head = (!on) || (e == 0) || (sp != sv);
    bool tail = (!on) || (sn != sv) || (lane == 63);
    int idx = head ? (int)lane : 0;
    int j = smaxi(idx);
    Conds C = mkconds((int)lane, (int)lane - j);

    int uloc = max(su - u0, 0);
    float hxu = accf[uloc * 15 + 0];
    float hyu = accf[uloc * 15 + 1];
    float dd = 0.f, dd2 = 0.f;
    if (on) {
      float dx = xy.x - hxu, dyv = xy.y - hyu;
      float d2v = fmaf(dx, dx, dyv * dyv);
      dd2 = d2v;
      dd = sqrtf(d2v);
    }
    dd = sadd(dd, C); dd2 = sadd(dd2, C);
    if (tail && su >= 0) {
      float* a = accf + (su - u0) * 15;
      atomicAdd(a + 13, dd);
      atomicAdd(a + 14, dd2);
    }
  }

  // ---------------- phase B: unique locations (wave-per-user LDS hash) ----------------
  unsigned* hashp = s_pool + 3840 + w * 128;
  int wave_u0 = u0 + 64 * w;
  float uqf = 0.f;
  for (int uu = 0; uu < 64; ++uu) {
    if (wave_u0 + uu >= p.N) break;
    int suu = rdlane_i(s0, uu), euu = rdlane_i(e0, uu);
    int Lu = euu - suu;
    int uq = 0;
    if (Lu <= 96) {
      hashp[lane] = 0u; hashp[64 + lane] = 0u;
      asm volatile("s_waitcnt lgkmcnt(0)" ::: "memory");
      for (int b2 = suu; b2 < euu; b2 += 64) {
        int i = b2 + lane;
        bool fresh = false;
        if (i < euu) {
          float2 xy = lp2[i];
          int kx = (int)lrintf(xy.x * 50.0f) + 2048;
          int ky = (int)lrintf(xy.y * 50.0f) + 2048;
          unsigned key = (((unsigned)kx << 12) | (unsigned)ky) + 1u;
          unsigned h = (key * 2654435761u) >> 25;
          while (true) {
            unsigned old = atomicCAS(&hashp[h], 0u, key);
            if (old == 0u) { fresh = true; break; }
            if (old == key) break;
            h = (h + 1) & 127u;
          }
        }
        uq += (int)__popcll(__ballot(fresh));
      }
    } else {
      for (int b2 = suu; b2 < euu; b2 += 64) {
        int i = b2 + lane;
        bool fresh = false;
        if (i < euu) {
          float x = p.loc[2*(size_t)i], y = p.loc[2*(size_t)i+1];
          fresh = true;
          for (int jj = suu; jj < i; ++jj) {
            if (p.loc[2*(size_t)jj] == x && p.loc[2*(size_t)jj+1] == y) { fresh = false; break; }
          }
        }
        uq += (int)__popcll(__ballot(fresh));
      }
    }
    if (lane == uu) uqf = (float)uq;
  }
  __syncthreads();   // pass2 + phaseB complete; acc final

  // ---------------- finalize: per-thread features + MLP1 ----------------
  unsigned hp[64];
  {
    float* a = accf + tid * 15;
    unsigned* au = (unsigned*)a;
    float sh = a[2], sdy = a[3], smo = a[4], sdf = a[5], sdf2 = a[6];
    unsigned cw0 = au[7], cw1 = au[8], cw2 = au[9], cw3 = au[10];
    float tmxv = __uint_as_float(au[11]);
    float tmnv = __uint_as_float(au[12]);
    float sD = a[13], sD2 = a[14];

    float th = sh / Lf, tdy = sdy / Lf, tmo = smo / Lf;
    float varD = (sD2 - sD * sD / Lf) / (Lf - 1.0f);
    float rad  = sqrtf(fmaxf(varD, 0.0f));
    float divy = uqf / Lf;
    float span = (tmxv - tmnv) / 86400.0f;
    float freq = Lf / fmaxf(span, 1.0f);
    float mm   = Lf - 1.0f;
    float dmu  = sdf / mm;
    float dvar = (sdf2 - mm * dmu * dmu) / (mm - 1.0f);
    float reg  = 1.0f / (sqrtf(fmaxf(dvar, 0.0f)) + 1e-6f);

    float act[10];
    act[0] = (float)(cw0 & 1023u) / Lf;
    act[1] = (float)((cw0 >> 10) & 1023u) / Lf;
    act[2] = (float)((cw0 >> 20) & 1023u) / Lf;
    act[3] = (float)(cw1 & 1023u) / Lf;
    act[4] = (float)((cw1 >> 10) & 1023u) / Lf;
    act[5] = (float)((cw1 >> 20) & 1023u) / Lf;
    act[6] = (float)(cw2 & 1023u) / Lf;
    act[7] = (float)((cw2 >> 10) & 1023u) / Lf;
    act[8] = (float)((cw2 >> 20) & 1023u) / Lf;
    act[9] = (float)(cw3 & 1023u) / Lf;

    #pragma unroll
    for (int j = 0; j < 16; ++j)
      hp[j] = pack_hl(fmaxf(s_b1[j] + hx * s_w1[j] + hy * s_w1[16 + j], 0.f));
    #pragma unroll
    for (int j = 0; j < 16; ++j)
      hp[16 + j] = pack_hl(fmaxf(s_b1[16 + j] + th * s_w1[32 + j] + tdy * s_w1[48 + j]
                                 + tmo * s_w1[64 + j], 0.f));
    #pragma unroll
    for (int j = 0; j < 16; ++j) {
      float aa = s_b1[32 + j];
      #pragma unroll
      for (int b = 0; b < 10; ++b) aa = fmaf(act[b], s_w1[80 + b * 16 + j], aa);
      hp[32 + j] = pack_hl(fmaxf(aa, 0.f));
    }
    #pragma unroll
    for (int j = 0; j < 16; ++j)
      hp[48 + j] = pack_hl(fmaxf(s_b1[48 + j] + rad * s_w1[240 + j] + divy * s_w1[256 + j]
                                 + freq * s_w1[272 + j] + reg * s_w1[288 + j], 0.f));
  }
  __syncthreads();   // acc/hash dead; pool becomes feat space

  // ---------------- 3-layer MFMA chain, 4 batches of 16 users ----------------
  unsigned* fw = s_pool + w * 1088;
  int lr = lane & 15, lg = lane >> 4;
  const unsigned* arow = fw + lr * 68 + (lg << 3);

  for (int b = 0; b < 4; ++b) {
    if (lg == b) {
      unsigned* row = fw + lr * 68;
      #pragma unroll
      for (int j = 0; j < 16; ++j)
        *(uint4*)(row + j * 4) = make_uint4(hp[4*j], hp[4*j+1], hp[4*j+2], hp[4*j+3]);
    }
    asm volatile("s_waitcnt lgkmcnt(0)" ::: "memory");

    bf16x8 ah[2], al[2];
    lda(arow,      ah[0], al[0]);
    lda(arow + 32, ah[1], al[1]);
    f32x4 acc[4];
    #pragma unroll
    for (int nt = 0; nt < 4; ++nt) {
      float bv = s_b2[nt * 16 + lr];
      acc[nt] = (f32x4){bv, bv, bv, bv};
      int ks = nt >> 1;
      bf16x8 bw = ldb(s_wfrag, nt, lane);
      acc[nt] = mfma16(ah[ks], bw, acc[nt]);
      acc[nt] = mfma16(al[ks], bw, acc[nt]);
    }
    #pragma unroll
    for (int nt = 0; nt < 4; ++nt)
      #pragma unroll
      for (int r = 0; r < 4; ++r)
        fw[(lg * 4 + r) * 68 + nt * 16 + lr] = pack_hl(acc[nt][r]);
    asm volatile("s_waitcnt lgkmcnt(0)" ::: "memory");

    lda(arow,      ah[0], al[0]);
    lda(arow + 32, ah[1], al[1]);
    #pragma unroll
    for (int nt = 0; nt < 4; ++nt) {
      float bv = s_bc1[nt * 16 + lr];
      acc[nt] = (f32x4){bv, bv, bv, bv};
      #pragma unroll
      for (int ks = 0; ks < 2; ++ks) {
        bf16x8 bw = ldb(s_wfrag, 4 + nt * 2 + ks, lane);
        acc[nt] = mfma16(ah[ks], bw, acc[nt]);
        acc[nt] = mfma16(al[ks], bw, acc[nt]);
      }
    }
    #pragma unroll
    for (int nt = 0; nt < 4; ++nt)
      #pragma unroll
      for (int r = 0; r < 4; ++r)
        fw[(lg * 4 + r) * 68 + nt * 16 + lr] = pack_hl(fmaxf(acc[nt][r], 0.f));
    asm volatile("s_waitcnt lgkmcnt(0)" ::: "memory");

    lda(arow,      ah[0], al[0]);
    lda(arow + 32, ah[1], al[1]);
    #pragma unroll
    for (int nt = 0; nt < 4; ++nt) {
      float bv = s_bc2[nt * 16 + lr];
      acc[nt] = (f32x4){bv, bv, bv, bv};
      #pragma unroll
      for (int ks = 0; ks < 2; ++ks) {
        bf16x8 bw = ldb(s_wfrag, 12 + nt * 2 + ks, lane);
        acc[nt] = mfma16(ah[ks], bw, acc[nt]);
        acc[nt] = mfma16(al[ks], bw, acc[nt]);
      }
    }
    #pragma unroll
    for (int nt = 0; nt < 4; ++nt)
      #pragma unroll
      for (int r = 0; r < 4; ++r) {
        int uo = wave_u0 + 16 * b + lg * 4 + r;
        if (uo < p.N) p.out[(size_t)uo * 64 + nt * 16 + lr] = acc[nt][r];
      }
    asm volatile("s_waitcnt lgkmcnt(0)" ::: "memory");
  }
}

extern "C" void kernel_launch(void* const* d_in, const int* in_sizes, int n_in,
                              void* d_out, int out_size, void* d_ws, size_t ws_size,
                              hipStream_t stream) {
  Params p;
  p.loc = (const float*)d_in[0];
  p.ts  = (const float*)d_in[1];
  p.cat = (const int*)d_in[2];
  p.seg = (const int*)d_in[3];
  p.wl1 = (const float*)d_in[5];  p.bl1 = (const float*)d_in[6];
  p.wl2 = (const float*)d_in[7];  p.bl2 = (const float*)d_in[8];
  p.wt1 = (const float*)d_in[9];  p.bt1 = (const float*)d_in[10];
  p.wt2 = (const float*)d_in[11]; p.bt2 = (const float*)d_in[12];
  p.wa1 = (const float*)d_in[13]; p.ba1 = (const float*)d_in[14];
  p.wa2 = (const float*)d_in[15]; p.ba2 = (const float*)d_in[16];
  p.wm1 = (const float*)d_in[17]; p.bm1 = (const float*)d_in[18];
  p.wm2 = (const float*)d_in[19]; p.bm2 = (const float*)d_in[20];
  p.wc1 = (const float*)d_in[21]; p.bc1 = (const float*)d_in[22];
  p.wc2 = (const float*)d_in[23]; p.bc2 = (const float*)d_in[24];
  p.out = (float*)d_out;
  p.N = out_size / 64;
  p.T = in_sizes[1];
  int* off = (int*)d_ws;
  p.off = off;
  p.use_off = (ws_size >= (size_t)(p.N + 1) * sizeof(int)) ? 1 : 0;

  if (p.use_off) {
    offsets_kernel<<<(p.T + 255)/256, 256, 0, stream>>>(p.seg, off, p.T, p.N);
  }
  int nblocks = (p.N + 255) / 256;
  mobility_kernel<<<nblocks, 256, 0, stream>>>(p);
}

// Round 7
// 221.431 us; speedup vs baseline: 1.1852x; 1.1852x over previous
//
#include <hip/hip_runtime.h>

typedef short bf16x8 __attribute__((ext_vector_type(8)));
typedef float f32x4 __attribute__((ext_vector_type(4)));

struct Params {
  const float* loc; const float* ts; const int* cat; const int* seg;
  const int* off;
  const float *wl1,*bl1,*wl2,*bl2;
  const float *wt1,*bt1,*wt2,*bt2;
  const float *wa1,*ba1,*wa2,*ba2;
  const float *wm1,*bm1,*wm2,*bm2;
  const float *wc1,*bc1,*wc2,*bc2;
  float* out;
  int N, T, use_off;
};

__global__ void offsets_kernel(const int* __restrict__ seg, int* __restrict__ off, int T, int N) {
  int i = blockIdx.x * blockDim.x + threadIdx.x;
  if (i == 0) off[N] = T;
  if (i < T) {
    int s = seg[i];
    if (i == 0 || seg[i-1] != s) off[s] = i;
  }
}

__device__ __forceinline__ int rdlane_i(int v, int l) {
  return __builtin_amdgcn_readlane(v, l);
}

__device__ __forceinline__ unsigned bf16r(float f) {
  unsigned x = __float_as_uint(f);
  return (x + 0x7fffu + ((x >> 16) & 1u)) >> 16;
}
__device__ __forceinline__ unsigned pack_hl(float f) {
  unsigned hi = bf16r(f);
  float r = f - __uint_as_float(hi << 16);
  return (hi << 16) | bf16r(r);
}

__device__ __forceinline__ float exact_fmod(float a, float m, float rcp_m) {
  float q = floorf(a * rcp_m);
  float r = fmaf(q, -m, a);
  if (r < 0.0f) r += m;
  else if (r >= m) r -= m;
  return r;
}

__device__ __forceinline__ f32x4 mfma16(bf16x8 a, bf16x8 b, f32x4 c) {
  return __builtin_amdgcn_mfma_f32_16x16x32_bf16(a, b, c, 0, 0, 0);
}

__device__ __forceinline__ void lda(const unsigned* rp, bf16x8& hi, bf16x8& lo) {
  uint4 w0 = *(const uint4*)rp;
  uint4 w1 = *(const uint4*)(rp + 4);
  union { unsigned u[4]; bf16x8 v; } H, L;
  H.u[0] = __builtin_amdgcn_perm(w0.y, w0.x, 0x07060302u);
  H.u[1] = __builtin_amdgcn_perm(w0.w, w0.z, 0x07060302u);
  H.u[2] = __builtin_amdgcn_perm(w1.y, w1.x, 0x07060302u);
  H.u[3] = __builtin_amdgcn_perm(w1.w, w1.z, 0x07060302u);
  L.u[0] = __builtin_amdgcn_perm(w0.y, w0.x, 0x05040100u);
  L.u[1] = __builtin_amdgcn_perm(w0.w, w0.z, 0x05040100u);
  L.u[2] = __builtin_amdgcn_perm(w1.y, w1.x, 0x05040100u);
  L.u[3] = __builtin_amdgcn_perm(w1.w, w1.z, 0x05040100u);
  hi = H.v; lo = L.v;
}

__device__ __forceinline__ bf16x8 ldb(const unsigned* wf, int fi, int lane) {
  union { uint4 q; bf16x8 v; } U;
  U.q = *(const uint4*)(wf + ((fi * 64 + lane) << 2));
  return U.v;
}

__device__ __forceinline__ float bdval(const Params& p, int k, int col) {
  if ((k >> 4) != (col >> 4)) return 0.f;
  int b = col >> 4;
  const float* W2 = (b & 2) ? ((b & 1) ? p.wm2 : p.wa2) : ((b & 1) ? p.wt2 : p.wl2);
  return W2[(k & 15) * 16 + (col & 15)];
}

__device__ __forceinline__ int lower_bound(const int* seg, int T, int v) {
  int lo = 0, hi = T;
  while (lo < hi) { int m = (lo + hi) >> 1; if (seg[m] < v) lo = m + 1; else hi = m; }
  return lo;
}

// ---------------- unsegmented wave64 inclusive prefix scans (DPP) ----------------
__device__ __forceinline__ float pscan_f(float v) {
  v += __int_as_float(__builtin_amdgcn_update_dpp(0, __float_as_int(v), 0x111, 0xf, 0xf, true));
  v += __int_as_float(__builtin_amdgcn_update_dpp(0, __float_as_int(v), 0x112, 0xf, 0xf, true));
  v += __int_as_float(__builtin_amdgcn_update_dpp(0, __float_as_int(v), 0x114, 0xf, 0xf, true));
  v += __int_as_float(__builtin_amdgcn_update_dpp(0, __float_as_int(v), 0x118, 0xf, 0xf, true));
  v += __int_as_float(__builtin_amdgcn_update_dpp(0, __float_as_int(v), 0x142, 0xa, 0xf, true));
  v += __int_as_float(__builtin_amdgcn_update_dpp(0, __float_as_int(v), 0x143, 0xc, 0xf, true));
  return v;
}
__device__ __forceinline__ unsigned pscan_u(unsigned v) {
  int x = (int)v;
  x += __builtin_amdgcn_update_dpp(0, x, 0x111, 0xf, 0xf, true);
  x += __builtin_amdgcn_update_dpp(0, x, 0x112, 0xf, 0xf, true);
  x += __builtin_amdgcn_update_dpp(0, x, 0x114, 0xf, 0xf, true);
  x += __builtin_amdgcn_update_dpp(0, x, 0x118, 0xf, 0xf, true);
  x += __builtin_amdgcn_update_dpp(0, x, 0x142, 0xa, 0xf, true);
  x += __builtin_amdgcn_update_dpp(0, x, 0x143, 0xc, 0xf, true);
  return (unsigned)x;
}
// wave-wide shift: lane i <- lane i-1 (lane 0 -> 0)
__device__ __forceinline__ unsigned wshr1_u(unsigned v) {
  return (unsigned)__builtin_amdgcn_update_dpp(0, (int)v, 0x138, 0xf, 0xf, true);
}
__device__ __forceinline__ float wshr1_f(float v) {
  return __int_as_float(__builtin_amdgcn_update_dpp(0, __float_as_int(v), 0x138, 0xf, 0xf, true));
}

// ---------------- segmented max/min scans (for tmx/tmn only) ----------------
#define DPPI0(v, ctrl, rm) __builtin_amdgcn_update_dpp(0, (v), ctrl, rm, 0xf, true)
#define DPPFO(v, o, ctrl, rm) __int_as_float(__builtin_amdgcn_update_dpp(__float_as_int(o), __float_as_int(v), ctrl, rm, 0xf, false))

struct Conds { bool c1,c2,c4,c8,cA,cB; };
__device__ __forceinline__ Conds mkconds(int lane, int dist) {
  Conds C;
  C.c1 = dist >= 1; C.c2 = dist >= 2; C.c4 = dist >= 4; C.c8 = dist >= 8;
  C.cA = ((lane & 15) + 1) <= dist;
  C.cB = (lane - 31) <= dist;
  return C;
}
__device__ __forceinline__ int smaxi(int v) {
  int i;
  i = DPPI0(v,0x111,0xf); v = max(v,i);
  i = DPPI0(v,0x112,0xf); v = max(v,i);
  i = DPPI0(v,0x114,0xf); v = max(v,i);
  i = DPPI0(v,0x118,0xf); v = max(v,i);
  i = DPPI0(v,0x142,0xa); v = max(v,i);
  i = DPPI0(v,0x143,0xc); v = max(v,i);
  return v;
}
__device__ __forceinline__ float smaxf(float v, const Conds& C) {
  const float NI = __int_as_float(0xff800000u);
  float i;
  i = DPPFO(v,NI,0x111,0xf); v = C.c1 ? fmaxf(v,i) : v;
  i = DPPFO(v,NI,0x112,0xf); v = C.c2 ? fmaxf(v,i) : v;
  i = DPPFO(v,NI,0x114,0xf); v = C.c4 ? fmaxf(v,i) : v;
  i = DPPFO(v,NI,0x118,0xf); v = C.c8 ? fmaxf(v,i) : v;
  i = DPPFO(v,NI,0x142,0xa); v = C.cA ? fmaxf(v,i) : v;
  i = DPPFO(v,NI,0x143,0xc); v = C.cB ? fmaxf(v,i) : v;
  return v;
}
__device__ __forceinline__ float sminf(float v, const Conds& C) {
  const float PI_ = __int_as_float(0x7f800000u);
  float i;
  i = DPPFO(v,PI_,0x111,0xf); v = C.c1 ? fminf(v,i) : v;
  i = DPPFO(v,PI_,0x112,0xf); v = C.c2 ? fminf(v,i) : v;
  i = DPPFO(v,PI_,0x114,0xf); v = C.c4 ? fminf(v,i) : v;
  i = DPPFO(v,PI_,0x118,0xf); v = C.c8 ? fminf(v,i) : v;
  i = DPPFO(v,PI_,0x142,0xa); v = C.cA ? fminf(v,i) : v;
  i = DPPFO(v,PI_,0x143,0xc); v = C.cB ? fminf(v,i) : v;
  return v;
}

__global__ __launch_bounds__(256, 4) void mobility_kernel(Params p) {
  __shared__ __align__(16) unsigned s_wfrag[5120];   // 20480 B
  __shared__ __align__(16) unsigned s_pool[4352];    // 17408 B: per-wave featT (hash aliases)
  __shared__ float s_w1[304];
  __shared__ float s_b1[64], s_b2[64], s_bc1[64], s_bc2[64];

  int tid = threadIdx.x;
  int lane = tid & 63, w = tid >> 6;

  // ---- stage W fragments (bf16) ----
  for (int m = tid; m < 5120; m += 256) {
    int fi = m >> 8;
    int ln = (m >> 2) & 63;
    int j2 = m & 3;
    int layer, nt, ks;
    if (fi < 4)       { layer = 0; nt = fi;             ks = nt >> 1; }
    else if (fi < 12) { layer = 1; nt = (fi - 4) >> 1;  ks = (fi - 4) & 1; }
    else              { layer = 2; nt = (fi - 12) >> 1; ks = (fi - 12) & 1; }
    int col = nt * 16 + (ln & 15);
    int k0  = ks * 32 + ((ln >> 4) << 3) + (j2 << 1);
    float v0, v1;
    if (layer == 0) { v0 = bdval(p, k0, col); v1 = bdval(p, k0 + 1, col); }
    else {
      const float* W = (layer == 1) ? p.wc1 : p.wc2;
      v0 = W[k0 * 64 + col]; v1 = W[(k0 + 1) * 64 + col];
    }
    s_wfrag[m] = (bf16r(v1) << 16) | bf16r(v0);
  }
  if (tid < 32)  s_w1[tid]       = p.wl1[tid];
  if (tid < 48)  s_w1[32 + tid]  = p.wt1[tid];
  if (tid < 160) s_w1[80 + tid]  = p.wa1[tid];
  if (tid < 64)  s_w1[240 + tid] = p.wm1[tid];
  if (tid < 16) {
    s_b1[tid]    = p.bl1[tid]; s_b1[16+tid] = p.bt1[tid];
    s_b1[32+tid] = p.ba1[tid]; s_b1[48+tid] = p.bm1[tid];
    s_b2[tid]    = p.bl2[tid]; s_b2[16+tid] = p.bt2[tid];
    s_b2[32+tid] = p.ba2[tid]; s_b2[48+tid] = p.bm2[tid];
  }
  if (tid < 64) { s_bc1[tid] = p.bc1[tid]; s_bc2[tid] = p.bc2[tid]; }
  __syncthreads();

  int u0 = blockIdx.x * 256;
  int wave_u0 = u0 + 64 * w;
  int myu = wave_u0 + lane;
  int myuc = min(myu, p.N - 1);
  int s0, e0;
  if (p.use_off) {
    s0 = p.off[myuc]; e0 = p.off[myuc + 1];
  } else {
    s0 = lower_bound(p.seg, p.T, myuc);
    e0 = lower_bound(p.seg, p.T, myuc + 1);
  }
  int W0 = rdlane_i(s0, 0);
  int W1 = rdlane_i(e0, 63);
  float Lf = (float)(e0 - s0);

  const float2* lp2 = (const float2*)p.loc;
  const float NINF = __int_as_float(0xff800000u);
  const float PINF = __int_as_float(0x7f800000u);

  // owning-lane accumulators (user myuc)
  int aKx = 0, aKy = 0, aXX = 0;
  float aH = 0.f, aDY = 0.f, aT = 0.f, aDF2 = 0.f, aD = 0.f;
  unsigned aH0 = 0u, aH1 = 0u, aH2 = 0u;
  float aTMX = NINF, aTMN = PINF;

  // ---------------- pass 1: coalesced stats, prefix-diff to owning lanes ----------------
  for (int base = W0; base < W1; base += 64) {
    int e = base + lane;
    bool on = e < W1;
    int ec = on ? e : (W1 - 1);
    int sv = p.seg[ec];
    int sp = (ec > 0) ? p.seg[ec - 1] : -1;
    int sn = (ec + 1 < p.T) ? p.seg[ec + 1] : -2;
    float t  = p.ts[ec];
    float tnx = (ec + 1 < p.T) ? p.ts[ec + 1] : 0.f;
    int c = p.cat[ec];
    float2 xy = lp2[ec];

    unsigned vXY = 0u, vXX = 0u, vH0 = 0u, vH1 = 0u, vH2 = 0u;
    float vH = 0.f, vDY = 0.f, vT = 0.f, vDF2 = 0.f;
    float vtmx = NINF, vtmn = PINF;
    if (on) {
      int kx = (int)lrintf(xy.x * 50.0f);
      int ky = (int)lrintf(xy.y * 50.0f);
      vXY = ((unsigned)(kx + 512) << 16) | (unsigned)(ky + 512);
      vXX = (unsigned)(kx * kx + ky * ky);
      float hr = exact_fmod(t, 86400.0f, 1.0f / 86400.0f);
      vH = hr * (1.0f / 3600.0f);
      float ud = (float)((double)t * (1.0 / 86400.0));
      vDY = exact_fmod(ud, 7.0f, 1.0f / 7.0f);
      vT = t;
      unsigned bit = 1u << ((c & 3) * 8);
      int wsel = c >> 2;
      vH0 = (wsel == 0) ? bit : 0u;
      vH1 = (wsel == 1) ? bit : 0u;
      vH2 = (wsel == 2) ? bit : 0u;
      if (sn == sv) { float dt = tnx - t; vDF2 = dt * dt; }
      vtmx = t; vtmn = t;
    }

    unsigned pXY = pscan_u(vXY), pXX = pscan_u(vXX);
    unsigned pH0 = pscan_u(vH0), pH1 = pscan_u(vH1), pH2 = pscan_u(vH2);
    float pH = pscan_f(vH), pDY = pscan_f(vDY), pT = pscan_f(vT), pDF2 = pscan_f(vDF2);

    bool head = (!on) || (sp != sv);
    int j = smaxi(head ? lane : 0);
    Conds C = mkconds(lane, lane - j);
    float pTMX = smaxf(vtmx, C);
    float pTMN = sminf(vtmn, C);

    // owning-lane pulls
    int lo = min(max(s0 - base, 0), 64);
    int hi = min(max(e0 - base, 0), 64);
    int idx = max(hi - 1, 0);
    unsigned PXY = (unsigned)__shfl((int)pXY, idx);
    unsigned PXX = (unsigned)__shfl((int)pXX, idx);
    unsigned PH0 = (unsigned)__shfl((int)pH0, idx);
    unsigned PH1 = (unsigned)__shfl((int)pH1, idx);
    unsigned PH2 = (unsigned)__shfl((int)pH2, idx);
    float PH = __shfl(pH, idx), PDY = __shfl(pDY, idx);
    float PT = __shfl(pT, idx), PDF2 = __shfl(pDF2, idx);
    float PTMX = __shfl(pTMX, idx), PTMN = __shfl(pTMN, idx);
    // neighbor's hi-pull == my lo-pull (users contiguous)
    unsigned LXY = wshr1_u(PXY), LXX = wshr1_u(PXX);
    unsigned LH0 = wshr1_u(PH0), LH1 = wshr1_u(PH1), LH2 = wshr1_u(PH2);
    float LH = wshr1_f(PH), LDY = wshr1_f(PDY);
    float LT = wshr1_f(PT), LDF2 = wshr1_f(PDF2);

    if (hi > lo) {
      int cnt = hi - lo;
      bool ul_ = lo > 0;
      unsigned dXY = PXY - (ul_ ? LXY : 0u);
      aKx += (int)(dXY >> 16) - (cnt << 9);
      aKy += (int)(dXY & 0xffffu) - (cnt << 9);
      aXX += (int)(PXX - (ul_ ? LXX : 0u));
      aH0 += PH0 - (ul_ ? LH0 : 0u);
      aH1 += PH1 - (ul_ ? LH1 : 0u);
      aH2 += PH2 - (ul_ ? LH2 : 0u);
      aH   += PH   - (ul_ ? LH   : 0.f);
      aDY  += PDY  - (ul_ ? LDY  : 0.f);
      aT   += PT   - (ul_ ? LT   : 0.f);
      aDF2 += PDF2 - (ul_ ? LDF2 : 0.f);
      aTMX = fmaxf(aTMX, PTMX);
      aTMN = fminf(aTMN, PTMN);
    }
  }

  float sx = (float)aKx / 50.0f, sy = (float)aKy / 50.0f;
  float hx = sx / Lf, hy = sy / Lf;

  // ---------------- pass 2: sum of distances ----------------
  for (int base = W0; base < W1; base += 64) {
    int e = base + lane;
    bool on = e < W1;
    int ec = on ? e : (W1 - 1);
    int sv = p.seg[ec];
    float2 xy = lp2[ec];
    int ul = sv - wave_u0;
    float hxu = __shfl(hx, ul), hyu = __shfl(hy, ul);
    float d = 0.f;
    if (on) {
      float dx = xy.x - hxu, dyv = xy.y - hyu;
      d = sqrtf(fmaf(dx, dx, dyv * dyv));
    }
    float pD = pscan_f(d);
    int lo = min(max(s0 - base, 0), 64);
    int hi = min(max(e0 - base, 0), 64);
    int idx = max(hi - 1, 0);
    float PD = __shfl(pD, idx);
    float LD = wshr1_f(PD);
    if (hi > lo) aD += PD - ((lo > 0) ? LD : 0.f);
  }

  // ---------------- phase B: unique locations (wave-per-user LDS hash) ----------------
  unsigned* fw = s_pool + w * 1088;
  unsigned* hashp = fw;   // alias featT (used before MFMA phase)
  float uqf = 0.f;
  for (int uu = 0; uu < 64; ++uu) {
    if (wave_u0 + uu >= p.N) break;
    int suu = rdlane_i(s0, uu), euu = rdlane_i(e0, uu);
    int Lu = euu - suu;
    int uq = 0;
    if (Lu <= 96) {
      hashp[lane] = 0u; hashp[64 + lane] = 0u;
      asm volatile("s_waitcnt lgkmcnt(0)" ::: "memory");
      for (int b2 = suu; b2 < euu; b2 += 64) {
        int i = b2 + lane;
        bool fresh = false;
        if (i < euu) {
          float2 xy = lp2[i];
          int kx = (int)lrintf(xy.x * 50.0f) + 2048;
          int ky = (int)lrintf(xy.y * 50.0f) + 2048;
          unsigned key = (((unsigned)kx << 12) | (unsigned)ky) + 1u;
          unsigned h = (key * 2654435761u) >> 25;
          while (true) {
            unsigned old = atomicCAS(&hashp[h], 0u, key);
            if (old == 0u) { fresh = true; break; }
            if (old == key) break;
            h = (h + 1) & 127u;
          }
        }
        uq += (int)__popcll(__ballot(fresh));
      }
    } else {
      for (int b2 = suu; b2 < euu; b2 += 64) {
        int i = b2 + lane;
        bool fresh = false;
        if (i < euu) {
          float x = p.loc[2*(size_t)i], y = p.loc[2*(size_t)i+1];
          fresh = true;
          for (int jj = suu; jj < i; ++jj) {
            if (p.loc[2*(size_t)jj] == x && p.loc[2*(size_t)jj+1] == y) { fresh = false; break; }
          }
        }
        uq += (int)__popcll(__ballot(fresh));
      }
    }
    if (lane == uu) uqf = (float)uq;
  }
  asm volatile("s_waitcnt lgkmcnt(0)" ::: "memory");

  // ---------------- finalize: per-lane features + MLP1 ----------------
  unsigned hp[64];
  {
    float sxx = (float)aXX / 2500.0f;
    float sD = aD;
    float sD2 = sxx - (sx * sx + sy * sy) / Lf;

    float th = aH / Lf, tdy = aDY / Lf;
    float tmo = (aT * (1.0f / 2592000.0f)) / Lf;
    float varD = (sD2 - sD * sD / Lf) / (Lf - 1.0f);
    float rad  = sqrtf(fmaxf(varD, 0.0f));
    float divy = uqf / Lf;
    float span = (aTMX - aTMN) / 86400.0f;
    float freq = Lf / fmaxf(span, 1.0f);
    float tfirst = p.ts[s0];
    float tlast  = p.ts[e0 - 1];
    float sdf = tlast - tfirst;
    float mm   = Lf - 1.0f;
    float dmu  = sdf / mm;
    float dvar = (aDF2 - mm * dmu * dmu) / (mm - 1.0f);
    float reg  = 1.0f / (sqrtf(fmaxf(dvar, 0.0f)) + 1e-6f);

    float act[10];
    act[0] = (float)(aH0 & 255u) / Lf;
    act[1] = (float)((aH0 >> 8) & 255u) / Lf;
    act[2] = (float)((aH0 >> 16) & 255u) / Lf;
    act[3] = (float)((aH0 >> 24) & 255u) / Lf;
    act[4] = (float)(aH1 & 255u) / Lf;
    act[5] = (float)((aH1 >> 8) & 255u) / Lf;
    act[6] = (float)((aH1 >> 16) & 255u) / Lf;
    act[7] = (float)((aH1 >> 24) & 255u) / Lf;
    act[8] = (float)(aH2 & 255u) / Lf;
    act[9] = (float)((aH2 >> 8) & 255u) / Lf;

    #pragma unroll
    for (int j = 0; j < 16; ++j)
      hp[j] = pack_hl(fmaxf(s_b1[j] + hx * s_w1[j] + hy * s_w1[16 + j], 0.f));
    #pragma unroll
    for (int j = 0; j < 16; ++j)
      hp[16 + j] = pack_hl(fmaxf(s_b1[16 + j] + th * s_w1[32 + j] + tdy * s_w1[48 + j]
                                 + tmo * s_w1[64 + j], 0.f));
    #pragma unroll
    for (int j = 0; j < 16; ++j) {
      float aa = s_b1[32 + j];
      #pragma unroll
      for (int b = 0; b < 10; ++b) aa = fmaf(act[b], s_w1[80 + b * 16 + j], aa);
      hp[32 + j] = pack_hl(fmaxf(aa, 0.f));
    }
    #pragma unroll
    for (int j = 0; j < 16; ++j)
      hp[48 + j] = pack_hl(fmaxf(s_b1[48 + j] + rad * s_w1[240 + j] + divy * s_w1[256 + j]
                                 + freq * s_w1[272 + j] + reg * s_w1[288 + j], 0.f));
  }

  // ---------------- 3-layer MFMA chain, 4 batches of 16 users ----------------
  int lr = lane & 15, lg = lane >> 4;
  const unsigned* arow = fw + lr * 68 + (lg << 3);

  for (int b = 0; b < 4; ++b) {
    if (lg == b) {
      unsigned* row = fw + lr * 68;
      #pragma unroll
      for (int j = 0; j < 16; ++j)
        *(uint4*)(row + j * 4) = make_uint4(hp[4*j], hp[4*j+1], hp[4*j+2], hp[4*j+3]);
    }
    asm volatile("s_waitcnt lgkmcnt(0)" ::: "memory");

    bf16x8 ah[2], al[2];
    lda(arow,      ah[0], al[0]);
    lda(arow + 32, ah[1], al[1]);
    f32x4 acc[4];
    #pragma unroll
    for (int nt = 0; nt < 4; ++nt) {
      float bv = s_b2[nt * 16 + lr];
      acc[nt] = (f32x4){bv, bv, bv, bv};
      int ks = nt >> 1;
      bf16x8 bw = ldb(s_wfrag, nt, lane);
      acc[nt] = mfma16(ah[ks], bw, acc[nt]);
      acc[nt] = mfma16(al[ks], bw, acc[nt]);
    }
    #pragma unroll
    for (int nt = 0; nt < 4; ++nt)
      #pragma unroll
      for (int r = 0; r < 4; ++r)
        fw[(lg * 4 + r) * 68 + nt * 16 + lr] = pack_hl(acc[nt][r]);
    asm volatile("s_waitcnt lgkmcnt(0)" ::: "memory");

    lda(arow,      ah[0], al[0]);
    lda(arow + 32, ah[1], al[1]);
    #pragma unroll
    for (int nt = 0; nt < 4; ++nt) {
      float bv = s_bc1[nt * 16 + lr];
      acc[nt] = (f32x4){bv, bv, bv, bv};
      #pragma unroll
      for (int ks = 0; ks < 2; ++ks) {
        bf16x8 bw = ldb(s_wfrag, 4 + nt * 2 + ks, lane);
        acc[nt] = mfma16(ah[ks], bw, acc[nt]);
        acc[nt] = mfma16(al[ks], bw, acc[nt]);
      }
    }
    #pragma unroll
    for (int nt = 0; nt < 4; ++nt)
      #pragma unroll
      for (int r = 0; r < 4; ++r)
        fw[(lg * 4 + r) * 68 + nt * 16 + lr] = pack_hl(fmaxf(acc[nt][r], 0.f));
    asm volatile("s_waitcnt lgkmcnt(0)" ::: "memory");

    lda(arow,      ah[0], al[0]);
    lda(arow + 32, ah[1], al[1]);
    #pragma unroll
    for (int nt = 0; nt < 4; ++nt) {
      float bv = s_bc2[nt * 16 + lr];
      acc[nt] = (f32x4){bv, bv, bv, bv};
      #pragma unroll
      for (int ks = 0; ks < 2; ++ks) {
        bf16x8 bw = ldb(s_wfrag, 12 + nt * 2 + ks, lane);
        acc[nt] = mfma16(ah[ks], bw, acc[nt]);
        acc[nt] = mfma16(al[ks], bw, acc[nt]);
      }
    }
    #pragma unroll
    for (int nt = 0; nt < 4; ++nt)
      #pragma unroll
      for (int r = 0; r < 4; ++r) {
        int uo = wave_u0 + 16 * b + lg * 4 + r;
        if (uo < p.N) p.out[(size_t)uo * 64 + nt * 16 + lr] = acc[nt][r];
      }
    asm volatile("s_waitcnt lgkmcnt(0)" ::: "memory");
  }
}

extern "C" void kernel_launch(void* const* d_in, const int* in_sizes, int n_in,
                              void* d_out, int out_size, void* d_ws, size_t ws_size,
                              hipStream_t stream) {
  Params p;
  p.loc = (const float*)d_in[0];
  p.ts  = (const float*)d_in[1];
  p.cat = (const int*)d_in[2];
  p.seg = (const int*)d_in[3];
  p.wl1 = (const float*)d_in[5];  p.bl1 = (const float*)d_in[6];
  p.wl2 = (const float*)d_in[7];  p.bl2 = (const float*)d_in[8];
  p.wt1 = (const float*)d_in[9];  p.bt1 = (const float*)d_in[10];
  p.wt2 = (const float*)d_in[11]; p.bt2 = (const float*)d_in[12];
  p.wa1 = (const float*)d_in[13]; p.ba1 = (const float*)d_in[14];
  p.wa2 = (const float*)d_in[15]; p.ba2 = (const float*)d_in[16];
  p.wm1 = (const float*)d_in[17]; p.bm1 = (const float*)d_in[18];
  p.wm2 = (const float*)d_in[19]; p.bm2 = (const float*)d_in[20];
  p.wc1 = (const float*)d_in[21]; p.bc1 = (const float*)d_in[22];
  p.wc2 = (const float*)d_in[23]; p.bc2 = (const float*)d_in[24];
  p.out = (float*)d_out;
  p.N = out_size / 64;
  p.T = in_sizes[1];
  int* off = (int*)d_ws;
  p.off = off;
  p.use_off = (ws_size >= (size_t)(p.N + 1) * sizeof(int)) ? 1 : 0;

  if (p.use_off) {
    offsets_kernel<<<(p.T + 255)/256, 256, 0, stream>>>(p.seg, off, p.T, p.N);
  }
  int nblocks = (p.N + 255) / 256;
  mobility_kernel<<<nblocks, 256, 0, stream>>>(p);
}

// Round 9
// 221.350 us; speedup vs baseline: 1.1856x; 1.0004x over previous
//
#include <hip/hip_runtime.h>

typedef short bf16x8 __attribute__((ext_vector_type(8)));
typedef float f32x4 __attribute__((ext_vector_type(4)));

struct Params {
  const float* loc; const float* ts; const int* cat; const int* seg;
  const int* off;
  const float *wl1,*bl1,*wl2,*bl2;
  const float *wt1,*bt1,*wt2,*bt2;
  const float *wa1,*ba1,*wa2,*ba2;
  const float *wm1,*bm1,*wm2,*bm2;
  const float *wc1,*bc1,*wc2,*bc2;
  float* out;
  int N, T, use_off;
};

__global__ void offsets_kernel(const int* __restrict__ seg, int* __restrict__ off, int T, int N) {
  int i = blockIdx.x * blockDim.x + threadIdx.x;
  if (i == 0) off[N] = T;
  if (i < T) {
    int s = seg[i];
    if (i == 0 || seg[i-1] != s) off[s] = i;
  }
}

__device__ __forceinline__ int rdlane_i(int v, int l) {   // UNIFORM l only
  return __builtin_amdgcn_readlane(v, l);
}

__device__ __forceinline__ unsigned bf16r(float f) {
  unsigned x = __float_as_uint(f);
  return (x + 0x7fffu + ((x >> 16) & 1u)) >> 16;
}
__device__ __forceinline__ unsigned pack_hl(float f) {
  unsigned hi = bf16r(f);
  float r = f - __uint_as_float(hi << 16);
  return (hi << 16) | bf16r(r);
}

__device__ __forceinline__ float exact_fmod(float a, float m, float rcp_m) {
  float q = floorf(a * rcp_m);
  float r = fmaf(q, -m, a);
  if (r < 0.0f) r += m;
  else if (r >= m) r -= m;
  return r;
}

__device__ __forceinline__ f32x4 mfma16(bf16x8 a, bf16x8 b, f32x4 c) {
  return __builtin_amdgcn_mfma_f32_16x16x32_bf16(a, b, c, 0, 0, 0);
}

__device__ __forceinline__ void lda(const unsigned* rp, bf16x8& hi, bf16x8& lo) {
  uint4 w0 = *(const uint4*)rp;
  uint4 w1 = *(const uint4*)(rp + 4);
  union { unsigned u[4]; bf16x8 v; } H, L;
  H.u[0] = __builtin_amdgcn_perm(w0.y, w0.x, 0x07060302u);
  H.u[1] = __builtin_amdgcn_perm(w0.w, w0.z, 0x07060302u);
  H.u[2] = __builtin_amdgcn_perm(w1.y, w1.x, 0x07060302u);
  H.u[3] = __builtin_amdgcn_perm(w1.w, w1.z, 0x07060302u);
  L.u[0] = __builtin_amdgcn_perm(w0.y, w0.x, 0x05040100u);
  L.u[1] = __builtin_amdgcn_perm(w0.w, w0.z, 0x05040100u);
  L.u[2] = __builtin_amdgcn_perm(w1.y, w1.x, 0x05040100u);
  L.u[3] = __builtin_amdgcn_perm(w1.w, w1.z, 0x05040100u);
  hi = H.v; lo = L.v;
}

__device__ __forceinline__ bf16x8 ldb(const unsigned* wf, int fi, int lane) {
  union { uint4 q; bf16x8 v; } U;
  U.q = *(const uint4*)(wf + ((fi * 64 + lane) << 2));
  return U.v;
}

__device__ __forceinline__ float bdval(const Params& p, int k, int col) {
  if ((k >> 4) != (col >> 4)) return 0.f;
  int b = col >> 4;
  const float* W2 = (b & 2) ? ((b & 1) ? p.wm2 : p.wa2) : ((b & 1) ? p.wt2 : p.wl2);
  return W2[(k & 15) * 16 + (col & 15)];
}

__device__ __forceinline__ int lower_bound(const int* seg, int T, int v) {
  int lo = 0, hi = T;
  while (lo < hi) { int m = (lo + hi) >> 1; if (seg[m] < v) lo = m + 1; else hi = m; }
  return lo;
}

// ---------------- unsegmented wave64 inclusive prefix scans (DPP) ----------------
__device__ __forceinline__ float pscan_f(float v) {
  v += __int_as_float(__builtin_amdgcn_update_dpp(0, __float_as_int(v), 0x111, 0xf, 0xf, true));
  v += __int_as_float(__builtin_amdgcn_update_dpp(0, __float_as_int(v), 0x112, 0xf, 0xf, true));
  v += __int_as_float(__builtin_amdgcn_update_dpp(0, __float_as_int(v), 0x114, 0xf, 0xf, true));
  v += __int_as_float(__builtin_amdgcn_update_dpp(0, __float_as_int(v), 0x118, 0xf, 0xf, true));
  v += __int_as_float(__builtin_amdgcn_update_dpp(0, __float_as_int(v), 0x142, 0xa, 0xf, true));
  v += __int_as_float(__builtin_amdgcn_update_dpp(0, __float_as_int(v), 0x143, 0xc, 0xf, true));
  return v;
}
__device__ __forceinline__ unsigned pscan_u(unsigned v) {
  int x = (int)v;
  x += __builtin_amdgcn_update_dpp(0, x, 0x111, 0xf, 0xf, true);
  x += __builtin_amdgcn_update_dpp(0, x, 0x112, 0xf, 0xf, true);
  x += __builtin_amdgcn_update_dpp(0, x, 0x114, 0xf, 0xf, true);
  x += __builtin_amdgcn_update_dpp(0, x, 0x118, 0xf, 0xf, true);
  x += __builtin_amdgcn_update_dpp(0, x, 0x142, 0xa, 0xf, true);
  x += __builtin_amdgcn_update_dpp(0, x, 0x143, 0xc, 0xf, true);
  return (unsigned)x;
}
__device__ __forceinline__ unsigned wshr1_u(unsigned v) {
  return (unsigned)__builtin_amdgcn_update_dpp(0, (int)v, 0x138, 0xf, 0xf, true);
}
__device__ __forceinline__ float wshr1_f(float v) {
  return __int_as_float(__builtin_amdgcn_update_dpp(0, __float_as_int(v), 0x138, 0xf, 0xf, true));
}

// ---------------- segmented max/min scans (for tmx/tmn only) ----------------
#define DPPI0(v, ctrl, rm) __builtin_amdgcn_update_dpp(0, (v), ctrl, rm, 0xf, true)
#define DPPFO(v, o, ctrl, rm) __int_as_float(__builtin_amdgcn_update_dpp(__float_as_int(o), __float_as_int(v), ctrl, rm, 0xf, false))

struct Conds { bool c1,c2,c4,c8,cA,cB; };
__device__ __forceinline__ Conds mkconds(int lane, int dist) {
  Conds C;
  C.c1 = dist >= 1; C.c2 = dist >= 2; C.c4 = dist >= 4; C.c8 = dist >= 8;
  C.cA = ((lane & 15) + 1) <= dist;
  C.cB = (lane - 31) <= dist;
  return C;
}
__device__ __forceinline__ int smaxi(int v) {
  int i;
  i = DPPI0(v,0x111,0xf); v = max(v,i);
  i = DPPI0(v,0x112,0xf); v = max(v,i);
  i = DPPI0(v,0x114,0xf); v = max(v,i);
  i = DPPI0(v,0x118,0xf); v = max(v,i);
  i = DPPI0(v,0x142,0xa); v = max(v,i);
  i = DPPI0(v,0x143,0xc); v = max(v,i);
  return v;
}
__device__ __forceinline__ float smaxf(float v, const Conds& C) {
  const float NI = __int_as_float(0xff800000u);
  float i;
  i = DPPFO(v,NI,0x111,0xf); v = C.c1 ? fmaxf(v,i) : v;
  i = DPPFO(v,NI,0x112,0xf); v = C.c2 ? fmaxf(v,i) : v;
  i = DPPFO(v,NI,0x114,0xf); v = C.c4 ? fmaxf(v,i) : v;
  i = DPPFO(v,NI,0x118,0xf); v = C.c8 ? fmaxf(v,i) : v;
  i = DPPFO(v,NI,0x142,0xa); v = C.cA ? fmaxf(v,i) : v;
  i = DPPFO(v,NI,0x143,0xc); v = C.cB ? fmaxf(v,i) : v;
  return v;
}
__device__ __forceinline__ float sminf(float v, const Conds& C) {
  const float PI_ = __int_as_float(0x7f800000u);
  float i;
  i = DPPFO(v,PI_,0x111,0xf); v = C.c1 ? fminf(v,i) : v;
  i = DPPFO(v,PI_,0x112,0xf); v = C.c2 ? fminf(v,i) : v;
  i = DPPFO(v,PI_,0x114,0xf); v = C.c4 ? fminf(v,i) : v;
  i = DPPFO(v,PI_,0x118,0xf); v = C.c8 ? fminf(v,i) : v;
  i = DPPFO(v,PI_,0x142,0xa); v = C.cA ? fminf(v,i) : v;
  i = DPPFO(v,PI_,0x143,0xc); v = C.cB ? fminf(v,i) : v;
  return v;
}

// cacc: 64 users x 16 u32 slots at s_pool[0..1024):
// 0 kx(i32) 1 ky(i32) 2 xx(i32) 3 H(f) 4 DY(f) 5 T(f) 6 DF2(f)
// 7,8,9 hist(u32) 10 tmx(bits,max) 11 tmn(bits,min) 12 D(f) 13 uq(f)
__global__ __launch_bounds__(256, 4) void mobility_kernel(Params p) {
  __shared__ __align__(16) unsigned s_wfrag[5120];   // 20480 B
  __shared__ __align__(16) unsigned s_pool[4352];    // 17408 B: cacc+hash alias featT
  __shared__ float s_w1[304];
  __shared__ float s_b1[64], s_b2[64], s_bc1[64], s_bc2[64];

  int tid = threadIdx.x;
  int lane = tid & 63, w = tid >> 6;

  // ---- stage W fragments (bf16) ----
  for (int m = tid; m < 5120; m += 256) {
    int fi = m >> 8;
    int ln = (m >> 2) & 63;
    int j2 = m & 3;
    int layer, nt, ks;
    if (fi < 4)       { layer = 0; nt = fi;             ks = nt >> 1; }
    else if (fi < 12) { layer = 1; nt = (fi - 4) >> 1;  ks = (fi - 4) & 1; }
    else              { layer = 2; nt = (fi - 12) >> 1; ks = (fi - 12) & 1; }
    int col = nt * 16 + (ln & 15);
    int k0  = ks * 32 + ((ln >> 4) << 3) + (j2 << 1);
    float v0, v1;
    if (layer == 0) { v0 = bdval(p, k0, col); v1 = bdval(p, k0 + 1, col); }
    else {
      const float* W = (layer == 1) ? p.wc1 : p.wc2;
      v0 = W[k0 * 64 + col]; v1 = W[(k0 + 1) * 64 + col];
    }
    s_wfrag[m] = (bf16r(v1) << 16) | bf16r(v0);
  }
  if (tid < 32)  s_w1[tid]       = p.wl1[tid];
  if (tid < 48)  s_w1[32 + tid]  = p.wt1[tid];
  if (tid < 160) s_w1[80 + tid]  = p.wa1[tid];
  if (tid < 64)  s_w1[240 + tid] = p.wm1[tid];
  if (tid < 16) {
    s_b1[tid]    = p.bl1[tid]; s_b1[16+tid] = p.bt1[tid];
    s_b1[32+tid] = p.ba1[tid]; s_b1[48+tid] = p.bm1[tid];
    s_b2[tid]    = p.bl2[tid]; s_b2[16+tid] = p.bt2[tid];
    s_b2[32+tid] = p.ba2[tid]; s_b2[48+tid] = p.bm2[tid];
  }
  if (tid < 64) { s_bc1[tid] = p.bc1[tid]; s_bc2[tid] = p.bc2[tid]; }
  for (int i = tid; i < 1024; i += 256)
    s_pool[i] = ((i & 15) == 11) ? 0x7f800000u : 0u;
  __syncthreads();

  int u0 = blockIdx.x * 64;
  int myu = u0 + lane;                 // same user set for ALL 4 waves
  int myuc = min(myu, p.N - 1);
  int s0, e0;
  if (p.use_off) {
    s0 = p.off[myuc]; e0 = p.off[myuc + 1];
  } else {
    s0 = lower_bound(p.seg, p.T, myuc);
    e0 = lower_bound(p.seg, p.T, myuc + 1);
  }
  int W0 = rdlane_i(s0, 0);
  int W1 = rdlane_i(e0, 63);
  float Lf = (float)(e0 - s0);

  const float2* lp2 = (const float2*)p.loc;
  const float NINF = __int_as_float(0xff800000u);
  const float PINF = __int_as_float(0x7f800000u);

  int aKx = 0, aKy = 0, aXX = 0;
  float aH = 0.f, aDY = 0.f, aT = 0.f, aDF2 = 0.f;
  unsigned aH0 = 0u, aH1 = 0u, aH2 = 0u;
  float aTMX = NINF, aTMN = PINF;

  // ---------------- pass 1: wave-striped tiles, prefix-diff to owners ----------------
  for (int base = W0 + 64 * w; base < W1; base += 256) {
    int e = base + lane;
    bool on = e < W1;
    int ec = on ? e : (W1 - 1);
    int sv = p.seg[ec];
    int sp = (ec > 0) ? p.seg[ec - 1] : -1;
    int sn = (ec + 1 < p.T) ? p.seg[ec + 1] : -2;
    float t  = p.ts[ec];
    float tnx = (ec + 1 < p.T) ? p.ts[ec + 1] : 0.f;
    int c = p.cat[ec];
    float2 xy = lp2[ec];

    unsigned vXY = 0u, vXX = 0u, vH0 = 0u, vH1 = 0u, vH2 = 0u;
    float vH = 0.f, vDY = 0.f, vT = 0.f, vDF2 = 0.f;
    float vtmx = NINF, vtmn = PINF;
    if (on) {
      int kx = (int)lrintf(xy.x * 50.0f);
      int ky = (int)lrintf(xy.y * 50.0f);
      vXY = ((unsigned)(kx + 512) << 16) | (unsigned)(ky + 512);
      vXX = (unsigned)(kx * kx + ky * ky);
      float hr = exact_fmod(t, 86400.0f, 1.0f / 86400.0f);
      vH = hr * (1.0f / 3600.0f);
      float ud = (float)((double)t * (1.0 / 86400.0));
      vDY = exact_fmod(ud, 7.0f, 1.0f / 7.0f);
      vT = t;
      unsigned bit = 1u << ((c & 3) * 8);
      int wsel = c >> 2;
      vH0 = (wsel == 0) ? bit : 0u;
      vH1 = (wsel == 1) ? bit : 0u;
      vH2 = (wsel == 2) ? bit : 0u;
      if (sn == sv) { float dt = tnx - t; vDF2 = dt * dt; }
      vtmx = t; vtmn = t;
    }

    unsigned pXY = pscan_u(vXY), pXX = pscan_u(vXX);
    unsigned pH0 = pscan_u(vH0), pH1 = pscan_u(vH1), pH2 = pscan_u(vH2);
    float pH = pscan_f(vH), pDY = pscan_f(vDY), pT = pscan_f(vT), pDF2 = pscan_f(vDF2);

    bool head = (!on) || (sp != sv);
    int j = smaxi(head ? lane : 0);
    Conds C = mkconds(lane, lane - j);
    float pTMX = smaxf(vtmx, C);
    float pTMN = sminf(vtmn, C);

    int lo = min(max(s0 - base, 0), 64);
    int hi = min(max(e0 - base, 0), 64);
    int idx = max(hi - 1, 0);
    unsigned PXY = (unsigned)__shfl((int)pXY, idx);
    unsigned PXX = (unsigned)__shfl((int)pXX, idx);
    unsigned PH0 = (unsigned)__shfl((int)pH0, idx);
    unsigned PH1 = (unsigned)__shfl((int)pH1, idx);
    unsigned PH2 = (unsigned)__shfl((int)pH2, idx);
    float PH = __shfl(pH, idx), PDY = __shfl(pDY, idx);
    float PT = __shfl(pT, idx), PDF2 = __shfl(pDF2, idx);
    float PTMX = __shfl(pTMX, idx), PTMN = __shfl(pTMN, idx);
    unsigned LXY = wshr1_u(PXY), LXX = wshr1_u(PXX);
    unsigned LH0 = wshr1_u(PH0), LH1 = wshr1_u(PH1), LH2 = wshr1_u(PH2);
    float LH = wshr1_f(PH), LDY = wshr1_f(PDY);
    float LT = wshr1_f(PT), LDF2 = wshr1_f(PDF2);

    if (hi > lo) {
      int cnt = hi - lo;
      bool ul_ = lo > 0;
      unsigned dXY = PXY - (ul_ ? LXY : 0u);
      aKx += (int)(dXY >> 16) - (cnt << 9);
      aKy += (int)(dXY & 0xffffu) - (cnt << 9);
      aXX += (int)(PXX - (ul_ ? LXX : 0u));
      aH0 += PH0 - (ul_ ? LH0 : 0u);
      aH1 += PH1 - (ul_ ? LH1 : 0u);
      aH2 += PH2 - (ul_ ? LH2 : 0u);
      aH   += PH   - (ul_ ? LH   : 0.f);
      aDY  += PDY  - (ul_ ? LDY  : 0.f);
      aT   += PT   - (ul_ ? LT   : 0.f);
      aDF2 += PDF2 - (ul_ ? LDF2 : 0.f);
      aTMX = fmaxf(aTMX, PTMX);
      aTMN = fminf(aTMN, PTMN);
    }
  }

  // ---------------- combine pass-1 partials across waves ----------------
  {
    int* ci = (int*)s_pool;
    float* cf = (float*)s_pool;
    int ro = lane * 16;
    atomicAdd(&ci[ro + 0], aKx);
    atomicAdd(&ci[ro + 1], aKy);
    atomicAdd(&ci[ro + 2], aXX);
    atomicAdd(&cf[ro + 3], aH);
    atomicAdd(&cf[ro + 4], aDY);
    atomicAdd(&cf[ro + 5], aT);
    atomicAdd(&cf[ro + 6], aDF2);
    atomicAdd(&s_pool[ro + 7], aH0);
    atomicAdd(&s_pool[ro + 8], aH1);
    atomicAdd(&s_pool[ro + 9], aH2);
    if (aTMX != NINF) atomicMax(&s_pool[ro + 10], __float_as_uint(aTMX));
    if (aTMN != PINF) atomicMin(&s_pool[ro + 11], __float_as_uint(aTMN));
  }
  __syncthreads();

  float hx, hy;
  {
    int kx = ((int*)s_pool)[lane * 16 + 0];
    int ky = ((int*)s_pool)[lane * 16 + 1];
    float sx = (float)kx / 50.0f, sy = (float)ky / 50.0f;
    hx = sx / Lf; hy = sy / Lf;
  }

  // ---------------- pass 2: wave-striped distance sums ----------------
  float aD = 0.f;
  for (int base = W0 + 64 * w; base < W1; base += 256) {
    int e = base + lane;
    bool on = e < W1;
    int ec = on ? e : (W1 - 1);
    int sv = p.seg[ec];
    float2 xy = lp2[ec];
    int ul = sv - u0;
    float hxu = __shfl(hx, ul), hyu = __shfl(hy, ul);
    float d = 0.f;
    if (on) {
      float dx = xy.x - hxu, dyv = xy.y - hyu;
      d = sqrtf(fmaf(dx, dx, dyv * dyv));
    }
    float pD = pscan_f(d);
    int lo = min(max(s0 - base, 0), 64);
    int hi = min(max(e0 - base, 0), 64);
    int idx = max(hi - 1, 0);
    float PD = __shfl(pD, idx);
    float LD = wshr1_f(PD);
    if (hi > lo) aD += PD - ((lo > 0) ? LD : 0.f);
  }
  atomicAdd(&((float*)s_pool)[lane * 16 + 12], aD);

  // ---------------- phase B: unique locations, 16 users per wave ----------------
  unsigned* hashp = s_pool + 1024 + w * 128;
  for (int uu = 0; uu < 16; ++uu) {
    int gu = w * 16 + uu;                       // uniform per wave iteration
    if (u0 + gu >= p.N) break;
    int suu = rdlane_i(s0, gu), euu = rdlane_i(e0, gu);   // uniform index: OK
    int Lu = euu - suu;
    int uq = 0;
    if (Lu <= 96) {
      hashp[lane] = 0u; hashp[64 + lane] = 0u;
      asm volatile("s_waitcnt lgkmcnt(0)" ::: "memory");
      for (int b2 = suu; b2 < euu; b2 += 64) {
        int i = b2 + lane;
        bool fresh = false;
        if (i < euu) {
          float2 xy = lp2[i];
          int kx = (int)lrintf(xy.x * 50.0f) + 2048;
          int ky = (int)lrintf(xy.y * 50.0f) + 2048;
          unsigned key = (((unsigned)kx << 12) | (unsigned)ky) + 1u;
          unsigned h = (key * 2654435761u) >> 25;
          while (true) {
            unsigned old = atomicCAS(&hashp[h], 0u, key);
            if (old == 0u) { fresh = true; break; }
            if (old == key) break;
            h = (h + 1) & 127u;
          }
        }
        uq += (int)__popcll(__ballot(fresh));
      }
    } else {
      for (int b2 = suu; b2 < euu; b2 += 64) {
        int i = b2 + lane;
        bool fresh = false;
        if (i < euu) {
          float x = p.loc[2*(size_t)i], y = p.loc[2*(size_t)i+1];
          fresh = true;
          for (int jj = suu; jj < i; ++jj) {
            if (p.loc[2*(size_t)jj] == x && p.loc[2*(size_t)jj+1] == y) { fresh = false; break; }
          }
        }
        uq += (int)__popcll(__ballot(fresh));
      }
    }
    if (lane == 0) ((float*)s_pool)[gu * 16 + 13] = (float)uq;
  }
  __syncthreads();   // pass2 atomics + uq writes visible block-wide

  // ---------------- finalize: lane = (user-in-batch lr, sub-MLP quarter g2) ----------------
  int lr = lane & 15, g2 = lane >> 4;
  int gu = w * 16 + lr;
  // FIX (r8 bug): gu is divergent -> use __shfl (bpermute), NOT readlane
  int us0 = __shfl(s0, gu), ue0 = __shfl(e0, gu);
  float LfU = (float)(ue0 - us0);
  const int* ci = (const int*)s_pool + gu * 16;
  const float* cf = (const float*)s_pool + gu * 16;
  const unsigned* cu = s_pool + gu * 16;

  unsigned hp16[16];
  if (g2 == 0) {
    float sxU = (float)ci[0] / 50.0f, syU = (float)ci[1] / 50.0f;
    float hxU = sxU / LfU, hyU = syU / LfU;
    #pragma unroll
    for (int j = 0; j < 16; ++j)
      hp16[j] = pack_hl(fmaxf(s_b1[j] + hxU * s_w1[j] + hyU * s_w1[16 + j], 0.f));
  } else if (g2 == 1) {
    float th = cf[3] / LfU, tdy = cf[4] / LfU;
    float tmo = (cf[5] * (1.0f / 2592000.0f)) / LfU;
    #pragma unroll
    for (int j = 0; j < 16; ++j)
      hp16[j] = pack_hl(fmaxf(s_b1[16 + j] + th * s_w1[32 + j] + tdy * s_w1[48 + j]
                              + tmo * s_w1[64 + j], 0.f));
  } else if (g2 == 2) {
    unsigned h0 = cu[7], h1 = cu[8], h2 = cu[9];
    float act[10];
    act[0] = (float)(h0 & 255u) / LfU;
    act[1] = (float)((h0 >> 8) & 255u) / LfU;
    act[2] = (float)((h0 >> 16) & 255u) / LfU;
    act[3] = (float)((h0 >> 24) & 255u) / LfU;
    act[4] = (float)(h1 & 255u) / LfU;
    act[5] = (float)((h1 >> 8) & 255u) / LfU;
    act[6] = (float)((h1 >> 16) & 255u) / LfU;
    act[7] = (float)((h1 >> 24) & 255u) / LfU;
    act[8] = (float)(h2 & 255u) / LfU;
    act[9] = (float)((h2 >> 8) & 255u) / LfU;
    #pragma unroll
    for (int j = 0; j < 16; ++j) {
      float aa = s_b1[32 + j];
      #pragma unroll
      for (int b = 0; b < 10; ++b) aa = fmaf(act[b], s_w1[80 + b * 16 + j], aa);
      hp16[j] = pack_hl(fmaxf(aa, 0.f));
    }
  } else {
    float sxU = (float)ci[0] / 50.0f, syU = (float)ci[1] / 50.0f;
    float sxx = (float)ci[2] / 2500.0f;
    float sD = cf[12];
    float sD2 = sxx - (sxU * sxU + syU * syU) / LfU;
    float varD = (sD2 - sD * sD / LfU) / (LfU - 1.0f);
    float rad  = sqrtf(fmaxf(varD, 0.0f));
    float divy = cf[13] / LfU;
    float tmxv = __uint_as_float(cu[10]);
    float tmnv = __uint_as_float(cu[11]);
    float span = (tmxv - tmnv) / 86400.0f;
    float freq = LfU / fmaxf(span, 1.0f);
    float tfirst = p.ts[us0];
    float tlast  = p.ts[ue0 - 1];
    float sdf = tlast - tfirst;
    float mm   = LfU - 1.0f;
    float dmu  = sdf / mm;
    float dvar = (cf[6] - mm * dmu * dmu) / (mm - 1.0f);
    float reg  = 1.0f / (sqrtf(fmaxf(dvar, 0.0f)) + 1e-6f);
    #pragma unroll
    for (int j = 0; j < 16; ++j)
      hp16[j] = pack_hl(fmaxf(s_b1[48 + j] + rad * s_w1[240 + j] + divy * s_w1[256 + j]
                              + freq * s_w1[272 + j] + reg * s_w1[288 + j], 0.f));
  }
  __syncthreads();   // cacc/hash dead; pool becomes featT space

  // ---------------- stage featT + 3-layer MFMA chain (one batch per wave) ----------------
  unsigned* fw = s_pool + w * 1088;
  {
    unsigned* row = fw + lr * 68 + g2 * 16;
    #pragma unroll
    for (int j = 0; j < 4; ++j)
      *(uint4*)(row + 4 * j) = make_uint4(hp16[4*j], hp16[4*j+1], hp16[4*j+2], hp16[4*j+3]);
  }
  asm volatile("s_waitcnt lgkmcnt(0)" ::: "memory");

  int lg = lane >> 4;
  const unsigned* arow = fw + lr * 68 + (lg << 3);

  bf16x8 ah[2], al[2];
  lda(arow,      ah[0], al[0]);
  lda(arow + 32, ah[1], al[1]);
  f32x4 acc[4];
  #pragma unroll
  for (int nt = 0; nt < 4; ++nt) {
    float bv = s_b2[nt * 16 + lr];
    acc[nt] = (f32x4){bv, bv, bv, bv};
    int ks = nt >> 1;
    bf16x8 bw = ldb(s_wfrag, nt, lane);
    acc[nt] = mfma16(ah[ks], bw, acc[nt]);
    acc[nt] = mfma16(al[ks], bw, acc[nt]);
  }
  #pragma unroll
  for (int nt = 0; nt < 4; ++nt)
    #pragma unroll
    for (int r = 0; r < 4; ++r)
      fw[(lg * 4 + r) * 68 + nt * 16 + lr] = pack_hl(acc[nt][r]);
  asm volatile("s_waitcnt lgkmcnt(0)" ::: "memory");

  lda(arow,      ah[0], al[0]);
  lda(arow + 32, ah[1], al[1]);
  #pragma unroll
  for (int nt = 0; nt < 4; ++nt) {
    float bv = s_bc1[nt * 16 + lr];
    acc[nt] = (f32x4){bv, bv, bv, bv};
    #pragma unroll
    for (int ks = 0; ks < 2; ++ks) {
      bf16x8 bw = ldb(s_wfrag, 4 + nt * 2 + ks, lane);
      acc[nt] = mfma16(ah[ks], bw, acc[nt]);
      acc[nt] = mfma16(al[ks], bw, acc[nt]);
    }
  }
  #pragma unroll
  for (int nt = 0; nt < 4; ++nt)
    #pragma unroll
    for (int r = 0; r < 4; ++r)
      fw[(lg * 4 + r) * 68 + nt * 16 + lr] = pack_hl(fmaxf(acc[nt][r], 0.f));
  asm volatile("s_waitcnt lgkmcnt(0)" ::: "memory");

  lda(arow,      ah[0], al[0]);
  lda(arow + 32, ah[1], al[1]);
  #pragma unroll
  for (int nt = 0; nt < 4; ++nt) {
    float bv = s_bc2[nt * 16 + lr];
    acc[nt] = (f32x4){bv, bv, bv, bv};
    #pragma unroll
    for (int ks = 0; ks < 2; ++ks) {
      bf16x8 bw = ldb(s_wfrag, 12 + nt * 2 + ks, lane);
      acc[nt] = mfma16(ah[ks], bw, acc[nt]);
      acc[nt] = mfma16(al[ks], bw, acc[nt]);
    }
  }
  #pragma unroll
  for (int nt = 0; nt < 4; ++nt)
    #pragma unroll
    for (int r = 0; r < 4; ++r) {
      int uo = u0 + w * 16 + lg * 4 + r;
      if (uo < p.N) p.out[(size_t)uo * 64 + nt * 16 + lr] = acc[nt][r];
    }
}

extern "C" void kernel_launch(void* const* d_in, const int* in_sizes, int n_in,
                              void* d_out, int out_size, void* d_ws, size_t ws_size,
                              hipStream_t stream) {
  Params p;
  p.loc = (const float*)d_in[0];
  p.ts  = (const float*)d_in[1];
  p.cat = (const int*)d_in[2];
  p.seg = (const int*)d_in[3];
  p.wl1 = (const float*)d_in[5];  p.bl1 = (const float*)d_in[6];
  p.wl2 = (const float*)d_in[7];  p.bl2 = (const float*)d_in[8];
  p.wt1 = (const float*)d_in[9];  p.bt1 = (const float*)d_in[10];
  p.wt2 = (const float*)d_in[11]; p.bt2 = (const float*)d_in[12];
  p.wa1 = (const float*)d_in[13]; p.ba1 = (const float*)d_in[14];
  p.wa2 = (const float*)d_in[15]; p.ba2 = (const float*)d_in[16];
  p.wm1 = (const float*)d_in[17]; p.bm1 = (const float*)d_in[18];
  p.wm2 = (const float*)d_in[19]; p.bm2 = (const float*)d_in[20];
  p.wc1 = (const float*)d_in[21]; p.bc1 = (const float*)d_in[22];
  p.wc2 = (const float*)d_in[23]; p.bc2 = (const float*)d_in[24];
  p.out = (float*)d_out;
  p.N = out_size / 64;
  p.T = in_sizes[1];
  int* off = (int*)d_ws;
  p.off = off;
  p.use_off = (ws_size >= (size_t)(p.N + 1) * sizeof(int)) ? 1 : 0;

  if (p.use_off) {
    offsets_kernel<<<(p.T + 255)/256, 256, 0, stream>>>(p.seg, off, p.T, p.N);
  }
  int nblocks = (p.N + 63) / 64;
  mobility_kernel<<<nblocks, 256, 0, stream>>>(p);
}

// Round 10
// 203.639 us; speedup vs baseline: 1.2888x; 1.0870x over previous
//
#include <hip/hip_runtime.h>

typedef short bf16x8 __attribute__((ext_vector_type(8)));
typedef float f32x4 __attribute__((ext_vector_type(4)));

struct Params {
  const float* loc; const float* ts; const int* cat; const int* seg;
  const int* off;
  const float *wl1,*bl1,*wl2,*bl2;
  const float *wt1,*bt1,*wt2,*bt2;
  const float *wa1,*ba1,*wa2,*ba2;
  const float *wm1,*bm1,*wm2,*bm2;
  const float *wc1,*bc1,*wc2,*bc2;
  float* out;
  int N, T, use_off;
};

__global__ void offsets_kernel(const int* __restrict__ seg, int* __restrict__ off, int T, int N) {
  int i = blockIdx.x * blockDim.x + threadIdx.x;
  if (i == 0) off[N] = T;
  if (i < T) {
    int s = seg[i];
    if (i == 0 || seg[i-1] != s) off[s] = i;
  }
}

__device__ __forceinline__ int rdlane_i(int v, int l) {   // UNIFORM l only
  return __builtin_amdgcn_readlane(v, l);
}

__device__ __forceinline__ unsigned bf16r(float f) {
  unsigned x = __float_as_uint(f);
  return (x + 0x7fffu + ((x >> 16) & 1u)) >> 16;
}
__device__ __forceinline__ unsigned pack_hl(float f) {
  unsigned hi = bf16r(f);
  float r = f - __uint_as_float(hi << 16);
  return (hi << 16) | bf16r(r);
}

__device__ __forceinline__ float exact_fmod(float a, float m, float rcp_m) {
  float q = floorf(a * rcp_m);
  float r = fmaf(q, -m, a);
  if (r < 0.0f) r += m;
  else if (r >= m) r -= m;
  return r;
}

__device__ __forceinline__ f32x4 mfma16(bf16x8 a, bf16x8 b, f32x4 c) {
  return __builtin_amdgcn_mfma_f32_16x16x32_bf16(a, b, c, 0, 0, 0);
}

__device__ __forceinline__ void lda(const unsigned* rp, bf16x8& hi, bf16x8& lo) {
  uint4 w0 = *(const uint4*)rp;
  uint4 w1 = *(const uint4*)(rp + 4);
  union { unsigned u[4]; bf16x8 v; } H, L;
  H.u[0] = __builtin_amdgcn_perm(w0.y, w0.x, 0x07060302u);
  H.u[1] = __builtin_amdgcn_perm(w0.w, w0.z, 0x07060302u);
  H.u[2] = __builtin_amdgcn_perm(w1.y, w1.x, 0x07060302u);
  H.u[3] = __builtin_amdgcn_perm(w1.w, w1.z, 0x07060302u);
  L.u[0] = __builtin_amdgcn_perm(w0.y, w0.x, 0x05040100u);
  L.u[1] = __builtin_amdgcn_perm(w0.w, w0.z, 0x05040100u);
  L.u[2] = __builtin_amdgcn_perm(w1.y, w1.x, 0x05040100u);
  L.u[3] = __builtin_amdgcn_perm(w1.w, w1.z, 0x05040100u);
  hi = H.v; lo = L.v;
}

__device__ __forceinline__ bf16x8 ldb(const unsigned* wf, int fi, int lane) {
  union { uint4 q; bf16x8 v; } U;
  U.q = *(const uint4*)(wf + ((fi * 64 + lane) << 2));
  return U.v;
}

__device__ __forceinline__ float bdval(const Params& p, int k, int col) {
  if ((k >> 4) != (col >> 4)) return 0.f;
  int b = col >> 4;
  const float* W2 = (b & 2) ? ((b & 1) ? p.wm2 : p.wa2) : ((b & 1) ? p.wt2 : p.wl2);
  return W2[(k & 15) * 16 + (col & 15)];
}

__device__ __forceinline__ int lower_bound(const int* seg, int T, int v) {
  int lo = 0, hi = T;
  while (lo < hi) { int m = (lo + hi) >> 1; if (seg[m] < v) lo = m + 1; else hi = m; }
  return lo;
}

// ---------------- unsegmented wave64 inclusive prefix scans (DPP) ----------------
__device__ __forceinline__ float pscan_f(float v) {
  v += __int_as_float(__builtin_amdgcn_update_dpp(0, __float_as_int(v), 0x111, 0xf, 0xf, true));
  v += __int_as_float(__builtin_amdgcn_update_dpp(0, __float_as_int(v), 0x112, 0xf, 0xf, true));
  v += __int_as_float(__builtin_amdgcn_update_dpp(0, __float_as_int(v), 0x114, 0xf, 0xf, true));
  v += __int_as_float(__builtin_amdgcn_update_dpp(0, __float_as_int(v), 0x118, 0xf, 0xf, true));
  v += __int_as_float(__builtin_amdgcn_update_dpp(0, __float_as_int(v), 0x142, 0xa, 0xf, true));
  v += __int_as_float(__builtin_amdgcn_update_dpp(0, __float_as_int(v), 0x143, 0xc, 0xf, true));
  return v;
}
__device__ __forceinline__ unsigned pscan_u(unsigned v) {
  int x = (int)v;
  x += __builtin_amdgcn_update_dpp(0, x, 0x111, 0xf, 0xf, true);
  x += __builtin_amdgcn_update_dpp(0, x, 0x112, 0xf, 0xf, true);
  x += __builtin_amdgcn_update_dpp(0, x, 0x114, 0xf, 0xf, true);
  x += __builtin_amdgcn_update_dpp(0, x, 0x118, 0xf, 0xf, true);
  x += __builtin_amdgcn_update_dpp(0, x, 0x142, 0xa, 0xf, true);
  x += __builtin_amdgcn_update_dpp(0, x, 0x143, 0xc, 0xf, true);
  return (unsigned)x;
}
__device__ __forceinline__ unsigned wshr1_u(unsigned v) {
  return (unsigned)__builtin_amdgcn_update_dpp(0, (int)v, 0x138, 0xf, 0xf, true);
}
__device__ __forceinline__ float wshr1_f(float v) {
  return __int_as_float(__builtin_amdgcn_update_dpp(0, __float_as_int(v), 0x138, 0xf, 0xf, true));
}

// ---------------- segmented max/min scans (for tmx/tmn only) ----------------
#define DPPI0(v, ctrl, rm) __builtin_amdgcn_update_dpp(0, (v), ctrl, rm, 0xf, true)
#define DPPFO(v, o, ctrl, rm) __int_as_float(__builtin_amdgcn_update_dpp(__float_as_int(o), __float_as_int(v), ctrl, rm, 0xf, false))

struct Conds { bool c1,c2,c4,c8,cA,cB; };
__device__ __forceinline__ Conds mkconds(int lane, int dist) {
  Conds C;
  C.c1 = dist >= 1; C.c2 = dist >= 2; C.c4 = dist >= 4; C.c8 = dist >= 8;
  C.cA = ((lane & 15) + 1) <= dist;
  C.cB = (lane - 31) <= dist;
  return C;
}
__device__ __forceinline__ int smaxi(int v) {
  int i;
  i = DPPI0(v,0x111,0xf); v = max(v,i);
  i = DPPI0(v,0x112,0xf); v = max(v,i);
  i = DPPI0(v,0x114,0xf); v = max(v,i);
  i = DPPI0(v,0x118,0xf); v = max(v,i);
  i = DPPI0(v,0x142,0xa); v = max(v,i);
  i = DPPI0(v,0x143,0xc); v = max(v,i);
  return v;
}
__device__ __forceinline__ float smaxf(float v, const Conds& C) {
  const float NI = __int_as_float(0xff800000u);
  float i;
  i = DPPFO(v,NI,0x111,0xf); v = C.c1 ? fmaxf(v,i) : v;
  i = DPPFO(v,NI,0x112,0xf); v = C.c2 ? fmaxf(v,i) : v;
  i = DPPFO(v,NI,0x114,0xf); v = C.c4 ? fmaxf(v,i) : v;
  i = DPPFO(v,NI,0x118,0xf); v = C.c8 ? fmaxf(v,i) : v;
  i = DPPFO(v,NI,0x142,0xa); v = C.cA ? fmaxf(v,i) : v;
  i = DPPFO(v,NI,0x143,0xc); v = C.cB ? fmaxf(v,i) : v;
  return v;
}
__device__ __forceinline__ float sminf(float v, const Conds& C) {
  const float PI_ = __int_as_float(0x7f800000u);
  float i;
  i = DPPFO(v,PI_,0x111,0xf); v = C.c1 ? fminf(v,i) : v;
  i = DPPFO(v,PI_,0x112,0xf); v = C.c2 ? fminf(v,i) : v;
  i = DPPFO(v,PI_,0x114,0xf); v = C.c4 ? fminf(v,i) : v;
  i = DPPFO(v,PI_,0x118,0xf); v = C.c8 ? fminf(v,i) : v;
  i = DPPFO(v,PI_,0x142,0xa); v = C.cA ? fminf(v,i) : v;
  i = DPPFO(v,PI_,0x143,0xc); v = C.cB ? fminf(v,i) : v;
  return v;
}

// 16 users per wave, fully independent waves. Owner lanes 0-15 hold per-user
// partials in registers; finalize distributes via __shfl (no LDS acc, no atomics).
__global__ __launch_bounds__(256, 4) void mobility_kernel(Params p) {
  __shared__ __align__(16) unsigned s_wfrag[5120];   // 20480 B
  __shared__ __align__(16) unsigned s_pool[4352];    // 17408 B: per-wave featT (hash aliases)
  __shared__ float s_w1[304];
  __shared__ float s_b1[64], s_b2[64], s_bc1[64], s_bc2[64];

  int tid = threadIdx.x;
  int lane = tid & 63, w = tid >> 6;

  // ---- stage W fragments (bf16) ----
  for (int m = tid; m < 5120; m += 256) {
    int fi = m >> 8;
    int ln = (m >> 2) & 63;
    int j2 = m & 3;
    int layer, nt, ks;
    if (fi < 4)       { layer = 0; nt = fi;             ks = nt >> 1; }
    else if (fi < 12) { layer = 1; nt = (fi - 4) >> 1;  ks = (fi - 4) & 1; }
    else              { layer = 2; nt = (fi - 12) >> 1; ks = (fi - 12) & 1; }
    int col = nt * 16 + (ln & 15);
    int k0  = ks * 32 + ((ln >> 4) << 3) + (j2 << 1);
    float v0, v1;
    if (layer == 0) { v0 = bdval(p, k0, col); v1 = bdval(p, k0 + 1, col); }
    else {
      const float* W = (layer == 1) ? p.wc1 : p.wc2;
      v0 = W[k0 * 64 + col]; v1 = W[(k0 + 1) * 64 + col];
    }
    s_wfrag[m] = (bf16r(v1) << 16) | bf16r(v0);
  }
  if (tid < 32)  s_w1[tid]       = p.wl1[tid];
  if (tid < 48)  s_w1[32 + tid]  = p.wt1[tid];
  if (tid < 160) s_w1[80 + tid]  = p.wa1[tid];
  if (tid < 64)  s_w1[240 + tid] = p.wm1[tid];
  if (tid < 16) {
    s_b1[tid]    = p.bl1[tid]; s_b1[16+tid] = p.bt1[tid];
    s_b1[32+tid] = p.ba1[tid]; s_b1[48+tid] = p.bm1[tid];
    s_b2[tid]    = p.bl2[tid]; s_b2[16+tid] = p.bt2[tid];
    s_b2[32+tid] = p.ba2[tid]; s_b2[48+tid] = p.bm2[tid];
  }
  if (tid < 64) { s_bc1[tid] = p.bc1[tid]; s_bc2[tid] = p.bc2[tid]; }
  __syncthreads();

  int uw0 = blockIdx.x * 64 + w * 16;        // this wave's 16 users
  if (uw0 >= p.N) return;
  int myu = uw0 + lane;
  int myuc = min(myu, p.N - 1);
  int s0, e0;
  if (p.use_off) {
    s0 = p.off[myuc]; e0 = p.off[myuc + 1];
  } else {
    s0 = lower_bound(p.seg, p.T, myuc);
    e0 = lower_bound(p.seg, p.T, myuc + 1);
  }
  int W0 = rdlane_i(s0, 0);
  int W1 = rdlane_i(e0, 15);
  float Lf = (float)(e0 - s0);

  const float2* lp2 = (const float2*)p.loc;
  const float NINF = __int_as_float(0xff800000u);
  const float PINF = __int_as_float(0x7f800000u);

  // owner-lane (0-15) register accumulators for user uw0+lane
  int aKx = 0, aKy = 0, aXX = 0;
  float aH = 0.f, aDY = 0.f, aT = 0.f, aDF2 = 0.f;
  unsigned aH0 = 0u, aH1 = 0u, aH2 = 0u;
  float aTMX = NINF, aTMN = PINF;

  // ---------------- pass 1: coalesced stats, prefix-diff to owner lanes ----------------
  for (int base = W0; base < W1; base += 64) {
    int e = base + lane;
    bool on = e < W1;
    int ec = on ? e : (W1 - 1);
    int sv = p.seg[ec];
    int sp = (ec > 0) ? p.seg[ec - 1] : -1;
    int sn = (ec + 1 < p.T) ? p.seg[ec + 1] : -2;
    float t  = p.ts[ec];
    float tnx = (ec + 1 < p.T) ? p.ts[ec + 1] : 0.f;
    int c = p.cat[ec];
    float2 xy = lp2[ec];

    unsigned vXY = 0u, vXX = 0u, vH0 = 0u, vH1 = 0u, vH2 = 0u;
    float vH = 0.f, vDY = 0.f, vT = 0.f, vDF2 = 0.f;
    float vtmx = NINF, vtmn = PINF;
    if (on) {
      int kx = (int)lrintf(xy.x * 50.0f);
      int ky = (int)lrintf(xy.y * 50.0f);
      vXY = ((unsigned)(kx + 512) << 16) | (unsigned)(ky + 512);
      vXX = (unsigned)(kx * kx + ky * ky);
      float hr = exact_fmod(t, 86400.0f, 1.0f / 86400.0f);
      vH = hr * (1.0f / 3600.0f);
      float ud = (float)((double)t * (1.0 / 86400.0));
      vDY = exact_fmod(ud, 7.0f, 1.0f / 7.0f);
      vT = t;
      unsigned bit = 1u << ((c & 3) * 8);
      int wsel = c >> 2;
      vH0 = (wsel == 0) ? bit : 0u;
      vH1 = (wsel == 1) ? bit : 0u;
      vH2 = (wsel == 2) ? bit : 0u;
      if (sn == sv) { float dt = tnx - t; vDF2 = dt * dt; }
      vtmx = t; vtmn = t;
    }

    unsigned pXY = pscan_u(vXY), pXX = pscan_u(vXX);
    unsigned pH0 = pscan_u(vH0), pH1 = pscan_u(vH1), pH2 = pscan_u(vH2);
    float pH = pscan_f(vH), pDY = pscan_f(vDY), pT = pscan_f(vT), pDF2 = pscan_f(vDF2);

    bool head = (!on) || (sp != sv);
    int j = smaxi(head ? lane : 0);
    Conds C = mkconds(lane, lane - j);
    float pTMX = smaxf(vtmx, C);
    float pTMN = sminf(vtmn, C);

    int lo = min(max(s0 - base, 0), 64);
    int hi = min(max(e0 - base, 0), 64);
    int idx = max(hi - 1, 0);
    unsigned PXY = (unsigned)__shfl((int)pXY, idx);
    unsigned PXX = (unsigned)__shfl((int)pXX, idx);
    unsigned PH0 = (unsigned)__shfl((int)pH0, idx);
    unsigned PH1 = (unsigned)__shfl((int)pH1, idx);
    unsigned PH2 = (unsigned)__shfl((int)pH2, idx);
    float PH = __shfl(pH, idx), PDY = __shfl(pDY, idx);
    float PT = __shfl(pT, idx), PDF2 = __shfl(pDF2, idx);
    float PTMX = __shfl(pTMX, idx), PTMN = __shfl(pTMN, idx);
    unsigned LXY = wshr1_u(PXY), LXX = wshr1_u(PXX);
    unsigned LH0 = wshr1_u(PH0), LH1 = wshr1_u(PH1), LH2 = wshr1_u(PH2);
    float LH = wshr1_f(PH), LDY = wshr1_f(PDY);
    float LT = wshr1_f(PT), LDF2 = wshr1_f(PDF2);

    if (hi > lo) {
      int cnt = hi - lo;
      bool ul_ = lo > 0;
      unsigned dXY = PXY - (ul_ ? LXY : 0u);
      aKx += (int)(dXY >> 16) - (cnt << 9);
      aKy += (int)(dXY & 0xffffu) - (cnt << 9);
      aXX += (int)(PXX - (ul_ ? LXX : 0u));
      aH0 += PH0 - (ul_ ? LH0 : 0u);
      aH1 += PH1 - (ul_ ? LH1 : 0u);
      aH2 += PH2 - (ul_ ? LH2 : 0u);
      aH   += PH   - (ul_ ? LH   : 0.f);
      aDY  += PDY  - (ul_ ? LDY  : 0.f);
      aT   += PT   - (ul_ ? LT   : 0.f);
      aDF2 += PDF2 - (ul_ ? LDF2 : 0.f);
      aTMX = fmaxf(aTMX, PTMX);
      aTMN = fminf(aTMN, PTMN);
    }
  }

  // per-lane home (valid on owner lanes 0-15)
  float hx, hy;
  {
    float sx = (float)aKx / 50.0f, sy = (float)aKy / 50.0f;
    hx = sx / Lf; hy = sy / Lf;
  }

  // ---------------- pass 2: distance sums ----------------
  float aD = 0.f;
  for (int base = W0; base < W1; base += 64) {
    int e = base + lane;
    bool on = e < W1;
    int ec = on ? e : (W1 - 1);
    int sv = p.seg[ec];
    float2 xy = lp2[ec];
    int ul = sv - uw0;                 // in [0,16)
    float hxu = __shfl(hx, ul), hyu = __shfl(hy, ul);
    float d = 0.f;
    if (on) {
      float dx = xy.x - hxu, dyv = xy.y - hyu;
      d = sqrtf(fmaf(dx, dx, dyv * dyv));
    }
    float pD = pscan_f(d);
    int lo = min(max(s0 - base, 0), 64);
    int hi = min(max(e0 - base, 0), 64);
    int idx = max(hi - 1, 0);
    float PD = __shfl(pD, idx);
    float LD = wshr1_f(PD);
    if (hi > lo) aD += PD - ((lo > 0) ? LD : 0.f);
  }

  // ---------------- phase B: unique locations, 16 users serial ----------------
  unsigned* fw = s_pool + w * 1088;
  unsigned* hashp = fw;                // alias featT (used before MFMA phase)
  float uqf = 0.f;
  for (int uu = 0; uu < 16; ++uu) {
    if (uw0 + uu >= p.N) break;
    int suu = rdlane_i(s0, uu), euu = rdlane_i(e0, uu);   // uniform index
    int Lu = euu - suu;
    int uq = 0;
    if (Lu <= 96) {
      hashp[lane] = 0u; hashp[64 + lane] = 0u;
      asm volatile("s_waitcnt lgkmcnt(0)" ::: "memory");
      for (int b2 = suu; b2 < euu; b2 += 64) {
        int i = b2 + lane;
        bool fresh = false;
        if (i < euu) {
          float2 xy = lp2[i];
          int kx = (int)lrintf(xy.x * 50.0f) + 2048;
          int ky = (int)lrintf(xy.y * 50.0f) + 2048;
          unsigned key = (((unsigned)kx << 12) | (unsigned)ky) + 1u;
          unsigned h = (key * 2654435761u) >> 25;
          while (true) {
            unsigned old = atomicCAS(&hashp[h], 0u, key);
            if (old == 0u) { fresh = true; break; }
            if (old == key) break;
            h = (h + 1) & 127u;
          }
        }
        uq += (int)__popcll(__ballot(fresh));
      }
    } else {
      for (int b2 = suu; b2 < euu; b2 += 64) {
        int i = b2 + lane;
        bool fresh = false;
        if (i < euu) {
          float x = p.loc[2*(size_t)i], y = p.loc[2*(size_t)i+1];
          fresh = true;
          for (int jj = suu; jj < i; ++jj) {
            if (p.loc[2*(size_t)jj] == x && p.loc[2*(size_t)jj+1] == y) { fresh = false; break; }
          }
        }
        uq += (int)__popcll(__ballot(fresh));
      }
    }
    if (lane == uu) uqf = (float)uq;
  }
  asm volatile("s_waitcnt lgkmcnt(0)" ::: "memory");   // hash reads done before featT overwrite

  // ---------------- finalize: lane = (user lr, quarter g2); stats via shfl ----------------
  int lr = lane & 15, g2 = lane >> 4;
  int us0 = __shfl(s0, lr), ue0 = __shfl(e0, lr);
  float LfU = (float)(ue0 - us0);
  int KX = __shfl(aKx, lr), KY = __shfl(aKy, lr), XX = __shfl(aXX, lr);
  float H_ = __shfl(aH, lr), DY_ = __shfl(aDY, lr);
  float T_ = __shfl(aT, lr), DF2_ = __shfl(aDF2, lr);
  unsigned H0_ = (unsigned)__shfl((int)aH0, lr);
  unsigned H1_ = (unsigned)__shfl((int)aH1, lr);
  unsigned H2_ = (unsigned)__shfl((int)aH2, lr);
  float TMX_ = __shfl(aTMX, lr), TMN_ = __shfl(aTMN, lr);
  float D_ = __shfl(aD, lr), UQ_ = __shfl(uqf, lr);

  unsigned hp16[16];
  if (g2 == 0) {
    float sxU = (float)KX / 50.0f, syU = (float)KY / 50.0f;
    float hxU = sxU / LfU, hyU = syU / LfU;
    #pragma unroll
    for (int j = 0; j < 16; ++j)
      hp16[j] = pack_hl(fmaxf(s_b1[j] + hxU * s_w1[j] + hyU * s_w1[16 + j], 0.f));
  } else if (g2 == 1) {
    float th = H_ / LfU, tdy = DY_ / LfU;
    float tmo = (T_ * (1.0f / 2592000.0f)) / LfU;
    #pragma unroll
    for (int j = 0; j < 16; ++j)
      hp16[j] = pack_hl(fmaxf(s_b1[16 + j] + th * s_w1[32 + j] + tdy * s_w1[48 + j]
                              + tmo * s_w1[64 + j], 0.f));
  } else if (g2 == 2) {
    float act[10];
    act[0] = (float)(H0_ & 255u) / LfU;
    act[1] = (float)((H0_ >> 8) & 255u) / LfU;
    act[2] = (float)((H0_ >> 16) & 255u) / LfU;
    act[3] = (float)((H0_ >> 24) & 255u) / LfU;
    act[4] = (float)(H1_ & 255u) / LfU;
    act[5] = (float)((H1_ >> 8) & 255u) / LfU;
    act[6] = (float)((H1_ >> 16) & 255u) / LfU;
    act[7] = (float)((H1_ >> 24) & 255u) / LfU;
    act[8] = (float)(H2_ & 255u) / LfU;
    act[9] = (float)((H2_ >> 8) & 255u) / LfU;
    #pragma unroll
    for (int j = 0; j < 16; ++j) {
      float aa = s_b1[32 + j];
      #pragma unroll
      for (int b = 0; b < 10; ++b) aa = fmaf(act[b], s_w1[80 + b * 16 + j], aa);
      hp16[j] = pack_hl(fmaxf(aa, 0.f));
    }
  } else {
    float sxU = (float)KX / 50.0f, syU = (float)KY / 50.0f;
    float sxx = (float)XX / 2500.0f;
    float sD = D_;
    float sD2 = sxx - (sxU * sxU + syU * syU) / LfU;
    float varD = (sD2 - sD * sD / LfU) / (LfU - 1.0f);
    float rad  = sqrtf(fmaxf(varD, 0.0f));
    float divy = UQ_ / LfU;
    float span = (TMX_ - TMN_) / 86400.0f;
    float freq = LfU / fmaxf(span, 1.0f);
    float tfirst = p.ts[us0];
    float tlast  = p.ts[ue0 - 1];
    float sdf = tlast - tfirst;
    float mm   = LfU - 1.0f;
    float dmu  = sdf / mm;
    float dvar = (DF2_ - mm * dmu * dmu) / (mm - 1.0f);
    float reg  = 1.0f / (sqrtf(fmaxf(dvar, 0.0f)) + 1e-6f);
    #pragma unroll
    for (int j = 0; j < 16; ++j)
      hp16[j] = pack_hl(fmaxf(s_b1[48 + j] + rad * s_w1[240 + j] + divy * s_w1[256 + j]
                              + freq * s_w1[272 + j] + reg * s_w1[288 + j], 0.f));
  }

  // ---------------- stage featT + 3-layer MFMA chain (one 16-user batch) ----------------
  {
    unsigned* row = fw + lr * 68 + g2 * 16;
    #pragma unroll
    for (int j = 0; j < 4; ++j)
      *(uint4*)(row + 4 * j) = make_uint4(hp16[4*j], hp16[4*j+1], hp16[4*j+2], hp16[4*j+3]);
  }
  asm volatile("s_waitcnt lgkmcnt(0)" ::: "memory");

  int lg = lane >> 4;
  const unsigned* arow = fw + lr * 68 + (lg << 3);

  bf16x8 ah[2], al[2];
  lda(arow,      ah[0], al[0]);
  lda(arow + 32, ah[1], al[1]);
  f32x4 acc[4];
  #pragma unroll
  for (int nt = 0; nt < 4; ++nt) {
    float bv = s_b2[nt * 16 + lr];
    acc[nt] = (f32x4){bv, bv, bv, bv};
    int ks = nt >> 1;
    bf16x8 bw = ldb(s_wfrag, nt, lane);
    acc[nt] = mfma16(ah[ks], bw, acc[nt]);
    acc[nt] = mfma16(al[ks], bw, acc[nt]);
  }
  #pragma unroll
  for (int nt = 0; nt < 4; ++nt)
    #pragma unroll
    for (int r = 0; r < 4; ++r)
      fw[(lg * 4 + r) * 68 + nt * 16 + lr] = pack_hl(acc[nt][r]);
  asm volatile("s_waitcnt lgkmcnt(0)" ::: "memory");

  lda(arow,      ah[0], al[0]);
  lda(arow + 32, ah[1], al[1]);
  #pragma unroll
  for (int nt = 0; nt < 4; ++nt) {
    float bv = s_bc1[nt * 16 + lr];
    acc[nt] = (f32x4){bv, bv, bv, bv};
    #pragma unroll
    for (int ks = 0; ks < 2; ++ks) {
      bf16x8 bw = ldb(s_wfrag, 4 + nt * 2 + ks, lane);
      acc[nt] = mfma16(ah[ks], bw, acc[nt]);
      acc[nt] = mfma16(al[ks], bw, acc[nt]);
    }
  }
  #pragma unroll
  for (int nt = 0; nt < 4; ++nt)
    #pragma unroll
    for (int r = 0; r < 4; ++r)
      fw[(lg * 4 + r) * 68 + nt * 16 + lr] = pack_hl(fmaxf(acc[nt][r], 0.f));
  asm volatile("s_waitcnt lgkmcnt(0)" ::: "memory");

  lda(arow,      ah[0], al[0]);
  lda(arow + 32, ah[1], al[1]);
  #pragma unroll
  for (int nt = 0; nt < 4; ++nt) {
    float bv = s_bc2[nt * 16 + lr];
    acc[nt] = (f32x4){bv, bv, bv, bv};
    #pragma unroll
    for (int ks = 0; ks < 2; ++ks) {
      bf16x8 bw = ldb(s_wfrag, 12 + nt * 2 + ks, lane);
      acc[nt] = mfma16(ah[ks], bw, acc[nt]);
      acc[nt] = mfma16(al[ks], bw, acc[nt]);
    }
  }
  #pragma unroll
  for (int nt = 0; nt < 4; ++nt)
    #pragma unroll
    for (int r = 0; r < 4; ++r) {
      int uo = uw0 + lg * 4 + r;
      if (uo < p.N) p.out[(size_t)uo * 64 + nt * 16 + lr] = acc[nt][r];
    }
}

extern "C" void kernel_launch(void* const* d_in, const int* in_sizes, int n_in,
                              void* d_out, int out_size, void* d_ws, size_t ws_size,
                              hipStream_t stream) {
  Params p;
  p.loc = (const float*)d_in[0];
  p.ts  = (const float*)d_in[1];
  p.cat = (const int*)d_in[2];
  p.seg = (const int*)d_in[3];
  p.wl1 = (const float*)d_in[5];  p.bl1 = (const float*)d_in[6];
  p.wl2 = (const float*)d_in[7];  p.bl2 = (const float*)d_in[8];
  p.wt1 = (const float*)d_in[9];  p.bt1 = (const float*)d_in[10];
  p.wt2 = (const float*)d_in[11]; p.bt2 = (const float*)d_in[12];
  p.wa1 = (const float*)d_in[13]; p.ba1 = (const float*)d_in[14];
  p.wa2 = (const float*)d_in[15]; p.ba2 = (const float*)d_in[16];
  p.wm1 = (const float*)d_in[17]; p.bm1 = (const float*)d_in[18];
  p.wm2 = (const float*)d_in[19]; p.bm2 = (const float*)d_in[20];
  p.wc1 = (const float*)d_in[21]; p.bc1 = (const float*)d_in[22];
  p.wc2 = (const float*)d_in[23]; p.bc2 = (const float*)d_in[24];
  p.out = (float*)d_out;
  p.N = out_size / 64;
  p.T = in_sizes[1];
  int* off = (int*)d_ws;
  p.off = off;
  p.use_off = (ws_size >= (size_t)(p.N + 1) * sizeof(int)) ? 1 : 0;

  if (p.use_off) {
    offsets_kernel<<<(p.T + 255)/256, 256, 0, stream>>>(p.seg, off, p.T, p.N);
  }
  int nblocks = (p.N + 63) / 64;
  mobility_kernel<<<nblocks, 256, 0, stream>>>(p);
}

// Round 12
// 181.223 us; speedup vs baseline: 1.4482x; 1.1237x over previous
//
#include <hip/hip_runtime.h>

typedef short bf16x8 __attribute__((ext_vector_type(8)));
typedef float f32x4 __attribute__((ext_vector_type(4)));

struct Params {
  const float* loc; const float* ts; const int* cat; const int* seg;
  const int* off;
  const float *wl1,*bl1,*wl2,*bl2;
  const float *wt1,*bt1,*wt2,*bt2;
  const float *wa1,*ba1,*wa2,*ba2;
  const float *wm1,*bm1,*wm2,*bm2;
  const float *wc1,*bc1,*wc2,*bc2;
  float* out;
  unsigned* wfrag;          // prepacked bf16 B-fragments in d_ws (or nullptr)
  int N, T, use_off;
};

__global__ void offsets_kernel(const int* __restrict__ seg, int* __restrict__ off, int T, int N) {
  int i = blockIdx.x * blockDim.x + threadIdx.x;
  if (i == 0) off[N] = T;
  if (i < T) {
    int s = seg[i];
    if (i == 0 || seg[i-1] != s) off[s] = i;
  }
}

__device__ __forceinline__ int rdlane_i(int v, int l) {   // UNIFORM l only
  return __builtin_amdgcn_readlane(v, l);
}

__device__ __forceinline__ unsigned bf16r(float f) {
  unsigned x = __float_as_uint(f);
  return (x + 0x7fffu + ((x >> 16) & 1u)) >> 16;
}
__device__ __forceinline__ unsigned pack_hl(float f) {
  unsigned hi = bf16r(f);
  float r = f - __uint_as_float(hi << 16);
  return (hi << 16) | bf16r(r);
}

__device__ __forceinline__ float exact_fmod(float a, float m, float rcp_m) {
  float q = floorf(a * rcp_m);
  float r = fmaf(q, -m, a);
  if (r < 0.0f) r += m;
  else if (r >= m) r -= m;
  return r;
}

__device__ __forceinline__ f32x4 mfma16(bf16x8 a, bf16x8 b, f32x4 c) {
  return __builtin_amdgcn_mfma_f32_16x16x32_bf16(a, b, c, 0, 0, 0);
}

__device__ __forceinline__ void lda(const unsigned* rp, bf16x8& hi, bf16x8& lo) {
  uint4 w0 = *(const uint4*)rp;
  uint4 w1 = *(const uint4*)(rp + 4);
  union { unsigned u[4]; bf16x8 v; } H, L;
  H.u[0] = __builtin_amdgcn_perm(w0.y, w0.x, 0x07060302u);
  H.u[1] = __builtin_amdgcn_perm(w0.w, w0.z, 0x07060302u);
  H.u[2] = __builtin_amdgcn_perm(w1.y, w1.x, 0x07060302u);
  H.u[3] = __builtin_amdgcn_perm(w1.w, w1.z, 0x07060302u);
  L.u[0] = __builtin_amdgcn_perm(w0.y, w0.x, 0x05040100u);
  L.u[1] = __builtin_amdgcn_perm(w0.w, w0.z, 0x05040100u);
  L.u[2] = __builtin_amdgcn_perm(w1.y, w1.x, 0x05040100u);
  L.u[3] = __builtin_amdgcn_perm(w1.w, w1.z, 0x05040100u);
  hi = H.v; lo = L.v;
}

__device__ __forceinline__ float bdval_(const float* wl2, const float* wt2,
                                        const float* wa2, const float* wm2,
                                        int k, int col) {
  if ((k >> 4) != (col >> 4)) return 0.f;
  int b = col >> 4;
  const float* W2 = (b & 2) ? ((b & 1) ? wm2 : wa2) : ((b & 1) ? wt2 : wl2);
  return W2[(k & 15) * 16 + (col & 15)];
}

__device__ __forceinline__ unsigned frag_word(const Params& p, int m) {
  int fi = m >> 8;
  int ln = (m >> 2) & 63;
  int j2 = m & 3;
  int layer, nt, ks;
  if (fi < 4)       { layer = 0; nt = fi;             ks = nt >> 1; }
  else if (fi < 12) { layer = 1; nt = (fi - 4) >> 1;  ks = (fi - 4) & 1; }
  else              { layer = 2; nt = (fi - 12) >> 1; ks = (fi - 12) & 1; }
  int col = nt * 16 + (ln & 15);
  int k0  = ks * 32 + ((ln >> 4) << 3) + (j2 << 1);
  float v0, v1;
  if (layer == 0) {
    v0 = bdval_(p.wl2, p.wt2, p.wa2, p.wm2, k0, col);
    v1 = bdval_(p.wl2, p.wt2, p.wa2, p.wm2, k0 + 1, col);
  } else {
    const float* W = (layer == 1) ? p.wc1 : p.wc2;
    v0 = W[k0 * 64 + col]; v1 = W[(k0 + 1) * 64 + col];
  }
  return (bf16r(v1) << 16) | bf16r(v0);
}

__global__ void pack_kernel(Params p) {
  int m = blockIdx.x * 256 + threadIdx.x;
  if (m < 5120) p.wfrag[m] = frag_word(p, m);
}

// B-fragment load: prepacked global (L2-hot) or on-the-fly fallback
__device__ __forceinline__ bf16x8 g_ldb(const Params& p, int fi, int lane) {
  union { uint4 q; unsigned u[4]; bf16x8 v; } U;
  if (p.wfrag) {
    U.q = *(const uint4*)(p.wfrag + ((fi * 64 + lane) << 2));
  } else {
    int m = fi * 256 + lane * 4;
    U.u[0] = frag_word(p, m + 0);
    U.u[1] = frag_word(p, m + 1);
    U.u[2] = frag_word(p, m + 2);
    U.u[3] = frag_word(p, m + 3);
  }
  return U.v;
}

__device__ __forceinline__ int lower_bound(const int* seg, int T, int v) {
  int lo = 0, hi = T;
  while (lo < hi) { int m = (lo + hi) >> 1; if (seg[m] < v) lo = m + 1; else hi = m; }
  return lo;
}

// ---------------- unsegmented wave64 inclusive prefix scans (DPP) ----------------
__device__ __forceinline__ float pscan_f(float v) {
  v += __int_as_float(__builtin_amdgcn_update_dpp(0, __float_as_int(v), 0x111, 0xf, 0xf, true));
  v += __int_as_float(__builtin_amdgcn_update_dpp(0, __float_as_int(v), 0x112, 0xf, 0xf, true));
  v += __int_as_float(__builtin_amdgcn_update_dpp(0, __float_as_int(v), 0x114, 0xf, 0xf, true));
  v += __int_as_float(__builtin_amdgcn_update_dpp(0, __float_as_int(v), 0x118, 0xf, 0xf, true));
  v += __int_as_float(__builtin_amdgcn_update_dpp(0, __float_as_int(v), 0x142, 0xa, 0xf, true));
  v += __int_as_float(__builtin_amdgcn_update_dpp(0, __float_as_int(v), 0x143, 0xc, 0xf, true));
  return v;
}
__device__ __forceinline__ unsigned pscan_u(unsigned v) {
  int x = (int)v;
  x += __builtin_amdgcn_update_dpp(0, x, 0x111, 0xf, 0xf, true);
  x += __builtin_amdgcn_update_dpp(0, x, 0x112, 0xf, 0xf, true);
  x += __builtin_amdgcn_update_dpp(0, x, 0x114, 0xf, 0xf, true);
  x += __builtin_amdgcn_update_dpp(0, x, 0x118, 0xf, 0xf, true);
  x += __builtin_amdgcn_update_dpp(0, x, 0x142, 0xa, 0xf, true);
  x += __builtin_amdgcn_update_dpp(0, x, 0x143, 0xc, 0xf, true);
  return (unsigned)x;
}
__device__ __forceinline__ unsigned wshr1_u(unsigned v) {
  return (unsigned)__builtin_amdgcn_update_dpp(0, (int)v, 0x138, 0xf, 0xf, true);
}
__device__ __forceinline__ float wshr1_f(float v) {
  return __int_as_float(__builtin_amdgcn_update_dpp(0, __float_as_int(v), 0x138, 0xf, 0xf, true));
}

// ---------------- segmented max/min scans (for tmx/tmn only) ----------------
#define DPPI0(v, ctrl, rm) __builtin_amdgcn_update_dpp(0, (v), ctrl, rm, 0xf, true)
#define DPPFO(v, o, ctrl, rm) __int_as_float(__builtin_amdgcn_update_dpp(__float_as_int(o), __float_as_int(v), ctrl, rm, 0xf, false))

struct Conds { bool c1,c2,c4,c8,cA,cB; };
__device__ __forceinline__ Conds mkconds(int lane, int dist) {
  Conds C;
  C.c1 = dist >= 1; C.c2 = dist >= 2; C.c4 = dist >= 4; C.c8 = dist >= 8;
  C.cA = ((lane & 15) + 1) <= dist;
  C.cB = (lane - 31) <= dist;
  return C;
}
__device__ __forceinline__ int smaxi(int v) {
  int i;
  i = DPPI0(v,0x111,0xf); v = max(v,i);
  i = DPPI0(v,0x112,0xf); v = max(v,i);
  i = DPPI0(v,0x114,0xf); v = max(v,i);
  i = DPPI0(v,0x118,0xf); v = max(v,i);
  i = DPPI0(v,0x142,0xa); v = max(v,i);
  i = DPPI0(v,0x143,0xc); v = max(v,i);
  return v;
}
__device__ __forceinline__ float smaxf(float v, const Conds& C) {
  const float NI = __int_as_float(0xff800000u);
  float i;
  i = DPPFO(v,NI,0x111,0xf); v = C.c1 ? fmaxf(v,i) : v;
  i = DPPFO(v,NI,0x112,0xf); v = C.c2 ? fmaxf(v,i) : v;
  i = DPPFO(v,NI,0x114,0xf); v = C.c4 ? fmaxf(v,i) : v;
  i = DPPFO(v,NI,0x118,0xf); v = C.c8 ? fmaxf(v,i) : v;
  i = DPPFO(v,NI,0x142,0xa); v = C.cA ? fmaxf(v,i) : v;
  i = DPPFO(v,NI,0x143,0xc); v = C.cB ? fmaxf(v,i) : v;
  return v;
}
__device__ __forceinline__ float sminf(float v, const Conds& C) {
  const float PI_ = __int_as_float(0x7f800000u);
  float i;
  i = DPPFO(v,PI_,0x111,0xf); v = C.c1 ? fminf(v,i) : v;
  i = DPPFO(v,PI_,0x112,0xf); v = C.c2 ? fminf(v,i) : v;
  i = DPPFO(v,PI_,0x114,0xf); v = C.c4 ? fminf(v,i) : v;
  i = DPPFO(v,PI_,0x118,0xf); v = C.c8 ? fminf(v,i) : v;
  i = DPPFO(v,PI_,0x142,0xa); v = C.cA ? fminf(v,i) : v;
  i = DPPFO(v,PI_,0x143,0xc); v = C.cB ? fminf(v,i) : v;
  return v;
}

// 16 users per wave, fully independent waves. Owner lanes 0-15 hold per-user
// partials in registers; finalize distributes via __shfl (no LDS acc, no atomics).
// LDS ~19.7KB -> 8 blocks/CU (W fragments moved to global/L2).
__global__ __launch_bounds__(256, 4) void mobility_kernel(Params p) {
  __shared__ __align__(16) unsigned s_pool[4352];    // 17408 B: per-wave featT (hash aliases)
  __shared__ float s_w1[304];
  __shared__ float s_b1[64], s_b2[64], s_bc1[64], s_bc2[64];

  int tid = threadIdx.x;
  int lane = tid & 63, w = tid >> 6;

  if (tid < 32)  s_w1[tid]       = p.wl1[tid];
  if (tid < 48)  s_w1[32 + tid]  = p.wt1[tid];
  if (tid < 160) s_w1[80 + tid]  = p.wa1[tid];
  if (tid < 64)  s_w1[240 + tid] = p.wm1[tid];
  if (tid < 16) {
    s_b1[tid]    = p.bl1[tid]; s_b1[16+tid] = p.bt1[tid];
    s_b1[32+tid] = p.ba1[tid]; s_b1[48+tid] = p.bm1[tid];
    s_b2[tid]    = p.bl2[tid]; s_b2[16+tid] = p.bt2[tid];
    s_b2[32+tid] = p.ba2[tid]; s_b2[48+tid] = p.bm2[tid];
  }
  if (tid < 64) { s_bc1[tid] = p.bc1[tid]; s_bc2[tid] = p.bc2[tid]; }
  __syncthreads();

  int uw0 = blockIdx.x * 64 + w * 16;        // this wave's 16 users
  if (uw0 >= p.N) return;
  int myu = uw0 + lane;
  int myuc = min(myu, p.N - 1);
  int s0, e0;
  if (p.use_off) {
    s0 = p.off[myuc]; e0 = p.off[myuc + 1];
  } else {
    s0 = lower_bound(p.seg, p.T, myuc);
    e0 = lower_bound(p.seg, p.T, myuc + 1);
  }
  int W0 = rdlane_i(s0, 0);
  int W1 = rdlane_i(e0, 15);
  float Lf = (float)(e0 - s0);

  const float2* lp2 = (const float2*)p.loc;
  const float NINF = __int_as_float(0xff800000u);
  const float PINF = __int_as_float(0x7f800000u);

  // owner-lane (0-15) register accumulators for user uw0+lane
  int aKx = 0, aKy = 0, aXX = 0;
  float aH = 0.f, aDY = 0.f, aT = 0.f, aDF2 = 0.f;
  unsigned aH0 = 0u, aH1 = 0u, aH2 = 0u;
  float aTMX = NINF, aTMN = PINF;

  // ---------------- pass 1: coalesced stats, prefix-diff to owner lanes ----------------
  for (int base = W0; base < W1; base += 64) {
    int e = base + lane;
    bool on = e < W1;
    int ec = on ? e : (W1 - 1);
    int sv = p.seg[ec];
    int sp = (ec > 0) ? p.seg[ec - 1] : -1;
    int sn = (ec + 1 < p.T) ? p.seg[ec + 1] : -2;
    float t  = p.ts[ec];
    float tnx = (ec + 1 < p.T) ? p.ts[ec + 1] : 0.f;
    int c = p.cat[ec];
    float2 xy = lp2[ec];

    unsigned vXY = 0u, vXX = 0u, vH0 = 0u, vH1 = 0u, vH2 = 0u;
    float vH = 0.f, vDY = 0.f, vT = 0.f, vDF2 = 0.f;
    float vtmx = NINF, vtmn = PINF;
    if (on) {
      int kx = (int)lrintf(xy.x * 50.0f);
      int ky = (int)lrintf(xy.y * 50.0f);
      vXY = ((unsigned)(kx + 512) << 16) | (unsigned)(ky + 512);
      vXX = (unsigned)(kx * kx + ky * ky);
      float hr = exact_fmod(t, 86400.0f, 1.0f / 86400.0f);
      vH = hr * (1.0f / 3600.0f);
      float ud = (float)((double)t * (1.0 / 86400.0));
      vDY = exact_fmod(ud, 7.0f, 1.0f / 7.0f);
      vT = t;
      unsigned bit = 1u << ((c & 3) * 8);
      int wsel = c >> 2;
      vH0 = (wsel == 0) ? bit : 0u;
      vH1 = (wsel == 1) ? bit : 0u;
      vH2 = (wsel == 2) ? bit : 0u;
      if (sn == sv) { float dt = tnx - t; vDF2 = dt * dt; }
      vtmx = t; vtmn = t;
    }

    unsigned pXY = pscan_u(vXY), pXX = pscan_u(vXX);
    unsigned pH0 = pscan_u(vH0), pH1 = pscan_u(vH1), pH2 = pscan_u(vH2);
    float pH = pscan_f(vH), pDY = pscan_f(vDY), pT = pscan_f(vT), pDF2 = pscan_f(vDF2);

    bool head = (!on) || (sp != sv);
    int j = smaxi(head ? lane : 0);
    Conds C = mkconds(lane, lane - j);
    float pTMX = smaxf(vtmx, C);
    float pTMN = sminf(vtmn, C);

    int lo = min(max(s0 - base, 0), 64);
    int hi = min(max(e0 - base, 0), 64);
    int idx = max(hi - 1, 0);
    unsigned PXY = (unsigned)__shfl((int)pXY, idx);
    unsigned PXX = (unsigned)__shfl((int)pXX, idx);
    unsigned PH0 = (unsigned)__shfl((int)pH0, idx);
    unsigned PH1 = (unsigned)__shfl((int)pH1, idx);
    unsigned PH2 = (unsigned)__shfl((int)pH2, idx);
    float PH = __shfl(pH, idx), PDY = __shfl(pDY, idx);
    float PT = __shfl(pT, idx), PDF2 = __shfl(pDF2, idx);
    float PTMX = __shfl(pTMX, idx), PTMN = __shfl(pTMN, idx);
    unsigned LXY = wshr1_u(PXY), LXX = wshr1_u(PXX);
    unsigned LH0 = wshr1_u(PH0), LH1 = wshr1_u(PH1), LH2 = wshr1_u(PH2);
    float LH = wshr1_f(PH), LDY = wshr1_f(PDY);
    float LT = wshr1_f(PT), LDF2 = wshr1_f(PDF2);

    if (hi > lo) {
      int cnt = hi - lo;
      bool ul_ = lo > 0;
      unsigned dXY = PXY - (ul_ ? LXY : 0u);
      aKx += (int)(dXY >> 16) - (cnt << 9);
      aKy += (int)(dXY & 0xffffu) - (cnt << 9);
      aXX += (int)(PXX - (ul_ ? LXX : 0u));
      aH0 += PH0 - (ul_ ? LH0 : 0u);
      aH1 += PH1 - (ul_ ? LH1 : 0u);
      aH2 += PH2 - (ul_ ? LH2 : 0u);
      aH   += PH   - (ul_ ? LH   : 0.f);
      aDY  += PDY  - (ul_ ? LDY  : 0.f);
      aT   += PT   - (ul_ ? LT   : 0.f);
      aDF2 += PDF2 - (ul_ ? LDF2 : 0.f);
      aTMX = fmaxf(aTMX, PTMX);
      aTMN = fminf(aTMN, PTMN);
    }
  }

  // per-lane home (valid on owner lanes 0-15)
  float hx, hy;
  {
    float sx = (float)aKx / 50.0f, sy = (float)aKy / 50.0f;
    hx = sx / Lf; hy = sy / Lf;
  }

  // ---------------- pass 2: distance sums ----------------
  float aD = 0.f;
  for (int base = W0; base < W1; base += 64) {
    int e = base + lane;
    bool on = e < W1;
    int ec = on ? e : (W1 - 1);
    int sv = p.seg[ec];
    float2 xy = lp2[ec];
    int ul = sv - uw0;                 // in [0,16)
    float hxu = __shfl(hx, ul), hyu = __shfl(hy, ul);
    float d = 0.f;
    if (on) {
      float dx = xy.x - hxu, dyv = xy.y - hyu;
      d = sqrtf(fmaf(dx, dx, dyv * dyv));
    }
    float pD = pscan_f(d);
    int lo = min(max(s0 - base, 0), 64);
    int hi = min(max(e0 - base, 0), 64);
    int idx = max(hi - 1, 0);
    float PD = __shfl(pD, idx);
    float LD = wshr1_f(PD);
    if (hi > lo) aD += PD - ((lo > 0) ? LD : 0.f);
  }

  // ---------------- phase B: unique locations, 16 users serial ----------------
  unsigned* fw = s_pool + w * 1088;
  unsigned* hashp = fw;                // alias featT (used before MFMA phase)
  float uqf = 0.f;
  for (int uu = 0; uu < 16; ++uu) {
    if (uw0 + uu >= p.N) break;
    int suu = rdlane_i(s0, uu), euu = rdlane_i(e0, uu);   // uniform index
    int Lu = euu - suu;
    int uq = 0;
    if (Lu <= 96) {
      hashp[lane] = 0u; hashp[64 + lane] = 0u;
      asm volatile("s_waitcnt lgkmcnt(0)" ::: "memory");
      for (int b2 = suu; b2 < euu; b2 += 64) {
        int i = b2 + lane;
        bool fresh = false;
        if (i < euu) {
          float2 xy = lp2[i];
          int kx = (int)lrintf(xy.x * 50.0f) + 2048;
          int ky = (int)lrintf(xy.y * 50.0f) + 2048;
          unsigned key = (((unsigned)kx << 12) | (unsigned)ky) + 1u;
          unsigned h = (key * 2654435761u) >> 25;
          while (true) {
            unsigned old = atomicCAS(&hashp[h], 0u, key);
            if (old == 0u) { fresh = true; break; }
            if (old == key) break;
            h = (h + 1) & 127u;
          }
        }
        uq += (int)__popcll(__ballot(fresh));
      }
    } else {
      for (int b2 = suu; b2 < euu; b2 += 64) {
        int i = b2 + lane;
        bool fresh = false;
        if (i < euu) {
          float x = p.loc[2*(size_t)i], y = p.loc[2*(size_t)i+1];
          fresh = true;
          for (int jj = suu; jj < i; ++jj) {
            if (p.loc[2*(size_t)jj] == x && p.loc[2*(size_t)jj+1] == y) { fresh = false; break; }
          }
        }
        uq += (int)__popcll(__ballot(fresh));
      }
    }
    if (lane == uu) uqf = (float)uq;
  }
  asm volatile("s_waitcnt lgkmcnt(0)" ::: "memory");   // hash reads done before featT overwrite

  // ---------------- finalize: lane = (user lr, quarter g2); stats via shfl ----------------
  int lr = lane & 15, g2 = lane >> 4;
  int us0 = __shfl(s0, lr), ue0 = __shfl(e0, lr);
  float LfU = (float)(ue0 - us0);
  int KX = __shfl(aKx, lr), KY = __shfl(aKy, lr), XX = __shfl(aXX, lr);
  float H_ = __shfl(aH, lr), DY_ = __shfl(aDY, lr);
  float T_ = __shfl(aT, lr), DF2_ = __shfl(aDF2, lr);
  unsigned H0_ = (unsigned)__shfl((int)aH0, lr);
  unsigned H1_ = (unsigned)__shfl((int)aH1, lr);
  unsigned H2_ = (unsigned)__shfl((int)aH2, lr);
  float TMX_ = __shfl(aTMX, lr), TMN_ = __shfl(aTMN, lr);
  float D_ = __shfl(aD, lr), UQ_ = __shfl(uqf, lr);

  unsigned hp16[16];
  if (g2 == 0) {
    float sxU = (float)KX / 50.0f, syU = (float)KY / 50.0f;
    float hxU = sxU / LfU, hyU = syU / LfU;
    #pragma unroll
    for (int j = 0; j < 16; ++j)
      hp16[j] = pack_hl(fmaxf(s_b1[j] + hxU * s_w1[j] + hyU * s_w1[16 + j], 0.f));
  } else if (g2 == 1) {
    float th = H_ / LfU, tdy = DY_ / LfU;
    float tmo = (T_ * (1.0f / 2592000.0f)) / LfU;
    #pragma unroll
    for (int j = 0; j < 16; ++j)
      hp16[j] = pack_hl(fmaxf(s_b1[16 + j] + th * s_w1[32 + j] + tdy * s_w1[48 + j]
                              + tmo * s_w1[64 + j], 0.f));
  } else if (g2 == 2) {
    float act[10];
    act[0] = (float)(H0_ & 255u) / LfU;
    act[1] = (float)((H0_ >> 8) & 255u) / LfU;
    act[2] = (float)((H0_ >> 16) & 255u) / LfU;
    act[3] = (float)((H0_ >> 24) & 255u) / LfU;
    act[4] = (float)(H1_ & 255u) / LfU;
    act[5] = (float)((H1_ >> 8) & 255u) / LfU;
    act[6] = (float)((H1_ >> 16) & 255u) / LfU;
    act[7] = (float)((H1_ >> 24) & 255u) / LfU;
    act[8] = (float)(H2_ & 255u) / LfU;
    act[9] = (float)((H2_ >> 8) & 255u) / LfU;
    #pragma unroll
    for (int j = 0; j < 16; ++j) {
      float aa = s_b1[32 + j];
      #pragma unroll
      for (int b = 0; b < 10; ++b) aa = fmaf(act[b], s_w1[80 + b * 16 + j], aa);
      hp16[j] = pack_hl(fmaxf(aa, 0.f));
    }
  } else {
    float sxU = (float)KX / 50.0f, syU = (float)KY / 50.0f;
    float sxx = (float)XX / 2500.0f;
    float sD = D_;
    float sD2 = sxx - (sxU * sxU + syU * syU) / LfU;
    float varD = (sD2 - sD * sD / LfU) / (LfU - 1.0f);
    float rad  = sqrtf(fmaxf(varD, 0.0f));
    float divy = UQ_ / LfU;
    float span = (TMX_ - TMN_) / 86400.0f;
    float freq = LfU / fmaxf(span, 1.0f);
    float tfirst = p.ts[us0];
    float tlast  = p.ts[ue0 - 1];
    float sdf = tlast - tfirst;
    float mm   = LfU - 1.0f;
    float dmu  = sdf / mm;
    float dvar = (DF2_ - mm * dmu * dmu) / (mm - 1.0f);
    float reg  = 1.0f / (sqrtf(fmaxf(dvar, 0.0f)) + 1e-6f);
    #pragma unroll
    for (int j = 0; j < 16; ++j)
      hp16[j] = pack_hl(fmaxf(s_b1[48 + j] + rad * s_w1[240 + j] + divy * s_w1[256 + j]
                              + freq * s_w1[272 + j] + reg * s_w1[288 + j], 0.f));
  }

  // ---------------- stage featT + 3-layer MFMA chain (one 16-user batch) ----------------
  {
    unsigned* row = fw + lr * 68 + g2 * 16;
    #pragma unroll
    for (int j = 0; j < 4; ++j)
      *(uint4*)(row + 4 * j) = make_uint4(hp16[4*j], hp16[4*j+1], hp16[4*j+2], hp16[4*j+3]);
  }
  asm volatile("s_waitcnt lgkmcnt(0)" ::: "memory");

  int lg = lane >> 4;
  const unsigned* arow = fw + lr * 68 + (lg << 3);

  bf16x8 ah[2], al[2];
  lda(arow,      ah[0], al[0]);
  lda(arow + 32, ah[1], al[1]);
  f32x4 acc[4];
  #pragma unroll
  for (int nt = 0; nt < 4; ++nt) {
    float bv = s_b2[nt * 16 + lr];
    acc[nt] = (f32x4){bv, bv, bv, bv};
    int ks = nt >> 1;
    bf16x8 bw = g_ldb(p, nt, lane);
    acc[nt] = mfma16(ah[ks], bw, acc[nt]);
    acc[nt] = mfma16(al[ks], bw, acc[nt]);
  }
  #pragma unroll
  for (int nt = 0; nt < 4; ++nt)
    #pragma unroll
    for (int r = 0; r < 4; ++r)
      fw[(lg * 4 + r) * 68 + nt * 16 + lr] = pack_hl(acc[nt][r]);
  asm volatile("s_waitcnt lgkmcnt(0)" ::: "memory");

  lda(arow,      ah[0], al[0]);
  lda(arow + 32, ah[1], al[1]);
  #pragma unroll
  for (int nt = 0; nt < 4; ++nt) {
    float bv = s_bc1[nt * 16 + lr];
    acc[nt] = (f32x4){bv, bv, bv, bv};
    #pragma unroll
    for (int ks = 0; ks < 2; ++ks) {
      bf16x8 bw = g_ldb(p, 4 + nt * 2 + ks, lane);
      acc[nt] = mfma16(ah[ks], bw, acc[nt]);
      acc[nt] = mfma16(al[ks], bw, acc[nt]);
    }
  }
  #pragma unroll
  for (int nt = 0; nt < 4; ++nt)
    #pragma unroll
    for (int r = 0; r < 4; ++r)
      fw[(lg * 4 + r) * 68 + nt * 16 + lr] = pack_hl(fmaxf(acc[nt][r], 0.f));
  asm volatile("s_waitcnt lgkmcnt(0)" ::: "memory");

  lda(arow,      ah[0], al[0]);
  lda(arow + 32, ah[1], al[1]);
  #pragma unroll
  for (int nt = 0; nt < 4; ++nt) {
    float bv = s_bc2[nt * 16 + lr];
    acc[nt] = (f32x4){bv, bv, bv, bv};
    #pragma unroll
    for (int ks = 0; ks < 2; ++ks) {
      bf16x8 bw = g_ldb(p, 12 + nt * 2 + ks, lane);
      acc[nt] = mfma16(ah[ks], bw, acc[nt]);
      acc[nt] = mfma16(al[ks], bw, acc[nt]);
    }
  }
  #pragma unroll
  for (int nt = 0; nt < 4; ++nt)
    #pragma unroll
    for (int r = 0; r < 4; ++r) {
      int uo = uw0 + lg * 4 + r;
      if (uo < p.N) p.out[(size_t)uo * 64 + nt * 16 + lr] = acc[nt][r];
    }
}

extern "C" void kernel_launch(void* const* d_in, const int* in_sizes, int n_in,
                              void* d_out, int out_size, void* d_ws, size_t ws_size,
                              hipStream_t stream) {
  Params p;
  p.loc = (const float*)d_in[0];
  p.ts  = (const float*)d_in[1];
  p.cat = (const int*)d_in[2];
  p.seg = (const int*)d_in[3];
  p.wl1 = (const float*)d_in[5];  p.bl1 = (const float*)d_in[6];
  p.wl2 = (const float*)d_in[7];  p.bl2 = (const float*)d_in[8];
  p.wt1 = (const float*)d_in[9];  p.bt1 = (const float*)d_in[10];
  p.wt2 = (const float*)d_in[11]; p.bt2 = (const float*)d_in[12];
  p.wa1 = (const float*)d_in[13]; p.ba1 = (const float*)d_in[14];
  p.wa2 = (const float*)d_in[15]; p.ba2 = (const float*)d_in[16];
  p.wm1 = (const float*)d_in[17]; p.bm1 = (const float*)d_in[18];
  p.wm2 = (const float*)d_in[19]; p.bm2 = (const float*)d_in[20];
  p.wc1 = (const float*)d_in[21]; p.bc1 = (const float*)d_in[22];
  p.wc2 = (const float*)d_in[23]; p.bc2 = (const float*)d_in[24];
  p.out = (float*)d_out;
  p.N = out_size / 64;
  p.T = in_sizes[1];
  int* off = (int*)d_ws;
  p.off = off;
  p.use_off = (ws_size >= (size_t)(p.N + 1) * sizeof(int)) ? 1 : 0;

  // prepacked W fragments behind off[] in d_ws (16B-aligned)
  size_t fragOff = (((size_t)p.N + 1) + 3) & ~(size_t)3;
  p.wfrag = nullptr;
  if (ws_size >= (fragOff + 5120) * sizeof(unsigned)) {
    p.wfrag = (unsigned*)d_ws + fragOff;
    pack_kernel<<<20, 256, 0, stream>>>(p);
  }

  if (p.use_off) {
    offsets_kernel<<<(p.T + 255)/256, 256, 0, stream>>>(p.seg, off, p.T, p.N);
  }
  int nblocks = (p.N + 63) / 64;
  mobility_kernel<<<nblocks, 256, 0, stream>>>(p);
}

// Round 15
// 177.001 us; speedup vs baseline: 1.4827x; 1.0239x over previous
//
#include <hip/hip_runtime.h>

typedef short bf16x8 __attribute__((ext_vector_type(8)));
typedef float f32x4 __attribute__((ext_vector_type(4)));

struct Params {
  const float* loc; const float* ts; const int* cat; const int* seg;
  const int* off;
  const float *wl1,*bl1,*wl2,*bl2;
  const float *wt1,*bt1,*wt2,*bt2;
  const float *wa1,*ba1,*wa2,*ba2;
  const float *wm1,*bm1,*wm2,*bm2;
  const float *wc1,*bc1,*wc2,*bc2;
  float* out;
  unsigned* wfrag;          // prepacked bf16 B-fragments in d_ws (or nullptr)
  int N, T, use_off;
};

__global__ void offsets_kernel(const int* __restrict__ seg, int* __restrict__ off, int T, int N) {
  int i = blockIdx.x * blockDim.x + threadIdx.x;
  if (i == 0) off[N] = T;
  if (i < T) {
    int s = seg[i];
    if (i == 0 || seg[i-1] != s) off[s] = i;
  }
}

__device__ __forceinline__ int rdlane_i(int v, int l) {   // UNIFORM l only
  return __builtin_amdgcn_readlane(v, l);
}
__device__ __forceinline__ float rdlane_f(float v, int l) {
  return __int_as_float(__builtin_amdgcn_readlane(__float_as_int(v), l));
}

__device__ __forceinline__ unsigned bf16r(float f) {
  unsigned x = __float_as_uint(f);
  return (x + 0x7fffu + ((x >> 16) & 1u)) >> 16;
}
__device__ __forceinline__ unsigned pack_hl(float f) {
  unsigned hi = bf16r(f);
  float r = f - __uint_as_float(hi << 16);
  return (hi << 16) | bf16r(r);
}

__device__ __forceinline__ float exact_fmod(float a, float m, float rcp_m) {
  float q = floorf(a * rcp_m);
  float r = fmaf(q, -m, a);
  if (r < 0.0f) r += m;
  else if (r >= m) r -= m;
  return r;
}

__device__ __forceinline__ f32x4 mfma16(bf16x8 a, bf16x8 b, f32x4 c) {
  return __builtin_amdgcn_mfma_f32_16x16x32_bf16(a, b, c, 0, 0, 0);
}

__device__ __forceinline__ void lda(const unsigned* rp, bf16x8& hi, bf16x8& lo) {
  uint4 w0 = *(const uint4*)rp;
  uint4 w1 = *(const uint4*)(rp + 4);
  union { unsigned u[4]; bf16x8 v; } H, L;
  H.u[0] = __builtin_amdgcn_perm(w0.y, w0.x, 0x07060302u);
  H.u[1] = __builtin_amdgcn_perm(w0.w, w0.z, 0x07060302u);
  H.u[2] = __builtin_amdgcn_perm(w1.y, w1.x, 0x07060302u);
  H.u[3] = __builtin_amdgcn_perm(w1.w, w1.z, 0x07060302u);
  L.u[0] = __builtin_amdgcn_perm(w0.y, w0.x, 0x05040100u);
  L.u[1] = __builtin_amdgcn_perm(w0.w, w0.z, 0x05040100u);
  L.u[2] = __builtin_amdgcn_perm(w1.y, w1.x, 0x05040100u);
  L.u[3] = __builtin_amdgcn_perm(w1.w, w1.z, 0x05040100u);
  hi = H.v; lo = L.v;
}

__device__ __forceinline__ float bdval_(const float* wl2, const float* wt2,
                                        const float* wa2, const float* wm2,
                                        int k, int col) {
  if ((k >> 4) != (col >> 4)) return 0.f;
  int b = col >> 4;
  const float* W2 = (b & 2) ? ((b & 1) ? wm2 : wa2) : ((b & 1) ? wt2 : wl2);
  return W2[(k & 15) * 16 + (col & 15)];
}

__device__ __forceinline__ unsigned frag_word(const Params& p, int m) {
  int fi = m >> 8;
  int ln = (m >> 2) & 63;
  int j2 = m & 3;
  int layer, nt, ks;
  if (fi < 4)       { layer = 0; nt = fi;             ks = nt >> 1; }
  else if (fi < 12) { layer = 1; nt = (fi - 4) >> 1;  ks = (fi - 4) & 1; }
  else              { layer = 2; nt = (fi - 12) >> 1; ks = (fi - 12) & 1; }
  int col = nt * 16 + (ln & 15);
  int k0  = ks * 32 + ((ln >> 4) << 3) + (j2 << 1);
  float v0, v1;
  if (layer == 0) {
    v0 = bdval_(p.wl2, p.wt2, p.wa2, p.wm2, k0, col);
    v1 = bdval_(p.wl2, p.wt2, p.wa2, p.wm2, k0 + 1, col);
  } else {
    const float* W = (layer == 1) ? p.wc1 : p.wc2;
    v0 = W[k0 * 64 + col]; v1 = W[(k0 + 1) * 64 + col];
  }
  return (bf16r(v1) << 16) | bf16r(v0);
}

__global__ void pack_kernel(Params p) {
  int m = blockIdx.x * 256 + threadIdx.x;
  if (m < 5120) p.wfrag[m] = frag_word(p, m);
}

// B-fragment load: prepacked global (L2-hot) or on-the-fly fallback
__device__ __forceinline__ bf16x8 g_ldb(const Params& p, int fi, int lane) {
  union { uint4 q; unsigned u[4]; bf16x8 v; } U;
  if (p.wfrag) {
    U.q = *(const uint4*)(p.wfrag + ((fi * 64 + lane) << 2));
  } else {
    int m = fi * 256 + lane * 4;
    U.u[0] = frag_word(p, m + 0);
    U.u[1] = frag_word(p, m + 1);
    U.u[2] = frag_word(p, m + 2);
    U.u[3] = frag_word(p, m + 3);
  }
  return U.v;
}

__device__ __forceinline__ int lower_bound(const int* seg, int T, int v) {
  int lo = 0, hi = T;
  while (lo < hi) { int m = (lo + hi) >> 1; if (seg[m] < v) lo = m + 1; else hi = m; }
  return lo;
}

// ---------------- unsegmented wave64 inclusive prefix scans (DPP) ----------------
__device__ __forceinline__ float pscan_f(float v) {
  v += __int_as_float(__builtin_amdgcn_update_dpp(0, __float_as_int(v), 0x111, 0xf, 0xf, true));
  v += __int_as_float(__builtin_amdgcn_update_dpp(0, __float_as_int(v), 0x112, 0xf, 0xf, true));
  v += __int_as_float(__builtin_amdgcn_update_dpp(0, __float_as_int(v), 0x114, 0xf, 0xf, true));
  v += __int_as_float(__builtin_amdgcn_update_dpp(0, __float_as_int(v), 0x118, 0xf, 0xf, true));
  v += __int_as_float(__builtin_amdgcn_update_dpp(0, __float_as_int(v), 0x142, 0xa, 0xf, true));
  v += __int_as_float(__builtin_amdgcn_update_dpp(0, __float_as_int(v), 0x143, 0xc, 0xf, true));
  return v;
}
__device__ __forceinline__ unsigned pscan_u(unsigned v) {
  int x = (int)v;
  x += __builtin_amdgcn_update_dpp(0, x, 0x111, 0xf, 0xf, true);
  x += __builtin_amdgcn_update_dpp(0, x, 0x112, 0xf, 0xf, true);
  x += __builtin_amdgcn_update_dpp(0, x, 0x114, 0xf, 0xf, true);
  x += __builtin_amdgcn_update_dpp(0, x, 0x118, 0xf, 0xf, true);
  x += __builtin_amdgcn_update_dpp(0, x, 0x142, 0xa, 0xf, true);
  x += __builtin_amdgcn_update_dpp(0, x, 0x143, 0xc, 0xf, true);
  return (unsigned)x;
}
__device__ __forceinline__ unsigned wshr1_u(unsigned v) {
  return (unsigned)__builtin_amdgcn_update_dpp(0, (int)v, 0x138, 0xf, 0xf, true);
}
__device__ __forceinline__ float wshr1_f(float v) {
  return __int_as_float(__builtin_amdgcn_update_dpp(0, __float_as_int(v), 0x138, 0xf, 0xf, true));
}

// 16 users per wave, fully independent waves. Owner lanes 0-15 hold per-user
// partials in registers; finalize distributes via __shfl (no LDS acc, no atomics).
// Pass 1: sums only (no segmented scans). Phase B: hash uniq + exact tmax/tmin + sum(d).
__global__ __launch_bounds__(256, 4) void mobility_kernel(Params p) {
  __shared__ __align__(16) unsigned s_pool[4352];    // per-wave featT (hash aliases)
  __shared__ float s_w1[304];
  __shared__ float s_b1[64], s_b2[64], s_bc1[64], s_bc2[64];

  int tid = threadIdx.x;
  int lane = tid & 63, w = tid >> 6;

  if (tid < 32)  s_w1[tid]       = p.wl1[tid];
  if (tid < 48)  s_w1[32 + tid]  = p.wt1[tid];
  if (tid < 160) s_w1[80 + tid]  = p.wa1[tid];
  if (tid < 64)  s_w1[240 + tid] = p.wm1[tid];
  if (tid < 16) {
    s_b1[tid]    = p.bl1[tid]; s_b1[16+tid] = p.bt1[tid];
    s_b1[32+tid] = p.ba1[tid]; s_b1[48+tid] = p.bm1[tid];
    s_b2[tid]    = p.bl2[tid]; s_b2[16+tid] = p.bt2[tid];
    s_b2[32+tid] = p.ba2[tid]; s_b2[48+tid] = p.bm2[tid];
  }
  if (tid < 64) { s_bc1[tid] = p.bc1[tid]; s_bc2[tid] = p.bc2[tid]; }
  __syncthreads();

  int uw0 = blockIdx.x * 64 + w * 16;        // this wave's 16 users
  if (uw0 >= p.N) return;
  int myu = uw0 + lane;
  int myuc = min(myu, p.N - 1);
  int s0, e0;
  if (p.use_off) {
    s0 = p.off[myuc]; e0 = p.off[myuc + 1];
  } else {
    s0 = lower_bound(p.seg, p.T, myuc);
    e0 = lower_bound(p.seg, p.T, myuc + 1);
  }
  int W0 = rdlane_i(s0, 0);
  int W1 = rdlane_i(e0, 15);
  float Lf = (float)(e0 - s0);

  const float2* lp2 = (const float2*)p.loc;
  const float NINF = __int_as_float(0xff800000u);
  const float PINF = __int_as_float(0x7f800000u);

  // owner-lane (0-15) register accumulators for user uw0+lane
  int aKx = 0, aKy = 0, aXX = 0;
  float aH = 0.f, aDY = 0.f, aT = 0.f, aDF2 = 0.f;
  unsigned aH0 = 0u, aH1 = 0u, aH2 = 0u;

  // ---------------- pass 1: coalesced stats, prefix-diff to owner lanes ----------------
  for (int base = W0; base < W1; base += 64) {
    int e = base + lane;
    bool on = e < W1;
    int ec = on ? e : (W1 - 1);
    int sv = p.seg[ec];
    int sn = (ec + 1 < p.T) ? p.seg[ec + 1] : -2;
    float t  = p.ts[ec];
    float tnx = (ec + 1 < p.T) ? p.ts[ec + 1] : 0.f;
    int c = p.cat[ec];
    float2 xy = lp2[ec];

    unsigned vXY = 0u, vXX = 0u, vH0 = 0u, vH1 = 0u, vH2 = 0u;
    float vH = 0.f, vDY = 0.f, vT = 0.f, vDF2 = 0.f;
    if (on) {
      int kx = (int)lrintf(xy.x * 50.0f);
      int ky = (int)lrintf(xy.y * 50.0f);
      vXY = ((unsigned)(kx + 512) << 16) | (unsigned)(ky + 512);
      vXX = (unsigned)(kx * kx + ky * ky);
      float hr = exact_fmod(t, 86400.0f, 1.0f / 86400.0f);
      vH = hr * (1.0f / 3600.0f);
      float ud = (float)((double)t * (1.0 / 86400.0));
      vDY = exact_fmod(ud, 7.0f, 1.0f / 7.0f);
      vT = t;
      unsigned bit = 1u << ((c & 3) * 8);
      int wsel = c >> 2;
      vH0 = (wsel == 0) ? bit : 0u;
      vH1 = (wsel == 1) ? bit : 0u;
      vH2 = (wsel == 2) ? bit : 0u;
      if (sn == sv) { float dt = tnx - t; vDF2 = dt * dt; }
    }

    unsigned pXY = pscan_u(vXY), pXX = pscan_u(vXX);
    unsigned pH0 = pscan_u(vH0), pH1 = pscan_u(vH1), pH2 = pscan_u(vH2);
    float pH = pscan_f(vH), pDY = pscan_f(vDY), pT = pscan_f(vT), pDF2 = pscan_f(vDF2);

    int lo = min(max(s0 - base, 0), 64);
    int hi = min(max(e0 - base, 0), 64);
    int idx = max(hi - 1, 0);
    unsigned PXY = (unsigned)__shfl((int)pXY, idx);
    unsigned PXX = (unsigned)__shfl((int)pXX, idx);
    unsigned PH0 = (unsigned)__shfl((int)pH0, idx);
    unsigned PH1 = (unsigned)__shfl((int)pH1, idx);
    unsigned PH2 = (unsigned)__shfl((int)pH2, idx);
    float PH = __shfl(pH, idx), PDY = __shfl(pDY, idx);
    float PT = __shfl(pT, idx), PDF2 = __shfl(pDF2, idx);
    unsigned LXY = wshr1_u(PXY), LXX = wshr1_u(PXX);
    unsigned LH0 = wshr1_u(PH0), LH1 = wshr1_u(PH1), LH2 = wshr1_u(PH2);
    float LH = wshr1_f(PH), LDY = wshr1_f(PDY);
    float LT = wshr1_f(PT), LDF2 = wshr1_f(PDF2);

    if (hi > lo) {
      int cnt = hi - lo;
      bool ul_ = lo > 0;
      unsigned dXY = PXY - (ul_ ? LXY : 0u);
      aKx += (int)(dXY >> 16) - (cnt << 9);
      aKy += (int)(dXY & 0xffffu) - (cnt << 9);
      aXX += (int)(PXX - (ul_ ? LXX : 0u));
      aH0 += PH0 - (ul_ ? LH0 : 0u);
      aH1 += PH1 - (ul_ ? LH1 : 0u);
      aH2 += PH2 - (ul_ ? LH2 : 0u);
      aH   += PH   - (ul_ ? LH   : 0.f);
      aDY  += PDY  - (ul_ ? LDY  : 0.f);
      aT   += PT   - (ul_ ? LT   : 0.f);
      aDF2 += PDF2 - (ul_ ? LDF2 : 0.f);
    }
  }

  // per-lane home (valid on owner lanes 0-15)
  float hx, hy;
  {
    float sx = (float)aKx / 50.0f, sy = (float)aKy / 50.0f;
    hx = sx / Lf; hy = sy / Lf;
  }

  // ---------- phase B: uniq hash + exact tmax/tmin + sum(d), 16 users serial ----------
  unsigned* fw = s_pool + w * 1088;
  unsigned* hashp = fw;                // alias featT (used before MFMA phase)
  float uqf = 0.f, tmxA = NINF, tmnA = PINF, aD = 0.f;
  for (int uu = 0; uu < 16; ++uu) {
    if (uw0 + uu >= p.N) break;
    int suu = rdlane_i(s0, uu), euu = rdlane_i(e0, uu);   // uniform index
    float hxu = rdlane_f(hx, uu), hyu = rdlane_f(hy, uu); // uniform index
    int Lu = euu - suu;
    int uq = 0;
    float cmx = NINF, cmn = PINF, dsum = 0.f;
    if (Lu <= 96) {
      hashp[lane] = 0u; hashp[64 + lane] = 0u;
      asm volatile("s_waitcnt lgkmcnt(0)" ::: "memory");
      for (int b2 = suu; b2 < euu; b2 += 64) {
        int i = b2 + lane;
        bool fresh = false;
        if (i < euu) {
          float tv = p.ts[i];
          cmx = fmaxf(cmx, tv); cmn = fminf(cmn, tv);
          float2 xy = lp2[i];
          float dx = xy.x - hxu, dyv = xy.y - hyu;
          dsum += sqrtf(fmaf(dx, dx, dyv * dyv));
          int kx = (int)lrintf(xy.x * 50.0f) + 2048;
          int ky = (int)lrintf(xy.y * 50.0f) + 2048;
          unsigned key = (((unsigned)kx << 12) | (unsigned)ky) + 1u;
          unsigned h = (key * 2654435761u) >> 25;
          while (true) {
            unsigned old = atomicCAS(&hashp[h], 0u, key);
            if (old == 0u) { fresh = true; break; }
            if (old == key) break;
            h = (h + 1) & 127u;
          }
        }
        uq += (int)__popcll(__ballot(fresh));
      }
    } else {
      for (int b2 = suu; b2 < euu; b2 += 64) {
        int i = b2 + lane;
        bool fresh = false;
        if (i < euu) {
          float tv = p.ts[i];
          cmx = fmaxf(cmx, tv); cmn = fminf(cmn, tv);
          float x = p.loc[2*(size_t)i], y = p.loc[2*(size_t)i+1];
          float dx = x - hxu, dyv = y - hyu;
          dsum += sqrtf(fmaf(dx, dx, dyv * dyv));
          fresh = true;
          for (int jj = suu; jj < i; ++jj) {
            if (p.loc[2*(size_t)jj] == x && p.loc[2*(size_t)jj+1] == y) { fresh = false; break; }
          }
        }
        uq += (int)__popcll(__ballot(fresh));
      }
    }
    #pragma unroll
    for (int o = 32; o > 0; o >>= 1) {
      cmx = fmaxf(cmx, __shfl_xor(cmx, o));
      cmn = fminf(cmn, __shfl_xor(cmn, o));
      dsum += __shfl_xor(dsum, o);
    }
    if (lane == uu) { uqf = (float)uq; tmxA = cmx; tmnA = cmn; aD = dsum; }
  }
  asm volatile("s_waitcnt lgkmcnt(0)" ::: "memory");   // hash reads done before featT overwrite

  // ---------------- finalize: lane = (user lr, quarter g2); stats via shfl ----------------
  int lr = lane & 15, g2 = lane >> 4;
  int us0 = __shfl(s0, lr), ue0 = __shfl(e0, lr);
  float LfU = (float)(ue0 - us0);
  int KX = __shfl(aKx, lr), KY = __shfl(aKy, lr), XX = __shfl(aXX, lr);
  float H_ = __shfl(aH, lr), DY_ = __shfl(aDY, lr);
  float T_ = __shfl(aT, lr), DF2_ = __shfl(aDF2, lr);
  unsigned H0_ = (unsigned)__shfl((int)aH0, lr);
  unsigned H1_ = (unsigned)__shfl((int)aH1, lr);
  unsigned H2_ = (unsigned)__shfl((int)aH2, lr);
  float TMX_ = __shfl(tmxA, lr), TMN_ = __shfl(tmnA, lr);
  float D_ = __shfl(aD, lr), UQ_ = __shfl(uqf, lr);

  unsigned hp16[16];
  if (g2 == 0) {
    float sxU = (float)KX / 50.0f, syU = (float)KY / 50.0f;
    float hxU = sxU / LfU, hyU = syU / LfU;
    #pragma unroll
    for (int j = 0; j < 16; ++j)
      hp16[j] = pack_hl(fmaxf(s_b1[j] + hxU * s_w1[j] + hyU * s_w1[16 + j], 0.f));
  } else if (g2 == 1) {
    float th = H_ / LfU, tdy = DY_ / LfU;
    float tmo = (T_ * (1.0f / 2592000.0f)) / LfU;
    #pragma unroll
    for (int j = 0; j < 16; ++j)
      hp16[j] = pack_hl(fmaxf(s_b1[16 + j] + th * s_w1[32 + j] + tdy * s_w1[48 + j]
                              + tmo * s_w1[64 + j], 0.f));
  } else if (g2 == 2) {
    float act[10];
    act[0] = (float)(H0_ & 255u) / LfU;
    act[1] = (float)((H0_ >> 8) & 255u) / LfU;
    act[2] = (float)((H0_ >> 16) & 255u) / LfU;
    act[3] = (float)((H0_ >> 24) & 255u) / LfU;
    act[4] = (float)(H1_ & 255u) / LfU;
    act[5] = (float)((H1_ >> 8) & 255u) / LfU;
    act[6] = (float)((H1_ >> 16) & 255u) / LfU;
    act[7] = (float)((H1_ >> 24) & 255u) / LfU;
    act[8] = (float)(H2_ & 255u) / LfU;
    act[9] = (float)((H2_ >> 8) & 255u) / LfU;
    #pragma unroll
    for (int j = 0; j < 16; ++j) {
      float aa = s_b1[32 + j];
      #pragma unroll
      for (int b = 0; b < 10; ++b) aa = fmaf(act[b], s_w1[80 + b * 16 + j], aa);
      hp16[j] = pack_hl(fmaxf(aa, 0.f));
    }
  } else {
    float sxU = (float)KX / 50.0f, syU = (float)KY / 50.0f;
    float sxx = (float)XX / 2500.0f;
    float sD = D_;
    float sD2 = sxx - (sxU * sxU + syU * syU) / LfU;
    float varD = (sD2 - sD * sD / LfU) / (LfU - 1.0f);
    float rad  = sqrtf(fmaxf(varD, 0.0f));
    float divy = UQ_ / LfU;
    float span = (TMX_ - TMN_) / 86400.0f;
    float freq = LfU / fmaxf(span, 1.0f);
    float tfirst = p.ts[us0];
    float tlast  = p.ts[ue0 - 1];
    float sdf = tlast - tfirst;
    float mm   = LfU - 1.0f;
    float dmu  = sdf / mm;
    float dvar = (DF2_ - mm * dmu * dmu) / (mm - 1.0f);
    float reg  = 1.0f / (sqrtf(fmaxf(dvar, 0.0f)) + 1e-6f);
    #pragma unroll
    for (int j = 0; j < 16; ++j)
      hp16[j] = pack_hl(fmaxf(s_b1[48 + j] + rad * s_w1[240 + j] + divy * s_w1[256 + j]
                              + freq * s_w1[272 + j] + reg * s_w1[288 + j], 0.f));
  }

  // ---------------- stage featT + 3-layer MFMA chain (one 16-user batch) ----------------
  {
    unsigned* row = fw + lr * 68 + g2 * 16;
    #pragma unroll
    for (int j = 0; j < 4; ++j)
      *(uint4*)(row + 4 * j) = make_uint4(hp16[4*j], hp16[4*j+1], hp16[4*j+2], hp16[4*j+3]);
  }
  asm volatile("s_waitcnt lgkmcnt(0)" ::: "memory");

  int lg = lane >> 4;
  const unsigned* arow = fw + lr * 68 + (lg << 3);

  bf16x8 ah[2], al[2];
  lda(arow,      ah[0], al[0]);
  lda(arow + 32, ah[1], al[1]);
  f32x4 acc[4];
  #pragma unroll
  for (int nt = 0; nt < 4; ++nt) {
    float bv = s_b2[nt * 16 + lr];
    acc[nt] = (f32x4){bv, bv, bv, bv};
    int ks = nt >> 1;
    bf16x8 bw = g_ldb(p, nt, lane);
    acc[nt] = mfma16(ah[ks], bw, acc[nt]);
    acc[nt] = mfma16(al[ks], bw, acc[nt]);
  }
  #pragma unroll
  for (int nt = 0; nt < 4; ++nt)
    #pragma unroll
    for (int r = 0; r < 4; ++r)
      fw[(lg * 4 + r) * 68 + nt * 16 + lr] = pack_hl(acc[nt][r]);
  asm volatile("s_waitcnt lgkmcnt(0)" ::: "memory");

  lda(arow,      ah[0], al[0]);
  lda(arow + 32, ah[1], al[1]);
  #pragma unroll
  for (int nt = 0; nt < 4; ++nt) {
    float bv = s_bc1[nt * 16 + lr];
    acc[nt] = (f32x4){bv, bv, bv, bv};
    #pragma unroll
    for (int ks = 0; ks < 2; ++ks) {
      bf16x8 bw = g_ldb(p, 4 + nt * 2 + ks, lane);
      acc[nt] = mfma16(ah[ks], bw, acc[nt]);
      acc[nt] = mfma16(al[ks], bw, acc[nt]);
    }
  }
  #pragma unroll
  for (int nt = 0; nt < 4; ++nt)
    #pragma unroll
    for (int r = 0; r < 4; ++r)
      fw[(lg * 4 + r) * 68 + nt * 16 + lr] = pack_hl(fmaxf(acc[nt][r], 0.f));
  asm volatile("s_waitcnt lgkmcnt(0)" ::: "memory");

  lda(arow,      ah[0], al[0]);
  lda(arow + 32, ah[1], al[1]);
  #pragma unroll
  for (int nt = 0; nt < 4; ++nt) {
    float bv = s_bc2[nt * 16 + lr];
    acc[nt] = (f32x4){bv, bv, bv, bv};
    #pragma unroll
    for (int ks = 0; ks < 2; ++ks) {
      bf16x8 bw = g_ldb(p, 12 + nt * 2 + ks, lane);
      acc[nt] = mfma16(ah[ks], bw, acc[nt]);
      acc[nt] = mfma16(al[ks], bw, acc[nt]);
    }
  }
  #pragma unroll
  for (int nt = 0; nt < 4; ++nt)
    #pragma unroll
    for (int r = 0; r < 4; ++r) {
      int uo = uw0 + lg * 4 + r;
      if (uo < p.N) p.out[(size_t)uo * 64 + nt * 16 + lr] = acc[nt][r];
    }
}

extern "C" void kernel_launch(void* const* d_in, const int* in_sizes, int n_in,
                              void* d_out, int out_size, void* d_ws, size_t ws_size,
                              hipStream_t stream) {
  Params p;
  p.loc = (const float*)d_in[0];
  p.ts  = (const float*)d_in[1];
  p.cat = (const int*)d_in[2];
  p.seg = (const int*)d_in[3];
  p.wl1 = (const float*)d_in[5];  p.bl1 = (const float*)d_in[6];
  p.wl2 = (const float*)d_in[7];  p.bl2 = (const float*)d_in[8];
  p.wt1 = (const float*)d_in[9];  p.bt1 = (const float*)d_in[10];
  p.wt2 = (const float*)d_in[11]; p.bt2 = (const float*)d_in[12];
  p.wa1 = (const float*)d_in[13]; p.ba1 = (const float*)d_in[14];
  p.wa2 = (const float*)d_in[15]; p.ba2 = (const float*)d_in[16];
  p.wm1 = (const float*)d_in[17]; p.bm1 = (const float*)d_in[18];
  p.wm2 = (const float*)d_in[19]; p.bm2 = (const float*)d_in[20];
  p.wc1 = (const float*)d_in[21]; p.bc1 = (const float*)d_in[22];
  p.wc2 = (const float*)d_in[23]; p.bc2 = (const float*)d_in[24];
  p.out = (float*)d_out;
  p.N = out_size / 64;
  p.T = in_sizes[1];
  int* off = (int*)d_ws;
  p.off = off;
  p.use_off = (ws_size >= (size_t)(p.N + 1) * sizeof(int)) ? 1 : 0;

  size_t fragOff = (((size_t)p.N + 1) + 3) & ~(size_t)3;
  p.wfrag = nullptr;
  if (ws_size >= (fragOff + 5120) * sizeof(unsigned)) {
    p.wfrag = (unsigned*)d_ws + fragOff;
    pack_kernel<<<20, 256, 0, stream>>>(p);
  }

  if (p.use_off) {
    offsets_kernel<<<(p.T + 255)/256, 256, 0, stream>>>(p.seg, off, p.T, p.N);
  }
  int nblocks = (p.N + 63) / 64;
  mobility_kernel<<<nblocks, 256, 0, stream>>>(p);
}

// Round 16
// 163.858 us; speedup vs baseline: 1.6016x; 1.0802x over previous
//
#include <hip/hip_runtime.h>

typedef short bf16x8 __attribute__((ext_vector_type(8)));
typedef float f32x4 __attribute__((ext_vector_type(4)));

struct Params {
  const float* loc; const float* ts; const int* cat; const int* seg;
  const int* off;
  const float *wl1,*bl1,*wl2,*bl2;
  const float *wt1,*bt1,*wt2,*bt2;
  const float *wa1,*ba1,*wa2,*ba2;
  const float *wm1,*bm1,*wm2,*bm2;
  const float *wc1,*bc1,*wc2,*bc2;
  float* out;
  unsigned* wfrag;          // prepacked bf16 B-fragments in d_ws (or nullptr)
  int N, T, use_off;
};

__global__ void offsets_kernel(const int* __restrict__ seg, int* __restrict__ off, int T, int N) {
  int i = blockIdx.x * blockDim.x + threadIdx.x;
  if (i == 0) off[N] = T;
  if (i < T) {
    int s = seg[i];
    if (i == 0 || seg[i-1] != s) off[s] = i;
  }
}

__device__ __forceinline__ int rdlane_i(int v, int l) {   // UNIFORM l only
  return __builtin_amdgcn_readlane(v, l);
}
__device__ __forceinline__ float rdlane_f(float v, int l) {
  return __int_as_float(__builtin_amdgcn_readlane(__float_as_int(v), l));
}

__device__ __forceinline__ unsigned bf16r(float f) {
  unsigned x = __float_as_uint(f);
  return (x + 0x7fffu + ((x >> 16) & 1u)) >> 16;
}
__device__ __forceinline__ unsigned pack_hl(float f) {
  unsigned hi = bf16r(f);
  float r = f - __uint_as_float(hi << 16);
  return (hi << 16) | bf16r(r);
}

__device__ __forceinline__ float exact_fmod(float a, float m, float rcp_m) {
  float q = floorf(a * rcp_m);
  float r = fmaf(q, -m, a);
  if (r < 0.0f) r += m;
  else if (r >= m) r -= m;
  return r;
}

__device__ __forceinline__ f32x4 mfma16(bf16x8 a, bf16x8 b, f32x4 c) {
  return __builtin_amdgcn_mfma_f32_16x16x32_bf16(a, b, c, 0, 0, 0);
}

__device__ __forceinline__ void lda(const unsigned* rp, bf16x8& hi, bf16x8& lo) {
  uint4 w0 = *(const uint4*)rp;
  uint4 w1 = *(const uint4*)(rp + 4);
  union { unsigned u[4]; bf16x8 v; } H, L;
  H.u[0] = __builtin_amdgcn_perm(w0.y, w0.x, 0x07060302u);
  H.u[1] = __builtin_amdgcn_perm(w0.w, w0.z, 0x07060302u);
  H.u[2] = __builtin_amdgcn_perm(w1.y, w1.x, 0x07060302u);
  H.u[3] = __builtin_amdgcn_perm(w1.w, w1.z, 0x07060302u);
  L.u[0] = __builtin_amdgcn_perm(w0.y, w0.x, 0x05040100u);
  L.u[1] = __builtin_amdgcn_perm(w0.w, w0.z, 0x05040100u);
  L.u[2] = __builtin_amdgcn_perm(w1.y, w1.x, 0x05040100u);
  L.u[3] = __builtin_amdgcn_perm(w1.w, w1.z, 0x05040100u);
  hi = H.v; lo = L.v;
}

__device__ __forceinline__ float bdval_(const float* wl2, const float* wt2,
                                        const float* wa2, const float* wm2,
                                        int k, int col) {
  if ((k >> 4) != (col >> 4)) return 0.f;
  int b = col >> 4;
  const float* W2 = (b & 2) ? ((b & 1) ? wm2 : wa2) : ((b & 1) ? wt2 : wl2);
  return W2[(k & 15) * 16 + (col & 15)];
}

__device__ __forceinline__ unsigned frag_word(const Params& p, int m) {
  int fi = m >> 8;
  int ln = (m >> 2) & 63;
  int j2 = m & 3;
  int layer, nt, ks;
  if (fi < 4)       { layer = 0; nt = fi;             ks = nt >> 1; }
  else if (fi < 12) { layer = 1; nt = (fi - 4) >> 1;  ks = (fi - 4) & 1; }
  else              { layer = 2; nt = (fi - 12) >> 1; ks = (fi - 12) & 1; }
  int col = nt * 16 + (ln & 15);
  int k0  = ks * 32 + ((ln >> 4) << 3) + (j2 << 1);
  float v0, v1;
  if (layer == 0) {
    v0 = bdval_(p.wl2, p.wt2, p.wa2, p.wm2, k0, col);
    v1 = bdval_(p.wl2, p.wt2, p.wa2, p.wm2, k0 + 1, col);
  } else {
    const float* W = (layer == 1) ? p.wc1 : p.wc2;
    v0 = W[k0 * 64 + col]; v1 = W[(k0 + 1) * 64 + col];
  }
  return (bf16r(v1) << 16) | bf16r(v0);
}

__global__ void pack_kernel(Params p) {
  int m = blockIdx.x * 256 + threadIdx.x;
  if (m < 5120) p.wfrag[m] = frag_word(p, m);
}

__device__ __forceinline__ bf16x8 g_ldb(const Params& p, int fi, int lane) {
  union { uint4 q; unsigned u[4]; bf16x8 v; } U;
  if (p.wfrag) {
    U.q = *(const uint4*)(p.wfrag + ((fi * 64 + lane) << 2));
  } else {
    int m = fi * 256 + lane * 4;
    U.u[0] = frag_word(p, m + 0);
    U.u[1] = frag_word(p, m + 1);
    U.u[2] = frag_word(p, m + 2);
    U.u[3] = frag_word(p, m + 3);
  }
  return U.v;
}

__device__ __forceinline__ int lower_bound(const int* seg, int T, int v) {
  int lo = 0, hi = T;
  while (lo < hi) { int m = (lo + hi) >> 1; if (seg[m] < v) lo = m + 1; else hi = m; }
  return lo;
}

// ---------------- unsegmented wave64 inclusive prefix scans (DPP) ----------------
__device__ __forceinline__ float pscan_f(float v) {
  v += __int_as_float(__builtin_amdgcn_update_dpp(0, __float_as_int(v), 0x111, 0xf, 0xf, true));
  v += __int_as_float(__builtin_amdgcn_update_dpp(0, __float_as_int(v), 0x112, 0xf, 0xf, true));
  v += __int_as_float(__builtin_amdgcn_update_dpp(0, __float_as_int(v), 0x114, 0xf, 0xf, true));
  v += __int_as_float(__builtin_amdgcn_update_dpp(0, __float_as_int(v), 0x118, 0xf, 0xf, true));
  v += __int_as_float(__builtin_amdgcn_update_dpp(0, __float_as_int(v), 0x142, 0xa, 0xf, true));
  v += __int_as_float(__builtin_amdgcn_update_dpp(0, __float_as_int(v), 0x143, 0xc, 0xf, true));
  return v;
}
__device__ __forceinline__ unsigned pscan_u(unsigned v) {
  int x = (int)v;
  x += __builtin_amdgcn_update_dpp(0, x, 0x111, 0xf, 0xf, true);
  x += __builtin_amdgcn_update_dpp(0, x, 0x112, 0xf, 0xf, true);
  x += __builtin_amdgcn_update_dpp(0, x, 0x114, 0xf, 0xf, true);
  x += __builtin_amdgcn_update_dpp(0, x, 0x118, 0xf, 0xf, true);
  x += __builtin_amdgcn_update_dpp(0, x, 0x142, 0xa, 0xf, true);
  x += __builtin_amdgcn_update_dpp(0, x, 0x143, 0xc, 0xf, true);
  return (unsigned)x;
}
__device__ __forceinline__ unsigned wshr1_u(unsigned v) {
  return (unsigned)__builtin_amdgcn_update_dpp(0, (int)v, 0x138, 0xf, 0xf, true);
}
__device__ __forceinline__ float wshr1_f(float v) {
  return __int_as_float(__builtin_amdgcn_update_dpp(0, __float_as_int(v), 0x138, 0xf, 0xf, true));
}
__device__ __forceinline__ int wshr1_i(int v) {
  return __builtin_amdgcn_update_dpp(0, v, 0x138, 0xf, 0xf, true);
}

// 16 users per wave, fully independent waves. Owner lanes 0-15 hold per-user
// partials in registers; finalize distributes via __shfl (no LDS acc, no atomics).
// Pass 1: sums only; dt via lane-shift+carry (no seg[e+1]/ts[e+1] gathers).
// Phase B: 2 users in parallel (32-lane halves): hash uniq + tmax/tmin + sum(d).
__global__ __launch_bounds__(256, 4) void mobility_kernel(Params p) {
  __shared__ __align__(16) unsigned s_pool[4352];    // per-wave featT (hash aliases)
  __shared__ float s_w1[304];
  __shared__ float s_b1[64], s_b2[64], s_bc1[64], s_bc2[64];

  int tid = threadIdx.x;
  int lane = tid & 63, w = tid >> 6;

  if (tid < 32)  s_w1[tid]       = p.wl1[tid];
  if (tid < 48)  s_w1[32 + tid]  = p.wt1[tid];
  if (tid < 160) s_w1[80 + tid]  = p.wa1[tid];
  if (tid < 64)  s_w1[240 + tid] = p.wm1[tid];
  if (tid < 16) {
    s_b1[tid]    = p.bl1[tid]; s_b1[16+tid] = p.bt1[tid];
    s_b1[32+tid] = p.ba1[tid]; s_b1[48+tid] = p.bm1[tid];
    s_b2[tid]    = p.bl2[tid]; s_b2[16+tid] = p.bt2[tid];
    s_b2[32+tid] = p.ba2[tid]; s_b2[48+tid] = p.bm2[tid];
  }
  if (tid < 64) { s_bc1[tid] = p.bc1[tid]; s_bc2[tid] = p.bc2[tid]; }
  __syncthreads();

  int uw0 = blockIdx.x * 64 + w * 16;        // this wave's 16 users
  if (uw0 >= p.N) return;
  int myu = uw0 + lane;
  int myuc = min(myu, p.N - 1);
  int s0, e0;
  if (p.use_off) {
    s0 = p.off[myuc]; e0 = p.off[myuc + 1];
  } else {
    s0 = lower_bound(p.seg, p.T, myuc);
    e0 = lower_bound(p.seg, p.T, myuc + 1);
  }
  int W0 = rdlane_i(s0, 0);
  int W1 = rdlane_i(e0, 15);
  float Lf = (float)(e0 - s0);

  const float2* lp2 = (const float2*)p.loc;
  const float NINF = __int_as_float(0xff800000u);
  const float PINF = __int_as_float(0x7f800000u);

  // owner-lane (0-15) register accumulators for user uw0+lane
  int aKx = 0, aKy = 0, aXX = 0;
  float aH = 0.f, aDY = 0.f, aT = 0.f, aDF2 = 0.f;
  unsigned aH0 = 0u, aH1 = 0u, aH2 = 0u;

  int carry_sv = -987654;
  float carry_t = 0.f;

  // ---------------- pass 1: coalesced stats, prefix-diff to owner lanes ----------------
  for (int base = W0; base < W1; base += 64) {
    int e = base + lane;
    bool on = e < W1;
    int ec = on ? e : (W1 - 1);
    int sv = p.seg[ec];
    float t  = p.ts[ec];
    int c = p.cat[ec];
    float2 xy = lp2[ec];

    // dt^2 via lane-shift: dt between (ec-1, ec), attributed at position ec
    int psv = wshr1_i(sv);
    float pt = wshr1_f(t);
    if (lane == 0) { psv = carry_sv; pt = carry_t; }

    unsigned vXY = 0u, vXX = 0u, vH0 = 0u, vH1 = 0u, vH2 = 0u;
    float vH = 0.f, vDY = 0.f, vT = 0.f, vDF2 = 0.f;
    if (on) {
      int kx = (int)lrintf(xy.x * 50.0f);
      int ky = (int)lrintf(xy.y * 50.0f);
      vXY = ((unsigned)(kx + 512) << 16) | (unsigned)(ky + 512);
      vXX = (unsigned)(kx * kx + ky * ky);
      float hr = exact_fmod(t, 86400.0f, 1.0f / 86400.0f);
      vH = hr * (1.0f / 3600.0f);
      float ud = (float)((double)t * (1.0 / 86400.0));
      vDY = exact_fmod(ud, 7.0f, 1.0f / 7.0f);
      vT = t;
      unsigned bit = 1u << ((c & 3) * 8);
      int wsel = c >> 2;
      vH0 = (wsel == 0) ? bit : 0u;
      vH1 = (wsel == 1) ? bit : 0u;
      vH2 = (wsel == 2) ? bit : 0u;
      if (psv == sv) { float dt = t - pt; vDF2 = dt * dt; }
    }

    unsigned pXY = pscan_u(vXY), pXX = pscan_u(vXX);
    unsigned pH0 = pscan_u(vH0), pH1 = pscan_u(vH1), pH2 = pscan_u(vH2);
    float pH = pscan_f(vH), pDY = pscan_f(vDY), pT = pscan_f(vT), pDF2 = pscan_f(vDF2);

    int lo = min(max(s0 - base, 0), 64);
    int hi = min(max(e0 - base, 0), 64);
    int idx = max(hi - 1, 0);
    unsigned PXY = (unsigned)__shfl((int)pXY, idx);
    unsigned PXX = (unsigned)__shfl((int)pXX, idx);
    unsigned PH0 = (unsigned)__shfl((int)pH0, idx);
    unsigned PH1 = (unsigned)__shfl((int)pH1, idx);
    unsigned PH2 = (unsigned)__shfl((int)pH2, idx);
    float PH = __shfl(pH, idx), PDY = __shfl(pDY, idx);
    float PT = __shfl(pT, idx), PDF2 = __shfl(pDF2, idx);
    unsigned LXY = wshr1_u(PXY), LXX = wshr1_u(PXX);
    unsigned LH0 = wshr1_u(PH0), LH1 = wshr1_u(PH1), LH2 = wshr1_u(PH2);
    float LH = wshr1_f(PH), LDY = wshr1_f(PDY);
    float LT = wshr1_f(PT), LDF2 = wshr1_f(PDF2);

    if (hi > lo) {
      int cnt = hi - lo;
      bool ul_ = lo > 0;
      unsigned dXY = PXY - (ul_ ? LXY : 0u);
      aKx += (int)(dXY >> 16) - (cnt << 9);
      aKy += (int)(dXY & 0xffffu) - (cnt << 9);
      aXX += (int)(PXX - (ul_ ? LXX : 0u));
      aH0 += PH0 - (ul_ ? LH0 : 0u);
      aH1 += PH1 - (ul_ ? LH1 : 0u);
      aH2 += PH2 - (ul_ ? LH2 : 0u);
      aH   += PH   - (ul_ ? LH   : 0.f);
      aDY  += PDY  - (ul_ ? LDY  : 0.f);
      aT   += PT   - (ul_ ? LT   : 0.f);
      aDF2 += PDF2 - (ul_ ? LDF2 : 0.f);
    }

    carry_sv = rdlane_i(sv, 63);
    carry_t  = rdlane_f(t, 63);
  }

  // per-lane home (valid on owner lanes 0-15)
  float hx, hy;
  {
    float sx = (float)aKx / 50.0f, sy = (float)aKy / 50.0f;
    hx = sx / Lf; hy = sy / Lf;
  }

  // ---- phase B: 2 users in parallel (32-lane halves): uniq + tmax/tmin + sum(d) ----
  unsigned* fw = s_pool + w * 1088;
  float uqf = 0.f, tmxA = NINF, tmnA = PINF, aD = 0.f;
  {
    int g  = lane >> 5;                 // half index
    int li = lane & 31;                 // lane within half
    unsigned* hashp = fw + g * 128;
    for (int uu = 0; uu < 8; ++uu) {
      int gu = 2 * uu + g;              // this half's user (0..15)
      bool uvalid = (uw0 + gu) < p.N;
      int suu = __shfl(s0, gu), euu = __shfl(e0, gu);
      float hxu = __shfl(hx, gu), hyu = __shfl(hy, gu);
      int Lu = euu - suu;
      int uq = 0;
      float cmx = NINF, cmn = PINF, dsum = 0.f;
      if (uvalid) {
        if (Lu <= 96) {
          hashp[li] = 0u; hashp[32 + li] = 0u; hashp[64 + li] = 0u; hashp[96 + li] = 0u;
          asm volatile("s_waitcnt lgkmcnt(0)" ::: "memory");
          for (int b2 = suu; b2 < euu; b2 += 32) {
            int i = b2 + li;
            bool fresh = false;
            if (i < euu) {
              float tv = p.ts[i];
              cmx = fmaxf(cmx, tv); cmn = fminf(cmn, tv);
              float2 xy = lp2[i];
              float dx = xy.x - hxu, dyv = xy.y - hyu;
              dsum += sqrtf(fmaf(dx, dx, dyv * dyv));
              int kx = (int)lrintf(xy.x * 50.0f) + 2048;
              int ky = (int)lrintf(xy.y * 50.0f) + 2048;
              unsigned key = (((unsigned)kx << 12) | (unsigned)ky) + 1u;
              unsigned h = (key * 2654435761u) >> 25;
              while (true) {
                unsigned old = atomicCAS(&hashp[h], 0u, key);
                if (old == 0u) { fresh = true; break; }
                if (old == key) break;
                h = (h + 1) & 127u;
              }
            }
            unsigned long long bm = __ballot(fresh);
            uq += __popc((unsigned)(bm >> (g * 32)));
          }
        } else {
          for (int b2 = suu; b2 < euu; b2 += 32) {
            int i = b2 + li;
            bool fresh = false;
            if (i < euu) {
              float tv = p.ts[i];
              cmx = fmaxf(cmx, tv); cmn = fminf(cmn, tv);
              float x = p.loc[2*(size_t)i], y = p.loc[2*(size_t)i+1];
              float dx = x - hxu, dyv = y - hyu;
              dsum += sqrtf(fmaf(dx, dx, dyv * dyv));
              fresh = true;
              for (int jj = suu; jj < i; ++jj) {
                if (p.loc[2*(size_t)jj] == x && p.loc[2*(size_t)jj+1] == y) { fresh = false; break; }
              }
            }
            unsigned long long bm = __ballot(fresh);
            uq += __popc((unsigned)(bm >> (g * 32)));
          }
        }
      }
      // butterfly within 32-lane half (uq already uniform per half)
      #pragma unroll
      for (int o = 16; o > 0; o >>= 1) {
        cmx = fmaxf(cmx, __shfl_xor(cmx, o));
        cmn = fminf(cmn, __shfl_xor(cmn, o));
        dsum += __shfl_xor(dsum, o);
      }
      // cross-half pull: value for user 2uu+b lives in half b (rep lanes 0 / 32)
      int srcl = (lane & 1) << 5;
      float mxv = __shfl(cmx, srcl);
      float mnv = __shfl(cmn, srcl);
      float dsv = __shfl(dsum, srcl);
      int   uqv = __shfl(uq, srcl);
      if ((lane >> 1) == uu) { tmxA = mxv; tmnA = mnv; aD = dsv; uqf = (float)uqv; }
    }
  }
  asm volatile("s_waitcnt lgkmcnt(0)" ::: "memory");   // hash reads done before featT overwrite

  // ---------------- finalize: lane = (user lr, quarter g2); stats via shfl ----------------
  int lr = lane & 15, g2 = lane >> 4;
  int us0 = __shfl(s0, lr), ue0 = __shfl(e0, lr);
  float LfU = (float)(ue0 - us0);
  int KX = __shfl(aKx, lr), KY = __shfl(aKy, lr), XX = __shfl(aXX, lr);
  float H_ = __shfl(aH, lr), DY_ = __shfl(aDY, lr);
  float T_ = __shfl(aT, lr), DF2_ = __shfl(aDF2, lr);
  unsigned H0_ = (unsigned)__shfl((int)aH0, lr);
  unsigned H1_ = (unsigned)__shfl((int)aH1, lr);
  unsigned H2_ = (unsigned)__shfl((int)aH2, lr);
  float TMX_ = __shfl(tmxA, lr), TMN_ = __shfl(tmnA, lr);
  float D_ = __shfl(aD, lr), UQ_ = __shfl(uqf, lr);

  unsigned hp16[16];
  if (g2 == 0) {
    float sxU = (float)KX / 50.0f, syU = (float)KY / 50.0f;
    float hxU = sxU / LfU, hyU = syU / LfU;
    #pragma unroll
    for (int j = 0; j < 16; ++j)
      hp16[j] = pack_hl(fmaxf(s_b1[j] + hxU * s_w1[j] + hyU * s_w1[16 + j], 0.f));
  } else if (g2 == 1) {
    float th = H_ / LfU, tdy = DY_ / LfU;
    float tmo = (T_ * (1.0f / 2592000.0f)) / LfU;
    #pragma unroll
    for (int j = 0; j < 16; ++j)
      hp16[j] = pack_hl(fmaxf(s_b1[16 + j] + th * s_w1[32 + j] + tdy * s_w1[48 + j]
                              + tmo * s_w1[64 + j], 0.f));
  } else if (g2 == 2) {
    float act[10];
    act[0] = (float)(H0_ & 255u) / LfU;
    act[1] = (float)((H0_ >> 8) & 255u) / LfU;
    act[2] = (float)((H0_ >> 16) & 255u) / LfU;
    act[3] = (float)((H0_ >> 24) & 255u) / LfU;
    act[4] = (float)(H1_ & 255u) / LfU;
    act[5] = (float)((H1_ >> 8) & 255u) / LfU;
    act[6] = (float)((H1_ >> 16) & 255u) / LfU;
    act[7] = (float)((H1_ >> 24) & 255u) / LfU;
    act[8] = (float)(H2_ & 255u) / LfU;
    act[9] = (float)((H2_ >> 8) & 255u) / LfU;
    #pragma unroll
    for (int j = 0; j < 16; ++j) {
      float aa = s_b1[32 + j];
      #pragma unroll
      for (int b = 0; b < 10; ++b) aa = fmaf(act[b], s_w1[80 + b * 16 + j], aa);
      hp16[j] = pack_hl(fmaxf(aa, 0.f));
    }
  } else {
    float sxU = (float)KX / 50.0f, syU = (float)KY / 50.0f;
    float sxx = (float)XX / 2500.0f;
    float sD = D_;
    float sD2 = sxx - (sxU * sxU + syU * syU) / LfU;
    float varD = (sD2 - sD * sD / LfU) / (LfU - 1.0f);
    float rad  = sqrtf(fmaxf(varD, 0.0f));
    float divy = UQ_ / LfU;
    float span = (TMX_ - TMN_) / 86400.0f;
    float freq = LfU / fmaxf(span, 1.0f);
    float tfirst = p.ts[us0];
    float tlast  = p.ts[ue0 - 1];
    float sdf = tlast - tfirst;
    float mm   = LfU - 1.0f;
    float dmu  = sdf / mm;
    float dvar = (DF2_ - mm * dmu * dmu) / (mm - 1.0f);
    float reg  = 1.0f / (sqrtf(fmaxf(dvar, 0.0f)) + 1e-6f);
    #pragma unroll
    for (int j = 0; j < 16; ++j)
      hp16[j] = pack_hl(fmaxf(s_b1[48 + j] + rad * s_w1[240 + j] + divy * s_w1[256 + j]
                              + freq * s_w1[272 + j] + reg * s_w1[288 + j], 0.f));
  }

  // ---------------- stage featT + 3-layer MFMA chain (one 16-user batch) ----------------
  {
    unsigned* row = fw + lr * 68 + g2 * 16;
    #pragma unroll
    for (int j = 0; j < 4; ++j)
      *(uint4*)(row + 4 * j) = make_uint4(hp16[4*j], hp16[4*j+1], hp16[4*j+2], hp16[4*j+3]);
  }
  asm volatile("s_waitcnt lgkmcnt(0)" ::: "memory");

  int lg = lane >> 4;
  const unsigned* arow = fw + lr * 68 + (lg << 3);

  bf16x8 ah[2], al[2];
  lda(arow,      ah[0], al[0]);
  lda(arow + 32, ah[1], al[1]);
  f32x4 acc[4];
  #pragma unroll
  for (int nt = 0; nt < 4; ++nt) {
    float bv = s_b2[nt * 16 + lr];
    acc[nt] = (f32x4){bv, bv, bv, bv};
    int ks = nt >> 1;
    bf16x8 bw = g_ldb(p, nt, lane);
    acc[nt] = mfma16(ah[ks], bw, acc[nt]);
    acc[nt] = mfma16(al[ks], bw, acc[nt]);
  }
  #pragma unroll
  for (int nt = 0; nt < 4; ++nt)
    #pragma unroll
    for (int r = 0; r < 4; ++r)
      fw[(lg * 4 + r) * 68 + nt * 16 + lr] = pack_hl(acc[nt][r]);
  asm volatile("s_waitcnt lgkmcnt(0)" ::: "memory");

  lda(arow,      ah[0], al[0]);
  lda(arow + 32, ah[1], al[1]);
  #pragma unroll
  for (int nt = 0; nt < 4; ++nt) {
    float bv = s_bc1[nt * 16 + lr];
    acc[nt] = (f32x4){bv, bv, bv, bv};
    #pragma unroll
    for (int ks = 0; ks < 2; ++ks) {
      bf16x8 bw = g_ldb(p, 4 + nt * 2 + ks, lane);
      acc[nt] = mfma16(ah[ks], bw, acc[nt]);
      acc[nt] = mfma16(al[ks], bw, acc[nt]);
    }
  }
  #pragma unroll
  for (int nt = 0; nt < 4; ++nt)
    #pragma unroll
    for (int r = 0; r < 4; ++r)
      fw[(lg * 4 + r) * 68 + nt * 16 + lr] = pack_hl(fmaxf(acc[nt][r], 0.f));
  asm volatile("s_waitcnt lgkmcnt(0)" ::: "memory");

  lda(arow,      ah[0], al[0]);
  lda(arow + 32, ah[1], al[1]);
  #pragma unroll
  for (int nt = 0; nt < 4; ++nt) {
    float bv = s_bc2[nt * 16 + lr];
    acc[nt] = (f32x4){bv, bv, bv, bv};
    #pragma unroll
    for (int ks = 0; ks < 2; ++ks) {
      bf16x8 bw = g_ldb(p, 12 + nt * 2 + ks, lane);
      acc[nt] = mfma16(ah[ks], bw, acc[nt]);
      acc[nt] = mfma16(al[ks], bw, acc[nt]);
    }
  }
  #pragma unroll
  for (int nt = 0; nt < 4; ++nt)
    #pragma unroll
    for (int r = 0; r < 4; ++r) {
      int uo = uw0 + lg * 4 + r;
      if (uo < p.N) p.out[(size_t)uo * 64 + nt * 16 + lr] = acc[nt][r];
    }
}

extern "C" void kernel_launch(void* const* d_in, const int* in_sizes, int n_in,
                              void* d_out, int out_size, void* d_ws, size_t ws_size,
                              hipStream_t stream) {
  Params p;
  p.loc = (const float*)d_in[0];
  p.ts  = (const float*)d_in[1];
  p.cat = (const int*)d_in[2];
  p.seg = (const int*)d_in[3];
  p.wl1 = (const float*)d_in[5];  p.bl1 = (const float*)d_in[6];
  p.wl2 = (const float*)d_in[7];  p.bl2 = (const float*)d_in[8];
  p.wt1 = (const float*)d_in[9];  p.bt1 = (const float*)d_in[10];
  p.wt2 = (const float*)d_in[11]; p.bt2 = (const float*)d_in[12];
  p.wa1 = (const float*)d_in[13]; p.ba1 = (const float*)d_in[14];
  p.wa2 = (const float*)d_in[15]; p.ba2 = (const float*)d_in[16];
  p.wm1 = (const float*)d_in[17]; p.bm1 = (const float*)d_in[18];
  p.wm2 = (const float*)d_in[19]; p.bm2 = (const float*)d_in[20];
  p.wc1 = (const float*)d_in[21]; p.bc1 = (const float*)d_in[22];
  p.wc2 = (const float*)d_in[23]; p.bc2 = (const float*)d_in[24];
  p.out = (float*)d_out;
  p.N = out_size / 64;
  p.T = in_sizes[1];
  int* off = (int*)d_ws;
  p.off = off;
  p.use_off = (ws_size >= (size_t)(p.N + 1) * sizeof(int)) ? 1 : 0;

  size_t fragOff = (((size_t)p.N + 1) + 3) & ~(size_t)3;
  p.wfrag = nullptr;
  if (ws_size >= (fragOff + 5120) * sizeof(unsigned)) {
    p.wfrag = (unsigned*)d_ws + fragOff;
    pack_kernel<<<20, 256, 0, stream>>>(p);
  }

  if (p.use_off) {
    offsets_kernel<<<(p.T + 255)/256, 256, 0, stream>>>(p.seg, off, p.T, p.N);
  }
  int nblocks = (p.N + 63) / 64;
  mobility_kernel<<<nblocks, 256, 0, stream>>>(p);
}

// Round 17
// 153.287 us; speedup vs baseline: 1.7121x; 1.0690x over previous
//
#include <hip/hip_runtime.h>

typedef short bf16x8 __attribute__((ext_vector_type(8)));
typedef float f32x4 __attribute__((ext_vector_type(4)));

struct Params {
  const float* loc; const float* ts; const int* cat; const int* seg;
  const int* off;
  const float *wl1,*bl1,*wl2,*bl2;
  const float *wt1,*bt1,*wt2,*bt2;
  const float *wa1,*ba1,*wa2,*ba2;
  const float *wm1,*bm1,*wm2,*bm2;
  const float *wc1,*bc1,*wc2,*bc2;
  float* out;
  unsigned* wfrag;          // prepacked bf16 B-fragments in d_ws (or nullptr)
  int N, T, use_off;
};

__global__ void offsets_kernel(const int* __restrict__ seg, int* __restrict__ off, int T, int N) {
  int i = blockIdx.x * blockDim.x + threadIdx.x;
  if (i == 0) off[N] = T;
  if (i < T) {
    int s = seg[i];
    if (i == 0 || seg[i-1] != s) off[s] = i;
  }
}

__device__ __forceinline__ int rdlane_i(int v, int l) {   // UNIFORM l only
  return __builtin_amdgcn_readlane(v, l);
}
__device__ __forceinline__ float rdlane_f(float v, int l) {
  return __int_as_float(__builtin_amdgcn_readlane(__float_as_int(v), l));
}

__device__ __forceinline__ unsigned bf16r(float f) {
  unsigned x = __float_as_uint(f);
  return (x + 0x7fffu + ((x >> 16) & 1u)) >> 16;
}
__device__ __forceinline__ unsigned pack_hl(float f) {
  unsigned hi = bf16r(f);
  float r = f - __uint_as_float(hi << 16);
  return (hi << 16) | bf16r(r);
}

__device__ __forceinline__ float exact_fmod(float a, float m, float rcp_m) {
  float q = floorf(a * rcp_m);
  float r = fmaf(q, -m, a);
  if (r < 0.0f) r += m;
  else if (r >= m) r -= m;
  return r;
}

__device__ __forceinline__ f32x4 mfma16(bf16x8 a, bf16x8 b, f32x4 c) {
  return __builtin_amdgcn_mfma_f32_16x16x32_bf16(a, b, c, 0, 0, 0);
}

__device__ __forceinline__ void lda(const unsigned* rp, bf16x8& hi, bf16x8& lo) {
  uint4 w0 = *(const uint4*)rp;
  uint4 w1 = *(const uint4*)(rp + 4);
  union { unsigned u[4]; bf16x8 v; } H, L;
  H.u[0] = __builtin_amdgcn_perm(w0.y, w0.x, 0x07060302u);
  H.u[1] = __builtin_amdgcn_perm(w0.w, w0.z, 0x07060302u);
  H.u[2] = __builtin_amdgcn_perm(w1.y, w1.x, 0x07060302u);
  H.u[3] = __builtin_amdgcn_perm(w1.w, w1.z, 0x07060302u);
  L.u[0] = __builtin_amdgcn_perm(w0.y, w0.x, 0x05040100u);
  L.u[1] = __builtin_amdgcn_perm(w0.w, w0.z, 0x05040100u);
  L.u[2] = __builtin_amdgcn_perm(w1.y, w1.x, 0x05040100u);
  L.u[3] = __builtin_amdgcn_perm(w1.w, w1.z, 0x05040100u);
  hi = H.v; lo = L.v;
}

__device__ __forceinline__ float bdval_(const float* wl2, const float* wt2,
                                        const float* wa2, const float* wm2,
                                        int k, int col) {
  if ((k >> 4) != (col >> 4)) return 0.f;
  int b = col >> 4;
  const float* W2 = (b & 2) ? ((b & 1) ? wm2 : wa2) : ((b & 1) ? wt2 : wl2);
  return W2[(k & 15) * 16 + (col & 15)];
}

__device__ __forceinline__ unsigned frag_word(const Params& p, int m) {
  int fi = m >> 8;
  int ln = (m >> 2) & 63;
  int j2 = m & 3;
  int layer, nt, ks;
  if (fi < 4)       { layer = 0; nt = fi;             ks = nt >> 1; }
  else if (fi < 12) { layer = 1; nt = (fi - 4) >> 1;  ks = (fi - 4) & 1; }
  else              { layer = 2; nt = (fi - 12) >> 1; ks = (fi - 12) & 1; }
  int col = nt * 16 + (ln & 15);
  int k0  = ks * 32 + ((ln >> 4) << 3) + (j2 << 1);
  float v0, v1;
  if (layer == 0) {
    v0 = bdval_(p.wl2, p.wt2, p.wa2, p.wm2, k0, col);
    v1 = bdval_(p.wl2, p.wt2, p.wa2, p.wm2, k0 + 1, col);
  } else {
    const float* W = (layer == 1) ? p.wc1 : p.wc2;
    v0 = W[k0 * 64 + col]; v1 = W[(k0 + 1) * 64 + col];
  }
  return (bf16r(v1) << 16) | bf16r(v0);
}

__global__ void pack_kernel(Params p) {
  int m = blockIdx.x * 256 + threadIdx.x;
  if (m < 5120) p.wfrag[m] = frag_word(p, m);
}

__device__ __forceinline__ bf16x8 g_ldb(const Params& p, int fi, int lane) {
  union { uint4 q; unsigned u[4]; bf16x8 v; } U;
  if (p.wfrag) {
    U.q = *(const uint4*)(p.wfrag + ((fi * 64 + lane) << 2));
  } else {
    int m = fi * 256 + lane * 4;
    U.u[0] = frag_word(p, m + 0);
    U.u[1] = frag_word(p, m + 1);
    U.u[2] = frag_word(p, m + 2);
    U.u[3] = frag_word(p, m + 3);
  }
  return U.v;
}

__device__ __forceinline__ int lower_bound(const int* seg, int T, int v) {
  int lo = 0, hi = T;
  while (lo < hi) { int m = (lo + hi) >> 1; if (seg[m] < v) lo = m + 1; else hi = m; }
  return lo;
}

// ---------------- unsegmented wave64 inclusive prefix scans (DPP) ----------------
__device__ __forceinline__ float pscan_f(float v) {
  v += __int_as_float(__builtin_amdgcn_update_dpp(0, __float_as_int(v), 0x111, 0xf, 0xf, true));
  v += __int_as_float(__builtin_amdgcn_update_dpp(0, __float_as_int(v), 0x112, 0xf, 0xf, true));
  v += __int_as_float(__builtin_amdgcn_update_dpp(0, __float_as_int(v), 0x114, 0xf, 0xf, true));
  v += __int_as_float(__builtin_amdgcn_update_dpp(0, __float_as_int(v), 0x118, 0xf, 0xf, true));
  v += __int_as_float(__builtin_amdgcn_update_dpp(0, __float_as_int(v), 0x142, 0xa, 0xf, true));
  v += __int_as_float(__builtin_amdgcn_update_dpp(0, __float_as_int(v), 0x143, 0xc, 0xf, true));
  return v;
}
__device__ __forceinline__ unsigned pscan_u(unsigned v) {
  int x = (int)v;
  x += __builtin_amdgcn_update_dpp(0, x, 0x111, 0xf, 0xf, true);
  x += __builtin_amdgcn_update_dpp(0, x, 0x112, 0xf, 0xf, true);
  x += __builtin_amdgcn_update_dpp(0, x, 0x114, 0xf, 0xf, true);
  x += __builtin_amdgcn_update_dpp(0, x, 0x118, 0xf, 0xf, true);
  x += __builtin_amdgcn_update_dpp(0, x, 0x142, 0xa, 0xf, true);
  x += __builtin_amdgcn_update_dpp(0, x, 0x143, 0xc, 0xf, true);
  return (unsigned)x;
}
__device__ __forceinline__ unsigned wshr1_u(unsigned v) {
  return (unsigned)__builtin_amdgcn_update_dpp(0, (int)v, 0x138, 0xf, 0xf, true);
}
__device__ __forceinline__ float wshr1_f(float v) {
  return __int_as_float(__builtin_amdgcn_update_dpp(0, __float_as_int(v), 0x138, 0xf, 0xf, true));
}
__device__ __forceinline__ int wshr1_i(int v) {
  return __builtin_amdgcn_update_dpp(0, v, 0x138, 0xf, 0xf, true);
}

// 16 users per wave, fully independent waves. Owner lanes 0-15 hold per-user
// partials in registers; finalize distributes via __shfl (no LDS acc, no atomics).
// Pass 1: sums only; dt via lane-shift+carry. Phase B: 4 users in parallel
// (16-lane quarters): hash uniq + tmax/tmin + sum(d).
__global__ __launch_bounds__(256, 4) void mobility_kernel(Params p) {
  __shared__ __align__(16) unsigned s_pool[4352];    // per-wave featT (hash aliases)
  __shared__ float s_w1[304];
  __shared__ float s_b1[64], s_b2[64], s_bc1[64], s_bc2[64];

  int tid = threadIdx.x;
  int lane = tid & 63, w = tid >> 6;

  if (tid < 32)  s_w1[tid]       = p.wl1[tid];
  if (tid < 48)  s_w1[32 + tid]  = p.wt1[tid];
  if (tid < 160) s_w1[80 + tid]  = p.wa1[tid];
  if (tid < 64)  s_w1[240 + tid] = p.wm1[tid];
  if (tid < 16) {
    s_b1[tid]    = p.bl1[tid]; s_b1[16+tid] = p.bt1[tid];
    s_b1[32+tid] = p.ba1[tid]; s_b1[48+tid] = p.bm1[tid];
    s_b2[tid]    = p.bl2[tid]; s_b2[16+tid] = p.bt2[tid];
    s_b2[32+tid] = p.ba2[tid]; s_b2[48+tid] = p.bm2[tid];
  }
  if (tid < 64) { s_bc1[tid] = p.bc1[tid]; s_bc2[tid] = p.bc2[tid]; }
  __syncthreads();

  int uw0 = blockIdx.x * 64 + w * 16;        // this wave's 16 users
  if (uw0 >= p.N) return;
  int myu = uw0 + lane;
  int myuc = min(myu, p.N - 1);
  int s0, e0;
  if (p.use_off) {
    s0 = p.off[myuc]; e0 = p.off[myuc + 1];
  } else {
    s0 = lower_bound(p.seg, p.T, myuc);
    e0 = lower_bound(p.seg, p.T, myuc + 1);
  }
  int W0 = rdlane_i(s0, 0);
  int W1 = rdlane_i(e0, 15);
  float Lf = (float)(e0 - s0);

  const float2* lp2 = (const float2*)p.loc;
  const float NINF = __int_as_float(0xff800000u);
  const float PINF = __int_as_float(0x7f800000u);

  // owner-lane (0-15) register accumulators for user uw0+lane
  int aKx = 0, aKy = 0, aXX = 0;
  float aH = 0.f, aDY = 0.f, aT = 0.f, aDF2 = 0.f;
  unsigned aH0 = 0u, aH1 = 0u, aH2 = 0u;

  int carry_sv = -987654;
  float carry_t = 0.f;

  // ---------------- pass 1: coalesced stats, prefix-diff to owner lanes ----------------
  for (int base = W0; base < W1; base += 64) {
    int e = base + lane;
    bool on = e < W1;
    int ec = on ? e : (W1 - 1);
    int sv = p.seg[ec];
    float t  = p.ts[ec];
    int c = p.cat[ec];
    float2 xy = lp2[ec];

    // dt^2 via lane-shift: dt between (ec-1, ec), attributed at position ec
    int psv = wshr1_i(sv);
    float pt = wshr1_f(t);
    if (lane == 0) { psv = carry_sv; pt = carry_t; }

    unsigned vXY = 0u, vXX = 0u, vH0 = 0u, vH1 = 0u, vH2 = 0u;
    float vH = 0.f, vDY = 0.f, vT = 0.f, vDF2 = 0.f;
    if (on) {
      int kx = (int)lrintf(xy.x * 50.0f);
      int ky = (int)lrintf(xy.y * 50.0f);
      vXY = ((unsigned)(kx + 512) << 16) | (unsigned)(ky + 512);
      vXX = (unsigned)(kx * kx + ky * ky);
      float hr = exact_fmod(t, 86400.0f, 1.0f / 86400.0f);
      vH = hr * (1.0f / 3600.0f);
      float ud = (float)((double)t * (1.0 / 86400.0));
      vDY = exact_fmod(ud, 7.0f, 1.0f / 7.0f);
      vT = t;
      unsigned bit = 1u << ((c & 3) * 8);
      int wsel = c >> 2;
      vH0 = (wsel == 0) ? bit : 0u;
      vH1 = (wsel == 1) ? bit : 0u;
      vH2 = (wsel == 2) ? bit : 0u;
      if (psv == sv) { float dt = t - pt; vDF2 = dt * dt; }
    }

    unsigned pXY = pscan_u(vXY), pXX = pscan_u(vXX);
    unsigned pH0 = pscan_u(vH0), pH1 = pscan_u(vH1), pH2 = pscan_u(vH2);
    float pH = pscan_f(vH), pDY = pscan_f(vDY), pT = pscan_f(vT), pDF2 = pscan_f(vDF2);

    int lo = min(max(s0 - base, 0), 64);
    int hi = min(max(e0 - base, 0), 64);
    int idx = max(hi - 1, 0);
    unsigned PXY = (unsigned)__shfl((int)pXY, idx);
    unsigned PXX = (unsigned)__shfl((int)pXX, idx);
    unsigned PH0 = (unsigned)__shfl((int)pH0, idx);
    unsigned PH1 = (unsigned)__shfl((int)pH1, idx);
    unsigned PH2 = (unsigned)__shfl((int)pH2, idx);
    float PH = __shfl(pH, idx), PDY = __shfl(pDY, idx);
    float PT = __shfl(pT, idx), PDF2 = __shfl(pDF2, idx);
    unsigned LXY = wshr1_u(PXY), LXX = wshr1_u(PXX);
    unsigned LH0 = wshr1_u(PH0), LH1 = wshr1_u(PH1), LH2 = wshr1_u(PH2);
    float LH = wshr1_f(PH), LDY = wshr1_f(PDY);
    float LT = wshr1_f(PT), LDF2 = wshr1_f(PDF2);

    if (hi > lo) {
      int cnt = hi - lo;
      bool ul_ = lo > 0;
      unsigned dXY = PXY - (ul_ ? LXY : 0u);
      aKx += (int)(dXY >> 16) - (cnt << 9);
      aKy += (int)(dXY & 0xffffu) - (cnt << 9);
      aXX += (int)(PXX - (ul_ ? LXX : 0u));
      aH0 += PH0 - (ul_ ? LH0 : 0u);
      aH1 += PH1 - (ul_ ? LH1 : 0u);
      aH2 += PH2 - (ul_ ? LH2 : 0u);
      aH   += PH   - (ul_ ? LH   : 0.f);
      aDY  += PDY  - (ul_ ? LDY  : 0.f);
      aT   += PT   - (ul_ ? LT   : 0.f);
      aDF2 += PDF2 - (ul_ ? LDF2 : 0.f);
    }

    carry_sv = rdlane_i(sv, 63);
    carry_t  = rdlane_f(t, 63);
  }

  // per-lane home (valid on owner lanes 0-15)
  float hx, hy;
  {
    float sx = (float)aKx / 50.0f, sy = (float)aKy / 50.0f;
    hx = sx / Lf; hy = sy / Lf;
  }

  // ---- phase B: 4 users in parallel (16-lane quarters): uniq + tmax/tmin + sum(d) ----
  unsigned* fw = s_pool + w * 1088;
  float uqf = 0.f, tmxA = NINF, tmnA = PINF, aD = 0.f;
  {
    int q  = lane >> 4;                 // quarter index 0..3
    int li = lane & 15;                 // lane within quarter
    unsigned* hashp = fw + q * 128;
    for (int uu = 0; uu < 4; ++uu) {
      int gu = 4 * uu + q;              // this quarter's user (0..15)
      int suu = __shfl(s0, gu), euu = __shfl(e0, gu);
      float hxu = __shfl(hx, gu), hyu = __shfl(hy, gu);
      int Lu = euu - suu;
      int uq = 0;
      float cmx = NINF, cmn = PINF, dsum = 0.f;
      if (Lu <= 96) {
        #pragma unroll
        for (int r = 0; r < 8; ++r) hashp[r * 16 + li] = 0u;
        asm volatile("s_waitcnt lgkmcnt(0)" ::: "memory");
        for (int b2 = suu; b2 < euu; b2 += 16) {
          int i = b2 + li;
          bool fresh = false;
          if (i < euu) {
            float tv = p.ts[i];
            cmx = fmaxf(cmx, tv); cmn = fminf(cmn, tv);
            float2 xy = lp2[i];
            float dx = xy.x - hxu, dyv = xy.y - hyu;
            dsum += sqrtf(fmaf(dx, dx, dyv * dyv));
            int kx = (int)lrintf(xy.x * 50.0f) + 2048;
            int ky = (int)lrintf(xy.y * 50.0f) + 2048;
            unsigned key = (((unsigned)kx << 12) | (unsigned)ky) + 1u;
            unsigned h = (key * 2654435761u) >> 25;
            while (true) {
              unsigned old = atomicCAS(&hashp[h], 0u, key);
              if (old == 0u) { fresh = true; break; }
              if (old == key) break;
              h = (h + 1) & 127u;
            }
          }
          unsigned long long bm = __ballot(fresh);
          uq += __popc((unsigned)((bm >> (q * 16)) & 0xffffu));
        }
      } else {
        for (int b2 = suu; b2 < euu; b2 += 16) {
          int i = b2 + li;
          bool fresh = false;
          if (i < euu) {
            float tv = p.ts[i];
            cmx = fmaxf(cmx, tv); cmn = fminf(cmn, tv);
            float x = p.loc[2*(size_t)i], y = p.loc[2*(size_t)i+1];
            float dx = x - hxu, dyv = y - hyu;
            dsum += sqrtf(fmaf(dx, dx, dyv * dyv));
            fresh = true;
            for (int jj = suu; jj < i; ++jj) {
              if (p.loc[2*(size_t)jj] == x && p.loc[2*(size_t)jj+1] == y) { fresh = false; break; }
            }
          }
          unsigned long long bm = __ballot(fresh);
          uq += __popc((unsigned)((bm >> (q * 16)) & 0xffffu));
        }
      }
      // butterfly within 16-lane quarter (uq already uniform per quarter)
      #pragma unroll
      for (int o = 8; o > 0; o >>= 1) {
        cmx = fmaxf(cmx, __shfl_xor(cmx, o));
        cmn = fminf(cmn, __shfl_xor(cmn, o));
        dsum += __shfl_xor(dsum, o);
      }
      // cross-quarter pull: value for user 4uu+b lives in quarter b (rep lane b*16)
      int srcl = (lane & 3) << 4;
      float mxv = __shfl(cmx, srcl);
      float mnv = __shfl(cmn, srcl);
      float dsv = __shfl(dsum, srcl);
      int   uqv = __shfl(uq, srcl);
      if ((lane >> 2) == uu) { tmxA = mxv; tmnA = mnv; aD = dsv; uqf = (float)uqv; }
    }
  }
  asm volatile("s_waitcnt lgkmcnt(0)" ::: "memory");   // hash reads done before featT overwrite

  // ---------------- finalize: lane = (user lr, quarter g2); stats via shfl ----------------
  int lr = lane & 15, g2 = lane >> 4;
  int us0 = __shfl(s0, lr), ue0 = __shfl(e0, lr);
  float LfU = (float)(ue0 - us0);
  int KX = __shfl(aKx, lr), KY = __shfl(aKy, lr), XX = __shfl(aXX, lr);
  float H_ = __shfl(aH, lr), DY_ = __shfl(aDY, lr);
  float T_ = __shfl(aT, lr), DF2_ = __shfl(aDF2, lr);
  unsigned H0_ = (unsigned)__shfl((int)aH0, lr);
  unsigned H1_ = (unsigned)__shfl((int)aH1, lr);
  unsigned H2_ = (unsigned)__shfl((int)aH2, lr);
  float TMX_ = __shfl(tmxA, lr), TMN_ = __shfl(tmnA, lr);
  float D_ = __shfl(aD, lr), UQ_ = __shfl(uqf, lr);

  unsigned hp16[16];
  if (g2 == 0) {
    float sxU = (float)KX / 50.0f, syU = (float)KY / 50.0f;
    float hxU = sxU / LfU, hyU = syU / LfU;
    #pragma unroll
    for (int j = 0; j < 16; ++j)
      hp16[j] = pack_hl(fmaxf(s_b1[j] + hxU * s_w1[j] + hyU * s_w1[16 + j], 0.f));
  } else if (g2 == 1) {
    float th = H_ / LfU, tdy = DY_ / LfU;
    float tmo = (T_ * (1.0f / 2592000.0f)) / LfU;
    #pragma unroll
    for (int j = 0; j < 16; ++j)
      hp16[j] = pack_hl(fmaxf(s_b1[16 + j] + th * s_w1[32 + j] + tdy * s_w1[48 + j]
                              + tmo * s_w1[64 + j], 0.f));
  } else if (g2 == 2) {
    float act[10];
    act[0] = (float)(H0_ & 255u) / LfU;
    act[1] = (float)((H0_ >> 8) & 255u) / LfU;
    act[2] = (float)((H0_ >> 16) & 255u) / LfU;
    act[3] = (float)((H0_ >> 24) & 255u) / LfU;
    act[4] = (float)(H1_ & 255u) / LfU;
    act[5] = (float)((H1_ >> 8) & 255u) / LfU;
    act[6] = (float)((H1_ >> 16) & 255u) / LfU;
    act[7] = (float)((H1_ >> 24) & 255u) / LfU;
    act[8] = (float)(H2_ & 255u) / LfU;
    act[9] = (float)((H2_ >> 8) & 255u) / LfU;
    #pragma unroll
    for (int j = 0; j < 16; ++j) {
      float aa = s_b1[32 + j];
      #pragma unroll
      for (int b = 0; b < 10; ++b) aa = fmaf(act[b], s_w1[80 + b * 16 + j], aa);
      hp16[j] = pack_hl(fmaxf(aa, 0.f));
    }
  } else {
    float sxU = (float)KX / 50.0f, syU = (float)KY / 50.0f;
    float sxx = (float)XX / 2500.0f;
    float sD = D_;
    float sD2 = sxx - (sxU * sxU + syU * syU) / LfU;
    float varD = (sD2 - sD * sD / LfU) / (LfU - 1.0f);
    float rad  = sqrtf(fmaxf(varD, 0.0f));
    float divy = UQ_ / LfU;
    float span = (TMX_ - TMN_) / 86400.0f;
    float freq = LfU / fmaxf(span, 1.0f);
    float tfirst = p.ts[us0];
    float tlast  = p.ts[ue0 - 1];
    float sdf = tlast - tfirst;
    float mm   = LfU - 1.0f;
    float dmu  = sdf / mm;
    float dvar = (DF2_ - mm * dmu * dmu) / (mm - 1.0f);
    float reg  = 1.0f / (sqrtf(fmaxf(dvar, 0.0f)) + 1e-6f);
    #pragma unroll
    for (int j = 0; j < 16; ++j)
      hp16[j] = pack_hl(fmaxf(s_b1[48 + j] + rad * s_w1[240 + j] + divy * s_w1[256 + j]
                              + freq * s_w1[272 + j] + reg * s_w1[288 + j], 0.f));
  }

  // ---------------- stage featT + 3-layer MFMA chain (one 16-user batch) ----------------
  {
    unsigned* row = fw + lr * 68 + g2 * 16;
    #pragma unroll
    for (int j = 0; j < 4; ++j)
      *(uint4*)(row + 4 * j) = make_uint4(hp16[4*j], hp16[4*j+1], hp16[4*j+2], hp16[4*j+3]);
  }
  asm volatile("s_waitcnt lgkmcnt(0)" ::: "memory");

  int lg = lane >> 4;
  const unsigned* arow = fw + lr * 68 + (lg << 3);

  bf16x8 ah[2], al[2];
  lda(arow,      ah[0], al[0]);
  lda(arow + 32, ah[1], al[1]);
  f32x4 acc[4];
  #pragma unroll
  for (int nt = 0; nt < 4; ++nt) {
    float bv = s_b2[nt * 16 + lr];
    acc[nt] = (f32x4){bv, bv, bv, bv};
    int ks = nt >> 1;
    bf16x8 bw = g_ldb(p, nt, lane);
    acc[nt] = mfma16(ah[ks], bw, acc[nt]);
    acc[nt] = mfma16(al[ks], bw, acc[nt]);
  }
  #pragma unroll
  for (int nt = 0; nt < 4; ++nt)
    #pragma unroll
    for (int r = 0; r < 4; ++r)
      fw[(lg * 4 + r) * 68 + nt * 16 + lr] = pack_hl(acc[nt][r]);
  asm volatile("s_waitcnt lgkmcnt(0)" ::: "memory");

  lda(arow,      ah[0], al[0]);
  lda(arow + 32, ah[1], al[1]);
  #pragma unroll
  for (int nt = 0; nt < 4; ++nt) {
    float bv = s_bc1[nt * 16 + lr];
    acc[nt] = (f32x4){bv, bv, bv, bv};
    #pragma unroll
    for (int ks = 0; ks < 2; ++ks) {
      bf16x8 bw = g_ldb(p, 4 + nt * 2 + ks, lane);
      acc[nt] = mfma16(ah[ks], bw, acc[nt]);
      acc[nt] = mfma16(al[ks], bw, acc[nt]);
    }
  }
  #pragma unroll
  for (int nt = 0; nt < 4; ++nt)
    #pragma unroll
    for (int r = 0; r < 4; ++r)
      fw[(lg * 4 + r) * 68 + nt * 16 + lr] = pack_hl(fmaxf(acc[nt][r], 0.f));
  asm volatile("s_waitcnt lgkmcnt(0)" ::: "memory");

  lda(arow,      ah[0], al[0]);
  lda(arow + 32, ah[1], al[1]);
  #pragma unroll
  for (int nt = 0; nt < 4; ++nt) {
    float bv = s_bc2[nt * 16 + lr];
    acc[nt] = (f32x4){bv, bv, bv, bv};
    #pragma unroll
    for (int ks = 0; ks < 2; ++ks) {
      bf16x8 bw = g_ldb(p, 12 + nt * 2 + ks, lane);
      acc[nt] = mfma16(ah[ks], bw, acc[nt]);
      acc[nt] = mfma16(al[ks], bw, acc[nt]);
    }
  }
  #pragma unroll
  for (int nt = 0; nt < 4; ++nt)
    #pragma unroll
    for (int r = 0; r < 4; ++r) {
      int uo = uw0 + lg * 4 + r;
      if (uo < p.N) p.out[(size_t)uo * 64 + nt * 16 + lr] = acc[nt][r];
    }
}

extern "C" void kernel_launch(void* const* d_in, const int* in_sizes, int n_in,
                              void* d_out, int out_size, void* d_ws, size_t ws_size,
                              hipStream_t stream) {
  Params p;
  p.loc = (const float*)d_in[0];
  p.ts  = (const float*)d_in[1];
  p.cat = (const int*)d_in[2];
  p.seg = (const int*)d_in[3];
  p.wl1 = (const float*)d_in[5];  p.bl1 = (const float*)d_in[6];
  p.wl2 = (const float*)d_in[7];  p.bl2 = (const float*)d_in[8];
  p.wt1 = (const float*)d_in[9];  p.bt1 = (const float*)d_in[10];
  p.wt2 = (const float*)d_in[11]; p.bt2 = (const float*)d_in[12];
  p.wa1 = (const float*)d_in[13]; p.ba1 = (const float*)d_in[14];
  p.wa2 = (const float*)d_in[15]; p.ba2 = (const float*)d_in[16];
  p.wm1 = (const float*)d_in[17]; p.bm1 = (const float*)d_in[18];
  p.wm2 = (const float*)d_in[19]; p.bm2 = (const float*)d_in[20];
  p.wc1 = (const float*)d_in[21]; p.bc1 = (const float*)d_in[22];
  p.wc2 = (const float*)d_in[23]; p.bc2 = (const float*)d_in[24];
  p.out = (float*)d_out;
  p.N = out_size / 64;
  p.T = in_sizes[1];
  int* off = (int*)d_ws;
  p.off = off;
  p.use_off = (ws_size >= (size_t)(p.N + 1) * sizeof(int)) ? 1 : 0;

  size_t fragOff = (((size_t)p.N + 1) + 3) & ~(size_t)3;
  p.wfrag = nullptr;
  if (ws_size >= (fragOff + 5120) * sizeof(unsigned)) {
    p.wfrag = (unsigned*)d_ws + fragOff;
    pack_kernel<<<20, 256, 0, stream>>>(p);
  }

  if (p.use_off) {
    offsets_kernel<<<(p.T + 255)/256, 256, 0, stream>>>(p.seg, off, p.T, p.N);
  }
  int nblocks = (p.N + 63) / 64;
  mobility_kernel<<<nblocks, 256, 0, stream>>>(p);
}